// Round 6
// baseline (2277.716 us; speedup 1.0000x reference)
//
#include <hip/hip_runtime.h>

// EdgeAttrHeteroConv — round 13 (= R12 with the srast/srpast typo fixed;
// R12 never compiled). R11 measured 1839 us; top dispatch agg_k<1>
// (t0, gene) 117 us: FETCH 172.8 MB @ 1.65 TB/s (20% peak), VALUBusy 29%,
// occ 60% -> the random hs-row gather is LATENCY-bound (serial 3-load chain
// perm->src->hs, one chain in flight per wave). This round: (a) scatter_k
// materializes srcp (clamped src) + cmb (packed t0 gate combo) in CSR order,
// removing two indirection levels; (b) agg_k processes FOUR destinations per
// wave -> 4 independent load chains in flight (4x MLP), nmax(4) ~ 25 iters
// vs sum ~ 67; (c) perm dropped from stages A/C (only t2 gate_k needs it),
// arena repacked. Math and per-destination edge order bit-identical to R11
// (verified absmax 1.95e-3). Dense kernels unchanged from R11.

typedef unsigned short u16;
typedef _Float16 h2_t __attribute__((ext_vector_type(2)));
union H2U { unsigned u; h2_t h; };
union HSU { _Float16 f; unsigned short s; };

#if __has_builtin(__builtin_amdgcn_fdot2)
#define FDOT2(a, b, c) __builtin_amdgcn_fdot2((a), (b), (c), false)
#else
#define FDOT2(a, b, c) ((c) + (float)(a).x * (float)(b).x + (float)(a).y * (float)(b).y)
#endif

__device__ __forceinline__ float sigm(float x) { return 1.f / (1.f + expf(-x)); }

// ---------------------------------------------------------------------------
__global__ void zero_k(float* __restrict__ p, int n) {
    int i = blockIdx.x * 256 + threadIdx.x;
    if (i < n) p[i] = 0.f;
}

__global__ void senthost_k(float* out, float v) { out[0] = v; }

// ---------------------------------------------------------------------------
// CSR build: histogram -> 3-kernel exclusive scan (1024-elem chunks) -> scatter
__global__ void hist_k(const int* __restrict__ dst, int* __restrict__ deg, int E, int Nd) {
    int e = blockIdx.x * 256 + threadIdx.x;
    if (e < E) {
        int d = dst[e];
        d = d < 0 ? 0 : (d >= Nd ? Nd - 1 : d);
        atomicAdd(&deg[d], 1);
    }
}

__global__ void scan1_k(const int* __restrict__ deg, int* __restrict__ csum, int Nd) {
    __shared__ int red[256];
    int base = blockIdx.x * 1024;
    int t = threadIdx.x;
    int s = 0;
    for (int i = 0; i < 4; i++) {
        int idx = base + t * 4 + i;
        if (idx < Nd) s += deg[idx];
    }
    red[t] = s;
    __syncthreads();
    for (int off = 128; off > 0; off >>= 1) {
        if (t < off) red[t] += red[t + off];
        __syncthreads();
    }
    if (t == 0) csum[blockIdx.x] = red[0];
}

__global__ void scan2_k(int* __restrict__ csum, int nch) {
    if (threadIdx.x == 0) {
        int acc = 0;
        for (int i = 0; i < nch; i++) { int v = csum[i]; csum[i] = acc; acc += v; }
    }
}

__global__ void scan3_k(const int* __restrict__ deg, const int* __restrict__ csum,
                        int* __restrict__ starts, int* __restrict__ cur, int Nd) {
    __shared__ int sc[256];
    int base = blockIdx.x * 1024;
    int t = threadIdx.x;
    int v[4];
    int s = 0;
    for (int i = 0; i < 4; i++) {
        int idx = base + t * 4 + i;
        v[i] = idx < Nd ? deg[idx] : 0;
        s += v[i];
    }
    sc[t] = s;
    __syncthreads();
    for (int off = 1; off < 256; off <<= 1) {           // Hillis-Steele inclusive
        int add = (t >= off) ? sc[t - off] : 0;
        __syncthreads();
        sc[t] += add;
        __syncthreads();
    }
    int excl = sc[t] - s + csum[blockIdx.x];
    for (int i = 0; i < 4; i++) {
        int idx = base + t * 4 + i;
        if (idx < Nd) { starts[idx] = excl; cur[idx] = excl; excl += v[i]; }
    }
}

// scatter: build CSR payloads directly. perm (edge id) only if needed (t2),
// srcp = clamped source index always, cmb = packed gate combo if cg given.
__global__ void scatter_k(const int* __restrict__ dst, const int* __restrict__ src,
                          const int* __restrict__ cg, int* __restrict__ cur,
                          int* __restrict__ perm, int* __restrict__ srcp,
                          int* __restrict__ cmb, int E, int Nd, int Ns) {
    int e = blockIdx.x * 256 + threadIdx.x;
    if (e < E) {
        int d = dst[e];
        d = d < 0 ? 0 : (d >= Nd ? Nd - 1 : d);
        int p = atomicAdd(&cur[d], 1);
        if (perm) perm[p] = e;
        int si = src[e];
        si = si < 0 ? 0 : (si >= Ns ? Ns - 1 : si);
        srcp[p] = si;
        if (cmb) {
            int a = cg[2 * e] & 7, b = cg[2 * e + 1] & 7;
            cmb[p] = a * 8 + b;
        }
    }
}

// ---------------------------------------------------------------------------
__global__ void gtbl_k(const float* __restrict__ temb, const float* __restrict__ semb,
                       const float* __restrict__ Wg, const float* __restrict__ bg,
                       float* __restrict__ gtbl) {
    int idx = blockIdx.x * 256 + threadIdx.x;
    if (idx >= 8192) return;
    int combo = idx >> 7, c = idx & 127;
    int a = combo >> 3, b = combo & 7;
    float s = bg[c];
    for (int k = 0; k < 32; k++) s += temb[a * 32 + k] * Wg[k * 128 + c];
    for (int k = 0; k < 32; k++) s += semb[b * 32 + k] * Wg[(32 + k) * 128 + c];
    gtbl[combo * 128 + c] = sigm(s);
}

// ---------------------------------------------------------------------------
// Dense kernels: 4 rows per wave, 2 channels per lane, float4 x / float2 W.
#define STEP4(A, XV)                                     \
    A.x += XV.x * w0.x; A.y += XV.x * w0.y;              \
    A.x += XV.y * w1.x; A.y += XV.y * w1.y;              \
    A.x += XV.z * w2.x; A.y += XV.z * w2.y;              \
    A.x += XV.w * w3.x; A.y += XV.w * w3.y;

__global__ __launch_bounds__(256) void hsrow4_k(const float* __restrict__ x, const float* __restrict__ W,
                                                const float* __restrict__ bias, float* __restrict__ hs, int N) {
    int l = threadIdx.x & 63;
    int wv = (blockIdx.x * 256 + threadIdx.x) >> 6;
    int r0 = wv * 4;
    if (r0 >= N) return;
    int c0 = 2 * l;
    float2 bi = *(const float2*)&bias[c0];
    float2 a0 = bi, a1 = bi, a2 = bi, a3 = bi;
    const float4* x4 = (const float4*)x;
    const float2* Wv = (const float2*)W;
    int r1 = min(r0 + 1, N - 1), r2 = min(r0 + 2, N - 1), r3 = min(r0 + 3, N - 1);
    #pragma unroll 4
    for (int kb = 0; kb < 32; kb++) {
        float4 xv0 = x4[(size_t)r0 * 32 + kb];
        float4 xv1 = x4[(size_t)r1 * 32 + kb];
        float4 xv2 = x4[(size_t)r2 * 32 + kb];
        float4 xv3 = x4[(size_t)r3 * 32 + kb];
        float2 w0 = Wv[(4 * kb + 0) * 64 + l];
        float2 w1 = Wv[(4 * kb + 1) * 64 + l];
        float2 w2 = Wv[(4 * kb + 2) * 64 + l];
        float2 w3 = Wv[(4 * kb + 3) * 64 + l];
        STEP4(a0, xv0) STEP4(a1, xv1) STEP4(a2, xv2) STEP4(a3, xv3)
    }
    float2* o = (float2*)hs;
    o[(size_t)r0 * 64 + l] = a0;
    if (r0 + 1 < N) o[(size_t)(r0 + 1) * 64 + l] = a1;
    if (r0 + 2 < N) o[(size_t)(r0 + 2) * 64 + l] = a2;
    if (r0 + 3 < N) o[(size_t)(r0 + 3) * 64 + l] = a3;
}

__global__ __launch_bounds__(256) void adirect4_k(const float* __restrict__ x, const float* __restrict__ Wd,
                                                  const float* __restrict__ bd, const float* __restrict__ attn_t,
                                                  float* __restrict__ ad, int N) {
    int l = threadIdx.x & 63;
    int wv = (blockIdx.x * 256 + threadIdx.x) >> 6;
    int r0 = wv * 4;
    if (r0 >= N) return;
    int c0 = 2 * l;
    float2 bi = *(const float2*)&bd[c0];
    float2 a0 = bi, a1 = bi, a2 = bi, a3 = bi;
    const float4* x4 = (const float4*)x;
    const float2* Wv = (const float2*)Wd;
    int r1 = min(r0 + 1, N - 1), r2 = min(r0 + 2, N - 1), r3 = min(r0 + 3, N - 1);
    #pragma unroll 4
    for (int kb = 0; kb < 32; kb++) {
        float4 xv0 = x4[(size_t)r0 * 32 + kb];
        float4 xv1 = x4[(size_t)r1 * 32 + kb];
        float4 xv2 = x4[(size_t)r2 * 32 + kb];
        float4 xv3 = x4[(size_t)r3 * 32 + kb];
        float2 w0 = Wv[(4 * kb + 0) * 64 + l];
        float2 w1 = Wv[(4 * kb + 1) * 64 + l];
        float2 w2 = Wv[(4 * kb + 2) * 64 + l];
        float2 w3 = Wv[(4 * kb + 3) * 64 + l];
        STEP4(a0, xv0) STEP4(a1, xv1) STEP4(a2, xv2) STEP4(a3, xv3)
    }
    float2 at = *(const float2*)&attn_t[c0];
    int h = l >> 4;
    float t0 = a0.x * at.x + a0.y * at.y;
    float t1 = a1.x * at.x + a1.y * at.y;
    float t2 = a2.x * at.x + a2.y * at.y;
    float t3 = a3.x * at.x + a3.y * at.y;
    t0 += __shfl_xor(t0, 1); t0 += __shfl_xor(t0, 2); t0 += __shfl_xor(t0, 4); t0 += __shfl_xor(t0, 8);
    t1 += __shfl_xor(t1, 1); t1 += __shfl_xor(t1, 2); t1 += __shfl_xor(t1, 4); t1 += __shfl_xor(t1, 8);
    t2 += __shfl_xor(t2, 1); t2 += __shfl_xor(t2, 2); t2 += __shfl_xor(t2, 4); t2 += __shfl_xor(t2, 8);
    t3 += __shfl_xor(t3, 1); t3 += __shfl_xor(t3, 2); t3 += __shfl_xor(t3, 4); t3 += __shfl_xor(t3, 8);
    if ((l & 15) == 0) {
        ad[(size_t)r0 * 4 + h] = t0;
        if (r0 + 1 < N) ad[(size_t)(r0 + 1) * 4 + h] = t1;
        if (r0 + 2 < N) ad[(size_t)(r0 + 2) * 4 + h] = t2;
        if (r0 + 3 < N) ad[(size_t)(r0 + 3) * 4 + h] = t3;
    }
}

// NIN = number of agg inputs (0: bias only, 1: A, 2: A+B)
template <int NIN>
__global__ __launch_bounds__(256) void outrow4_k(const float* __restrict__ A, const float* __restrict__ B,
                                                 const float* __restrict__ Wo, const float* __restrict__ bo,
                                                 float* __restrict__ out, int N) {
    int l = threadIdx.x & 63;
    int wv = (blockIdx.x * 256 + threadIdx.x) >> 6;
    int r0 = wv * 4;
    if (r0 >= N) return;
    int c0 = 2 * l;
    float2 bi = *(const float2*)&bo[c0];
    float2* o = (float2*)out;
    if (NIN == 0) {
        o[(size_t)r0 * 64 + l] = bi;
        if (r0 + 1 < N) o[(size_t)(r0 + 1) * 64 + l] = bi;
        if (r0 + 2 < N) o[(size_t)(r0 + 2) * 64 + l] = bi;
        if (r0 + 3 < N) o[(size_t)(r0 + 3) * 64 + l] = bi;
        return;
    }
    float2 a0 = bi, a1 = bi, a2 = bi, a3 = bi;
    const float4* A4 = (const float4*)A;
    const float4* B4 = (const float4*)B;
    const float2* Wv = (const float2*)Wo;
    int r1 = min(r0 + 1, N - 1), r2 = min(r0 + 2, N - 1), r3 = min(r0 + 3, N - 1);
    #pragma unroll 4
    for (int kb = 0; kb < 32; kb++) {
        float4 xv0 = A4[(size_t)r0 * 32 + kb];
        float4 xv1 = A4[(size_t)r1 * 32 + kb];
        float4 xv2 = A4[(size_t)r2 * 32 + kb];
        float4 xv3 = A4[(size_t)r3 * 32 + kb];
        if (NIN == 2) {
            float4 y0 = B4[(size_t)r0 * 32 + kb];
            float4 y1 = B4[(size_t)r1 * 32 + kb];
            float4 y2 = B4[(size_t)r2 * 32 + kb];
            float4 y3 = B4[(size_t)r3 * 32 + kb];
            xv0.x += y0.x; xv0.y += y0.y; xv0.z += y0.z; xv0.w += y0.w;
            xv1.x += y1.x; xv1.y += y1.y; xv1.z += y1.z; xv1.w += y1.w;
            xv2.x += y2.x; xv2.y += y2.y; xv2.z += y2.z; xv2.w += y2.w;
            xv3.x += y3.x; xv3.y += y3.y; xv3.z += y3.z; xv3.w += y3.w;
        }
        float2 w0 = Wv[(4 * kb + 0) * 64 + l];
        float2 w1 = Wv[(4 * kb + 1) * 64 + l];
        float2 w2 = Wv[(4 * kb + 2) * 64 + l];
        float2 w3 = Wv[(4 * kb + 3) * 64 + l];
        STEP4(a0, xv0) STEP4(a1, xv1) STEP4(a2, xv2) STEP4(a3, xv3)
    }
    o[(size_t)r0 * 64 + l] = a0;
    if (r0 + 1 < N) o[(size_t)(r0 + 1) * 64 + l] = a1;
    if (r0 + 2 < N) o[(size_t)(r0 + 2) * 64 + l] = a2;
    if (r0 + 3 < N) o[(size_t)(r0 + 3) * 64 + l] = a3;
}

// ---------------------------------------------------------------------------
// t2 gate precompute, perm-order chunk [starts[j0], starts[j1]).
__global__ __launch_bounds__(256) void gate_k(const float* __restrict__ cp,
                                              const float* __restrict__ W1c, const float* __restrict__ b1c,
                                              const float* __restrict__ W2c, const float* __restrict__ b2c,
                                              const int* __restrict__ perm, const int* __restrict__ starts,
                                              u16* __restrict__ gate,
                                              int j0, int j1, int NP_, int E, int CAP) {
    __shared__ __align__(16) u16 u_sh[256];
    int c = threadIdx.x & 127;
    int slot = threadIdx.x >> 7;
    int q0 = starts[j0];
    int q1 = (j1 >= NP_) ? E : starts[j1];
    int npairs = (q1 - q0 + 1) >> 1;
    h2_t w2r[64];
    #pragma unroll
    for (int kk = 0; kk < 64; kk++) {
        h2_t w;
        w.x = (_Float16)W2c[(2 * kk) * 128 + c];
        w.y = (_Float16)W2c[(2 * kk + 1) * 128 + c];
        w2r[kk] = w;
    }
    float w1a = W1c[c], w1b = W1c[128 + c], w1cc = W1c[256 + c];
    float b1 = b1c[c], b2 = b2c[c];
    const uint4* u4 = (const uint4*)u_sh;
    for (int it = blockIdx.x; it < npairs; it += gridDim.x) {
        int q = q0 + it * 2 + slot;
        bool act = q < q1;
        if (act) {
            int e = __builtin_amdgcn_readfirstlane(perm[q]);
            float p0 = cp[(size_t)e * 3 + 0];
            float p1 = cp[(size_t)e * 3 + 1];
            float p2 = cp[(size_t)e * 3 + 2];
            float z = b1 + p0 * w1a + p1 * w1b + p2 * w1cc;
            float u = 0.5f * z * (1.f + erff(z * 0.70710678118654752f));
            HSU cv; cv.f = (_Float16)u;
            u_sh[slot * 128 + c] = cv.s;
        }
        __syncthreads();
        if (act) {
            float acc = b2;
            #pragma unroll
            for (int t = 0; t < 16; t++) {
                uint4 uv = u4[slot * 16 + t];
                H2U x0, x1, x2, x3;
                x0.u = uv.x; x1.u = uv.y; x2.u = uv.z; x3.u = uv.w;
                acc = FDOT2(x0.h, w2r[4 * t + 0], acc);
                acc = FDOT2(x1.h, w2r[4 * t + 1], acc);
                acc = FDOT2(x2.h, w2r[4 * t + 2], acc);
                acc = FDOT2(x3.h, w2r[4 * t + 3], acc);
            }
            float g = sigm(acc);
            int qrel = q - q0;
            if (qrel < CAP) {
                HSU cv2; cv2.f = (_Float16)g;
                gate[(size_t)qrel * 128 + c] = cv2.s;
            }
        }
        __syncthreads();
    }
}

// ---------------------------------------------------------------------------
// Gather aggregation: FOUR destinations per wave (4 independent load chains
// in flight). MODE 0: plain. MODE 1: gate table via cmb. MODE 3: f16 gate.
// Exact online softmax per destination (running max, rescale on new max).
#define AGG_LOAD(K)                                                          \
    float2 hv##K; float2 gv##K; unsigned gu##K = 0;                          \
    if (q < dn##K) {                                                         \
        int si = srcp[st##K + q];                                            \
        hv##K = hs2v[(size_t)si * 64 + lane];                                \
        if (MODE == 1) { int ab = cmb[st##K + q]; gv##K = gt2v[ab * 64 + lane]; } \
        if (MODE == 3) { int qq = st##K + q - q0base;                        \
                         qq = qq < 79999 ? qq : 79999;                       \
                         gu##K = g32[(size_t)qq * 64 + lane]; }              \
    }

#define AGG_UPD(K)                                                           \
    if (q < dn##K) {                                                         \
        float mx = hv##K.x, my = hv##K.y;                                    \
        if (MODE == 1) { mx *= gv##K.x; my *= gv##K.y; }                     \
        if (MODE == 3) { H2U gz; gz.u = gu##K; mx *= (float)gz.h.x; my *= (float)gz.h.y; } \
        float p = mx * ax + my * ay;                                         \
        p += __shfl_xor(p, 1); p += __shfl_xor(p, 2);                        \
        p += __shfl_xor(p, 4); p += __shfl_xor(p, 8);                        \
        float logit = p + adv##K;                                            \
        logit = logit > 0.f ? logit : 0.2f * logit;                          \
        if (logit > mm##K) {                                                 \
            float r = expf(mm##K - logit);                                   \
            ss##K *= r; vx##K *= r; vy##K *= r; mm##K = logit;               \
        }                                                                    \
        float ex = expf(logit - mm##K);                                      \
        ss##K += ex; vx##K += ex * mx; vy##K += ex * my;                     \
    }

#define AGG_OUT(K, JJ, ACT)                                                  \
    if (ACT) {                                                               \
        float inv = ss##K > 0.f ? 1.f / ss##K : 0.f;                         \
        float2 o; o.x = vx##K * inv; o.y = vy##K * inv;                      \
        agg2v[(size_t)(JJ) * 64 + lane] = o;                                 \
    }

template <int MODE>
__global__ __launch_bounds__(256) void agg_k(const float* __restrict__ hs,
                                             const float* __restrict__ ad,
                                             const int* __restrict__ srcp,
                                             const int* __restrict__ cmb,
                                             const int* __restrict__ starts,
                                             const int* __restrict__ deg,
                                             const float* __restrict__ attn_t,
                                             const float* __restrict__ gtbl,
                                             const u16* __restrict__ gate,
                                             float* __restrict__ agg,
                                             int j0, int j1) {
    int lane = threadIdx.x & 63;
    int gw = (blockIdx.x * 256 + threadIdx.x) >> 6;
    int nw = gridDim.x * 4;
    int c0 = 2 * lane;
    float ax = attn_t[c0], ay = attn_t[c0 + 1];
    int h = lane >> 4;
    const float2* hs2v = (const float2*)hs;
    const float2* gt2v = (const float2*)gtbl;
    const unsigned* g32 = (const unsigned*)gate;
    float2* agg2v = (float2*)agg;
    int q0base = 0;
    if (MODE == 3) q0base = __builtin_amdgcn_readfirstlane(starts[j0]);
    for (int jb = j0 + gw * 4; jb < j1; jb += nw * 4) {
        bool a1 = jb + 1 < j1, a2 = jb + 2 < j1, a3 = jb + 3 < j1;
        int st0 = __builtin_amdgcn_readfirstlane(starts[jb]);
        int dn0 = __builtin_amdgcn_readfirstlane(deg[jb]);
        int st1 = 0, dn1 = 0, st2 = 0, dn2 = 0, st3 = 0, dn3 = 0;
        if (a1) { st1 = __builtin_amdgcn_readfirstlane(starts[jb + 1]);
                  dn1 = __builtin_amdgcn_readfirstlane(deg[jb + 1]); }
        if (a2) { st2 = __builtin_amdgcn_readfirstlane(starts[jb + 2]);
                  dn2 = __builtin_amdgcn_readfirstlane(deg[jb + 2]); }
        if (a3) { st3 = __builtin_amdgcn_readfirstlane(starts[jb + 3]);
                  dn3 = __builtin_amdgcn_readfirstlane(deg[jb + 3]); }
        int nmax = max(max(dn0, dn1), max(dn2, dn3));
        float adv0 = ad[(size_t)jb * 4 + h];
        float adv1 = a1 ? ad[(size_t)(jb + 1) * 4 + h] : 0.f;
        float adv2 = a2 ? ad[(size_t)(jb + 2) * 4 + h] : 0.f;
        float adv3 = a3 ? ad[(size_t)(jb + 3) * 4 + h] : 0.f;
        float mm0 = -3.0e38f, ss0 = 0.f, vx0 = 0.f, vy0 = 0.f;
        float mm1 = -3.0e38f, ss1 = 0.f, vx1 = 0.f, vy1 = 0.f;
        float mm2 = -3.0e38f, ss2 = 0.f, vx2 = 0.f, vy2 = 0.f;
        float mm3 = -3.0e38f, ss3 = 0.f, vx3 = 0.f, vy3 = 0.f;
        for (int q = 0; q < nmax; q++) {
            AGG_LOAD(0) AGG_LOAD(1) AGG_LOAD(2) AGG_LOAD(3)
            AGG_UPD(0) AGG_UPD(1) AGG_UPD(2) AGG_UPD(3)
        }
        AGG_OUT(0, jb, true)
        AGG_OUT(1, jb + 1, a1)
        AGG_OUT(2, jb + 2, a2)
        AGG_OUT(3, jb + 3, a3)
    }
}

// ---------------------------------------------------------------------------
extern "C" void kernel_launch(void* const* d_in, const int* in_sizes, int n_in,
                              void* d_out, int out_size, void* d_ws, size_t ws_size,
                              hipStream_t stream) {
    static const int expect[29] = {
        6400000, 3840000, 1280000, 640000,
        500000, 500000, 500000, 500000, 250000, 250000, 250000, 250000,
        1000000, 750000, 65536, 512, 65536, 512, 512, 320, 256,
        8192, 128, 384, 128, 16384, 128, 65536, 512};
    int bad = 0;
    if (n_in != 29) bad = 1;
    else {
        for (int i = 0; i < 29; i++)
            if (in_sizes[i] != expect[i]) { bad = 4 + i; break; }
    }
    if (!bad && out_size != 12160000) bad = 2;
    if (!bad && ws_size < (size_t)63425536) bad = 3;
    if (bad) {
        senthost_k<<<1, 1, 0, stream>>>((float*)d_out, 4096.f * (float)bad);
        return;
    }

    const float* x_chem = (const float*)d_in[0];
    const float* x_gene = (const float*)d_in[1];
    const float* x_dis  = (const float*)d_in[2];
    const float* x_path = (const float*)d_in[3];
    const int* src0 = (const int*)d_in[4];  const int* dst0 = (const int*)d_in[5];
    const int* src1 = (const int*)d_in[6];  const int* dst1 = (const int*)d_in[7];
    const int* src2 = (const int*)d_in[8];  const int* dst2 = (const int*)d_in[9];
    const int* src3 = (const int*)d_in[10]; const int* dst3 = (const int*)d_in[11];
    const int*   cg   = (const int*)d_in[12];
    const float* cp   = (const float*)d_in[13];
    const float* Wsrc = (const float*)d_in[14]; const float* bsrc = (const float*)d_in[15];
    const float* Wdst = (const float*)d_in[16]; const float* bdst = (const float*)d_in[17];
    const float* attn = (const float*)d_in[18];
    const float* temb = (const float*)d_in[19]; const float* semb = (const float*)d_in[20];
    const float* Wg   = (const float*)d_in[21]; const float* bg   = (const float*)d_in[22];
    const float* W1c  = (const float*)d_in[23]; const float* b1c  = (const float*)d_in[24];
    const float* W2c  = (const float*)d_in[25]; const float* b2c  = (const float*)d_in[26];
    const float* Wout = (const float*)d_in[27]; const float* bout = (const float*)d_in[28];

    constexpr int NC = 50000, NG = 30000, ND = 10000, NP = 5000;
    constexpr int E0 = 500000, E1 = 500000, E2 = 250000, E3 = 250000;
    constexpr int GCAP = 80000;

    char* ws = (char*)d_ws;
    float* gt   = (float*)ws;              // [64][128] f32 = 32768 B
    int*   csum = (int*)(ws + 32768);      // chunk sums for scan (<=49 ints)
    char*  A    = ws + 65536;              // stage arena (<= 63,360,000 B)

    float* out = (float*)d_out;
    float* out_chem = out;
    float* out_gene = out + (size_t)NC * 128;
    float* out_dis  = out + (size_t)(NC + NG) * 128;
    float* out_path = out + (size_t)(NC + NG + ND) * 128;

    gtbl_k<<<32, 256, 0, stream>>>(temb, semb, Wg, bg, gt);

    // ---------- STAGE A: chemical output (t1: gene -> chemical) ----------
    {
        float* hs1  = (float*)(A);                 //  0 .. 15,360,000
        float* ad1  = (float*)(A + 15360000);      // .. 16,160,000
        int*   deg  = (int*)  (A + 16160000);      // .. 16,360,000
        int*   sts  = (int*)  (A + 16360000);      // .. 16,560,000
        int*   cur  = (int*)  (A + 16560000);      // .. 16,760,000
        int*   srcpA = (int*) (A + 16760000);      // .. 18,760,000
        float* agg1 = (float*)(A + 18760000);      // .. 44,360,000
        int nch = (NC + 1023) / 1024;
        zero_k<<<(NC + 255) / 256, 256, 0, stream>>>((float*)deg, NC);
        hist_k<<<(E1 + 255) / 256, 256, 0, stream>>>(dst1, deg, E1, NC);
        scan1_k<<<nch, 256, 0, stream>>>(deg, csum, NC);
        scan2_k<<<1, 64, 0, stream>>>(csum, nch);
        scan3_k<<<nch, 256, 0, stream>>>(deg, csum, sts, cur, NC);
        scatter_k<<<(E1 + 255) / 256, 256, 0, stream>>>(dst1, src1, nullptr, cur,
                                                        nullptr, srcpA, nullptr, E1, NC, NG);
        hsrow4_k<<<(NG + 15) / 16, 256, 0, stream>>>(x_gene, Wsrc + 1 * 16384, bsrc + 1 * 128, hs1, NG);
        adirect4_k<<<(NC + 15) / 16, 256, 0, stream>>>(x_chem, Wdst + 1 * 16384, bdst + 1 * 128, attn + 1 * 128, ad1, NC);
        agg_k<0><<<3125, 256, 0, stream>>>(hs1, ad1, srcpA, nullptr, sts, deg,
                                           attn + 1 * 128, nullptr, nullptr, agg1, 0, NC);
        outrow4_k<1><<<(NC + 15) / 16, 256, 0, stream>>>(agg1, nullptr,
                                                         Wout + 0 * 16384, bout + 0 * 128, out_chem, NC);
    }

    // ---------- STAGE B: pathway output (t2: chemical -> pathway) ----------
    {
        float* hs2  = (float*)(A);                 //  0 .. 25,600,000
        float* ad2  = (float*)(A + 25600000);      // .. 25,680,000
        int*   deg  = (int*)  (A + 25680000);      // .. 25,700,000
        int*   sts  = (int*)  (A + 25700000);      // .. 25,720,000
        int*   cur  = (int*)  (A + 25720000);      // .. 25,740,000
        int*   perm = (int*)  (A + 25740000);      // .. 26,740,000
        int*   srcpB = (int*) (A + 26740000);      // .. 27,740,000
        float* agg2 = (float*)(A + 27740000);      // .. 30,300,000
        u16*   gatep = (u16*) (A + 30300000);      // .. 50,780,000
        int nch = (NP + 1023) / 1024;
        zero_k<<<(NP + 255) / 256, 256, 0, stream>>>((float*)deg, NP);
        hist_k<<<(E2 + 255) / 256, 256, 0, stream>>>(dst2, deg, E2, NP);
        scan1_k<<<nch, 256, 0, stream>>>(deg, csum, NP);
        scan2_k<<<1, 64, 0, stream>>>(csum, nch);
        scan3_k<<<nch, 256, 0, stream>>>(deg, csum, sts, cur, NP);
        scatter_k<<<(E2 + 255) / 256, 256, 0, stream>>>(dst2, src2, nullptr, cur,
                                                        perm, srcpB, nullptr, E2, NP, NC);
        hsrow4_k<<<(NC + 15) / 16, 256, 0, stream>>>(x_chem, Wsrc + 2 * 16384, bsrc + 2 * 128, hs2, NC);
        adirect4_k<<<(NP + 15) / 16, 256, 0, stream>>>(x_path, Wdst + 2 * 16384, bdst + 2 * 128, attn + 2 * 128, ad2, NP);
        for (int ck = 0; ck < 4; ck++) {
            int j0 = ck * 1250, j1 = j0 + 1250;
            gate_k<<<1024, 256, 0, stream>>>(cp, W1c, b1c, W2c, b2c, perm, sts, gatep,
                                             j0, j1, NP, E2, GCAP);
            agg_k<3><<<79, 256, 0, stream>>>(hs2, ad2, srcpB, nullptr, sts, deg,
                                             attn + 2 * 128, nullptr, gatep, agg2, j0, j1);
        }
        outrow4_k<1><<<(NP + 15) / 16, 256, 0, stream>>>(agg2, nullptr,
                                                         Wout + 3 * 16384, bout + 3 * 128, out_path, NP);
    }

    // ---------- STAGE C: gene output (t0 + t3, sequential buffer reuse) -----
    {
        float* ad0  = (float*)(A + 25600000);      // .. 26,080,000
        float* ad3  = (float*)(A + 26080000);      // .. 26,560,000 (survives)
        int*   deg  = (int*)  (A + 26560000);      // .. 26,680,000
        int*   sts  = (int*)  (A + 26680000);      // .. 26,800,000
        int*   cur  = (int*)  (A + 26800000);      // .. 26,920,000
        int*   srcpC = (int*) (A + 26920000);      // .. 28,920,000
        int*   cmbp = (int*)  (A + 28920000);      // .. 30,920,000
        float* agg0 = (float*)(A + 30920000);      // .. 46,280,000
        float* agg3 = (float*)(A + 46280000);      // .. 61,640,000
        int nch = (NG + 1023) / 1024;

        // phase 1: t0 chemical -> gene (categorical gate)
        float* hs0 = (float*)(A);                  //  0 .. 25,600,000
        zero_k<<<(NG + 255) / 256, 256, 0, stream>>>((float*)deg, NG);
        hist_k<<<(E0 + 255) / 256, 256, 0, stream>>>(dst0, deg, E0, NG);
        scan1_k<<<nch, 256, 0, stream>>>(deg, csum, NG);
        scan2_k<<<1, 64, 0, stream>>>(csum, nch);
        scan3_k<<<nch, 256, 0, stream>>>(deg, csum, sts, cur, NG);
        scatter_k<<<(E0 + 255) / 256, 256, 0, stream>>>(dst0, src0, cg, cur,
                                                        nullptr, srcpC, cmbp, E0, NG, NC);
        hsrow4_k<<<(NC + 15) / 16, 256, 0, stream>>>(x_chem, Wsrc + 0 * 16384, bsrc + 0 * 128, hs0, NC);
        adirect4_k<<<(NG + 15) / 16, 256, 0, stream>>>(x_gene, Wdst + 0 * 16384, bdst + 0 * 128, attn + 0 * 128, ad0, NG);
        adirect4_k<<<(NG + 15) / 16, 256, 0, stream>>>(x_gene, Wdst + 3 * 16384, bdst + 3 * 128, attn + 3 * 128, ad3, NG);
        agg_k<1><<<1875, 256, 0, stream>>>(hs0, ad0, srcpC, cmbp, sts, deg,
                                           attn + 0 * 128, gt, nullptr, agg0, 0, NG);

        // phase 2: t3 disease -> gene (plain), reusing hs/CSR buffers
        float* hs3 = (float*)(A);                  //  0 .. 5,120,000
        zero_k<<<(NG + 255) / 256, 256, 0, stream>>>((float*)deg, NG);
        hist_k<<<(E3 + 255) / 256, 256, 0, stream>>>(dst3, deg, E3, NG);
        scan1_k<<<nch, 256, 0, stream>>>(deg, csum, NG);
        scan2_k<<<1, 64, 0, stream>>>(csum, nch);
        scan3_k<<<nch, 256, 0, stream>>>(deg, csum, sts, cur, NG);
        scatter_k<<<(E3 + 255) / 256, 256, 0, stream>>>(dst3, src3, nullptr, cur,
                                                        nullptr, srcpC, nullptr, E3, NG, ND);
        hsrow4_k<<<(ND + 15) / 16, 256, 0, stream>>>(x_dis, Wsrc + 3 * 16384, bsrc + 3 * 128, hs3, ND);
        agg_k<0><<<1875, 256, 0, stream>>>(hs3, ad3, srcpC, nullptr, sts, deg,
                                           attn + 3 * 128, nullptr, nullptr, agg3, 0, NG);
        outrow4_k<2><<<(NG + 15) / 16, 256, 0, stream>>>(agg0, agg3,
                                                         Wout + 1 * 16384, bout + 1 * 128, out_gene, NG);
    }

    // ---------- STAGE D: disease output (no incoming edges: bias only) ------
    outrow4_k<0><<<(ND + 15) / 16, 256, 0, stream>>>(nullptr, nullptr,
                                                     Wout + 2 * 16384, bout + 2 * 128, out_dis, ND);
}

// Round 7
// 1665.988 us; speedup vs baseline: 1.3672x; 1.3672x over previous
//
#include <hip/hip_runtime.h>

// EdgeAttrHeteroConv — round 14. R13 = 2278 us, a REGRESSION vs R11's 1839:
// agg_k<3> (stage B) at 4-dests/wave x grid 79 = 316 waves total -> 2.9%
// occupancy, 166 us x 4 chunks = 664 us (latency fully exposed). R14 keeps
// the de-indirected CSR payloads (srcp/cmb) but batches MLP at the EDGE level:
// one wave per destination, 4 independent edge loads per iteration (loads
// batched, online-softmax update serial). Same 4-deep MLP, 4x the waves
// (1250/chunk for B, 30-50K for t0/t1), no nmax imbalance, fewer VGPRs.
// Math and per-destination edge order bit-identical to R11/R13 (absmax
// 1.95e-3 both). Dense kernels + CSR build + gate_k unchanged from R13.

typedef unsigned short u16;
typedef _Float16 h2_t __attribute__((ext_vector_type(2)));
union H2U { unsigned u; h2_t h; };
union HSU { _Float16 f; unsigned short s; };

#if __has_builtin(__builtin_amdgcn_fdot2)
#define FDOT2(a, b, c) __builtin_amdgcn_fdot2((a), (b), (c), false)
#else
#define FDOT2(a, b, c) ((c) + (float)(a).x * (float)(b).x + (float)(a).y * (float)(b).y)
#endif

__device__ __forceinline__ float sigm(float x) { return 1.f / (1.f + expf(-x)); }

// ---------------------------------------------------------------------------
__global__ void zero_k(float* __restrict__ p, int n) {
    int i = blockIdx.x * 256 + threadIdx.x;
    if (i < n) p[i] = 0.f;
}

__global__ void senthost_k(float* out, float v) { out[0] = v; }

// ---------------------------------------------------------------------------
// CSR build: histogram -> 3-kernel exclusive scan (1024-elem chunks) -> scatter
__global__ void hist_k(const int* __restrict__ dst, int* __restrict__ deg, int E, int Nd) {
    int e = blockIdx.x * 256 + threadIdx.x;
    if (e < E) {
        int d = dst[e];
        d = d < 0 ? 0 : (d >= Nd ? Nd - 1 : d);
        atomicAdd(&deg[d], 1);
    }
}

__global__ void scan1_k(const int* __restrict__ deg, int* __restrict__ csum, int Nd) {
    __shared__ int red[256];
    int base = blockIdx.x * 1024;
    int t = threadIdx.x;
    int s = 0;
    for (int i = 0; i < 4; i++) {
        int idx = base + t * 4 + i;
        if (idx < Nd) s += deg[idx];
    }
    red[t] = s;
    __syncthreads();
    for (int off = 128; off > 0; off >>= 1) {
        if (t < off) red[t] += red[t + off];
        __syncthreads();
    }
    if (t == 0) csum[blockIdx.x] = red[0];
}

__global__ void scan2_k(int* __restrict__ csum, int nch) {
    if (threadIdx.x == 0) {
        int acc = 0;
        for (int i = 0; i < nch; i++) { int v = csum[i]; csum[i] = acc; acc += v; }
    }
}

__global__ void scan3_k(const int* __restrict__ deg, const int* __restrict__ csum,
                        int* __restrict__ starts, int* __restrict__ cur, int Nd) {
    __shared__ int sc[256];
    int base = blockIdx.x * 1024;
    int t = threadIdx.x;
    int v[4];
    int s = 0;
    for (int i = 0; i < 4; i++) {
        int idx = base + t * 4 + i;
        v[i] = idx < Nd ? deg[idx] : 0;
        s += v[i];
    }
    sc[t] = s;
    __syncthreads();
    for (int off = 1; off < 256; off <<= 1) {           // Hillis-Steele inclusive
        int add = (t >= off) ? sc[t - off] : 0;
        __syncthreads();
        sc[t] += add;
        __syncthreads();
    }
    int excl = sc[t] - s + csum[blockIdx.x];
    for (int i = 0; i < 4; i++) {
        int idx = base + t * 4 + i;
        if (idx < Nd) { starts[idx] = excl; cur[idx] = excl; excl += v[i]; }
    }
}

// scatter: build CSR payloads directly. perm (edge id) only if needed (t2),
// srcp = clamped source index always, cmb = packed gate combo if cg given.
__global__ void scatter_k(const int* __restrict__ dst, const int* __restrict__ src,
                          const int* __restrict__ cg, int* __restrict__ cur,
                          int* __restrict__ perm, int* __restrict__ srcp,
                          int* __restrict__ cmb, int E, int Nd, int Ns) {
    int e = blockIdx.x * 256 + threadIdx.x;
    if (e < E) {
        int d = dst[e];
        d = d < 0 ? 0 : (d >= Nd ? Nd - 1 : d);
        int p = atomicAdd(&cur[d], 1);
        if (perm) perm[p] = e;
        int si = src[e];
        si = si < 0 ? 0 : (si >= Ns ? Ns - 1 : si);
        srcp[p] = si;
        if (cmb) {
            int a = cg[2 * e] & 7, b = cg[2 * e + 1] & 7;
            cmb[p] = a * 8 + b;
        }
    }
}

// ---------------------------------------------------------------------------
__global__ void gtbl_k(const float* __restrict__ temb, const float* __restrict__ semb,
                       const float* __restrict__ Wg, const float* __restrict__ bg,
                       float* __restrict__ gtbl) {
    int idx = blockIdx.x * 256 + threadIdx.x;
    if (idx >= 8192) return;
    int combo = idx >> 7, c = idx & 127;
    int a = combo >> 3, b = combo & 7;
    float s = bg[c];
    for (int k = 0; k < 32; k++) s += temb[a * 32 + k] * Wg[k * 128 + c];
    for (int k = 0; k < 32; k++) s += semb[b * 32 + k] * Wg[(32 + k) * 128 + c];
    gtbl[combo * 128 + c] = sigm(s);
}

// ---------------------------------------------------------------------------
// Dense kernels: 4 rows per wave, 2 channels per lane, float4 x / float2 W.
#define STEP4(A, XV)                                     \
    A.x += XV.x * w0.x; A.y += XV.x * w0.y;              \
    A.x += XV.y * w1.x; A.y += XV.y * w1.y;              \
    A.x += XV.z * w2.x; A.y += XV.z * w2.y;              \
    A.x += XV.w * w3.x; A.y += XV.w * w3.y;

__global__ __launch_bounds__(256) void hsrow4_k(const float* __restrict__ x, const float* __restrict__ W,
                                                const float* __restrict__ bias, float* __restrict__ hs, int N) {
    int l = threadIdx.x & 63;
    int wv = (blockIdx.x * 256 + threadIdx.x) >> 6;
    int r0 = wv * 4;
    if (r0 >= N) return;
    int c0 = 2 * l;
    float2 bi = *(const float2*)&bias[c0];
    float2 a0 = bi, a1 = bi, a2 = bi, a3 = bi;
    const float4* x4 = (const float4*)x;
    const float2* Wv = (const float2*)W;
    int r1 = min(r0 + 1, N - 1), r2 = min(r0 + 2, N - 1), r3 = min(r0 + 3, N - 1);
    #pragma unroll 4
    for (int kb = 0; kb < 32; kb++) {
        float4 xv0 = x4[(size_t)r0 * 32 + kb];
        float4 xv1 = x4[(size_t)r1 * 32 + kb];
        float4 xv2 = x4[(size_t)r2 * 32 + kb];
        float4 xv3 = x4[(size_t)r3 * 32 + kb];
        float2 w0 = Wv[(4 * kb + 0) * 64 + l];
        float2 w1 = Wv[(4 * kb + 1) * 64 + l];
        float2 w2 = Wv[(4 * kb + 2) * 64 + l];
        float2 w3 = Wv[(4 * kb + 3) * 64 + l];
        STEP4(a0, xv0) STEP4(a1, xv1) STEP4(a2, xv2) STEP4(a3, xv3)
    }
    float2* o = (float2*)hs;
    o[(size_t)r0 * 64 + l] = a0;
    if (r0 + 1 < N) o[(size_t)(r0 + 1) * 64 + l] = a1;
    if (r0 + 2 < N) o[(size_t)(r0 + 2) * 64 + l] = a2;
    if (r0 + 3 < N) o[(size_t)(r0 + 3) * 64 + l] = a3;
}

__global__ __launch_bounds__(256) void adirect4_k(const float* __restrict__ x, const float* __restrict__ Wd,
                                                  const float* __restrict__ bd, const float* __restrict__ attn_t,
                                                  float* __restrict__ ad, int N) {
    int l = threadIdx.x & 63;
    int wv = (blockIdx.x * 256 + threadIdx.x) >> 6;
    int r0 = wv * 4;
    if (r0 >= N) return;
    int c0 = 2 * l;
    float2 bi = *(const float2*)&bd[c0];
    float2 a0 = bi, a1 = bi, a2 = bi, a3 = bi;
    const float4* x4 = (const float4*)x;
    const float2* Wv = (const float2*)Wd;
    int r1 = min(r0 + 1, N - 1), r2 = min(r0 + 2, N - 1), r3 = min(r0 + 3, N - 1);
    #pragma unroll 4
    for (int kb = 0; kb < 32; kb++) {
        float4 xv0 = x4[(size_t)r0 * 32 + kb];
        float4 xv1 = x4[(size_t)r1 * 32 + kb];
        float4 xv2 = x4[(size_t)r2 * 32 + kb];
        float4 xv3 = x4[(size_t)r3 * 32 + kb];
        float2 w0 = Wv[(4 * kb + 0) * 64 + l];
        float2 w1 = Wv[(4 * kb + 1) * 64 + l];
        float2 w2 = Wv[(4 * kb + 2) * 64 + l];
        float2 w3 = Wv[(4 * kb + 3) * 64 + l];
        STEP4(a0, xv0) STEP4(a1, xv1) STEP4(a2, xv2) STEP4(a3, xv3)
    }
    float2 at = *(const float2*)&attn_t[c0];
    int h = l >> 4;
    float t0 = a0.x * at.x + a0.y * at.y;
    float t1 = a1.x * at.x + a1.y * at.y;
    float t2 = a2.x * at.x + a2.y * at.y;
    float t3 = a3.x * at.x + a3.y * at.y;
    t0 += __shfl_xor(t0, 1); t0 += __shfl_xor(t0, 2); t0 += __shfl_xor(t0, 4); t0 += __shfl_xor(t0, 8);
    t1 += __shfl_xor(t1, 1); t1 += __shfl_xor(t1, 2); t1 += __shfl_xor(t1, 4); t1 += __shfl_xor(t1, 8);
    t2 += __shfl_xor(t2, 1); t2 += __shfl_xor(t2, 2); t2 += __shfl_xor(t2, 4); t2 += __shfl_xor(t2, 8);
    t3 += __shfl_xor(t3, 1); t3 += __shfl_xor(t3, 2); t3 += __shfl_xor(t3, 4); t3 += __shfl_xor(t3, 8);
    if ((l & 15) == 0) {
        ad[(size_t)r0 * 4 + h] = t0;
        if (r0 + 1 < N) ad[(size_t)(r0 + 1) * 4 + h] = t1;
        if (r0 + 2 < N) ad[(size_t)(r0 + 2) * 4 + h] = t2;
        if (r0 + 3 < N) ad[(size_t)(r0 + 3) * 4 + h] = t3;
    }
}

// NIN = number of agg inputs (0: bias only, 1: A, 2: A+B)
template <int NIN>
__global__ __launch_bounds__(256) void outrow4_k(const float* __restrict__ A, const float* __restrict__ B,
                                                 const float* __restrict__ Wo, const float* __restrict__ bo,
                                                 float* __restrict__ out, int N) {
    int l = threadIdx.x & 63;
    int wv = (blockIdx.x * 256 + threadIdx.x) >> 6;
    int r0 = wv * 4;
    if (r0 >= N) return;
    int c0 = 2 * l;
    float2 bi = *(const float2*)&bo[c0];
    float2* o = (float2*)out;
    if (NIN == 0) {
        o[(size_t)r0 * 64 + l] = bi;
        if (r0 + 1 < N) o[(size_t)(r0 + 1) * 64 + l] = bi;
        if (r0 + 2 < N) o[(size_t)(r0 + 2) * 64 + l] = bi;
        if (r0 + 3 < N) o[(size_t)(r0 + 3) * 64 + l] = bi;
        return;
    }
    float2 a0 = bi, a1 = bi, a2 = bi, a3 = bi;
    const float4* A4 = (const float4*)A;
    const float4* B4 = (const float4*)B;
    const float2* Wv = (const float2*)Wo;
    int r1 = min(r0 + 1, N - 1), r2 = min(r0 + 2, N - 1), r3 = min(r0 + 3, N - 1);
    #pragma unroll 4
    for (int kb = 0; kb < 32; kb++) {
        float4 xv0 = A4[(size_t)r0 * 32 + kb];
        float4 xv1 = A4[(size_t)r1 * 32 + kb];
        float4 xv2 = A4[(size_t)r2 * 32 + kb];
        float4 xv3 = A4[(size_t)r3 * 32 + kb];
        if (NIN == 2) {
            float4 y0 = B4[(size_t)r0 * 32 + kb];
            float4 y1 = B4[(size_t)r1 * 32 + kb];
            float4 y2 = B4[(size_t)r2 * 32 + kb];
            float4 y3 = B4[(size_t)r3 * 32 + kb];
            xv0.x += y0.x; xv0.y += y0.y; xv0.z += y0.z; xv0.w += y0.w;
            xv1.x += y1.x; xv1.y += y1.y; xv1.z += y1.z; xv1.w += y1.w;
            xv2.x += y2.x; xv2.y += y2.y; xv2.z += y2.z; xv2.w += y2.w;
            xv3.x += y3.x; xv3.y += y3.y; xv3.z += y3.z; xv3.w += y3.w;
        }
        float2 w0 = Wv[(4 * kb + 0) * 64 + l];
        float2 w1 = Wv[(4 * kb + 1) * 64 + l];
        float2 w2 = Wv[(4 * kb + 2) * 64 + l];
        float2 w3 = Wv[(4 * kb + 3) * 64 + l];
        STEP4(a0, xv0) STEP4(a1, xv1) STEP4(a2, xv2) STEP4(a3, xv3)
    }
    o[(size_t)r0 * 64 + l] = a0;
    if (r0 + 1 < N) o[(size_t)(r0 + 1) * 64 + l] = a1;
    if (r0 + 2 < N) o[(size_t)(r0 + 2) * 64 + l] = a2;
    if (r0 + 3 < N) o[(size_t)(r0 + 3) * 64 + l] = a3;
}

// ---------------------------------------------------------------------------
// t2 gate precompute, perm-order chunk [starts[j0], starts[j1]).
__global__ __launch_bounds__(256) void gate_k(const float* __restrict__ cp,
                                              const float* __restrict__ W1c, const float* __restrict__ b1c,
                                              const float* __restrict__ W2c, const float* __restrict__ b2c,
                                              const int* __restrict__ perm, const int* __restrict__ starts,
                                              u16* __restrict__ gate,
                                              int j0, int j1, int NP_, int E, int CAP) {
    __shared__ __align__(16) u16 u_sh[256];
    int c = threadIdx.x & 127;
    int slot = threadIdx.x >> 7;
    int q0 = starts[j0];
    int q1 = (j1 >= NP_) ? E : starts[j1];
    int npairs = (q1 - q0 + 1) >> 1;
    h2_t w2r[64];
    #pragma unroll
    for (int kk = 0; kk < 64; kk++) {
        h2_t w;
        w.x = (_Float16)W2c[(2 * kk) * 128 + c];
        w.y = (_Float16)W2c[(2 * kk + 1) * 128 + c];
        w2r[kk] = w;
    }
    float w1a = W1c[c], w1b = W1c[128 + c], w1cc = W1c[256 + c];
    float b1 = b1c[c], b2 = b2c[c];
    const uint4* u4 = (const uint4*)u_sh;
    for (int it = blockIdx.x; it < npairs; it += gridDim.x) {
        int q = q0 + it * 2 + slot;
        bool act = q < q1;
        if (act) {
            int e = __builtin_amdgcn_readfirstlane(perm[q]);
            float p0 = cp[(size_t)e * 3 + 0];
            float p1 = cp[(size_t)e * 3 + 1];
            float p2 = cp[(size_t)e * 3 + 2];
            float z = b1 + p0 * w1a + p1 * w1b + p2 * w1cc;
            float u = 0.5f * z * (1.f + erff(z * 0.70710678118654752f));
            HSU cv; cv.f = (_Float16)u;
            u_sh[slot * 128 + c] = cv.s;
        }
        __syncthreads();
        if (act) {
            float acc = b2;
            #pragma unroll
            for (int t = 0; t < 16; t++) {
                uint4 uv = u4[slot * 16 + t];
                H2U x0, x1, x2, x3;
                x0.u = uv.x; x1.u = uv.y; x2.u = uv.z; x3.u = uv.w;
                acc = FDOT2(x0.h, w2r[4 * t + 0], acc);
                acc = FDOT2(x1.h, w2r[4 * t + 1], acc);
                acc = FDOT2(x2.h, w2r[4 * t + 2], acc);
                acc = FDOT2(x3.h, w2r[4 * t + 3], acc);
            }
            float g = sigm(acc);
            int qrel = q - q0;
            if (qrel < CAP) {
                HSU cv2; cv2.f = (_Float16)g;
                gate[(size_t)qrel * 128 + c] = cv2.s;
            }
        }
        __syncthreads();
    }
}

// ---------------------------------------------------------------------------
// Gather aggregation: ONE destination per wave, FOUR edges batched per
// iteration (4 independent hs-row loads in flight; online-softmax update is
// serial VALU). MODE 0: plain. MODE 1: gate table via cmb. MODE 3: f16 gate.
#define AGG_LOAD(K, ACT)                                                     \
    float2 hv##K; float2 gv##K; unsigned gu##K = 0;                          \
    if (ACT) {                                                               \
        int si = srcp[st + q + K];                                           \
        hv##K = hs2v[(size_t)si * 64 + lane];                                \
        if (MODE == 1) { int ab = cmb[st + q + K]; gv##K = gt2v[ab * 64 + lane]; } \
        if (MODE == 3) { int qq = st + q + K - q0base;                       \
                         qq = qq < 79999 ? qq : 79999;                       \
                         gu##K = g32[(size_t)qq * 64 + lane]; }              \
    }

#define AGG_UPD(K, ACT)                                                      \
    if (ACT) {                                                               \
        float mx = hv##K.x, my = hv##K.y;                                    \
        if (MODE == 1) { mx *= gv##K.x; my *= gv##K.y; }                     \
        if (MODE == 3) { H2U gz; gz.u = gu##K; mx *= (float)gz.h.x; my *= (float)gz.h.y; } \
        float p = mx * ax + my * ay;                                         \
        p += __shfl_xor(p, 1); p += __shfl_xor(p, 2);                        \
        p += __shfl_xor(p, 4); p += __shfl_xor(p, 8);                        \
        float logit = p + adv;                                               \
        logit = logit > 0.f ? logit : 0.2f * logit;                          \
        if (logit > mm) {                                                    \
            float r = expf(mm - logit);                                      \
            ss *= r; vx *= r; vy *= r; mm = logit;                           \
        }                                                                    \
        float ex = expf(logit - mm);                                         \
        ss += ex; vx += ex * mx; vy += ex * my;                              \
    }

template <int MODE>
__global__ __launch_bounds__(256) void agg_k(const float* __restrict__ hs,
                                             const float* __restrict__ ad,
                                             const int* __restrict__ srcp,
                                             const int* __restrict__ cmb,
                                             const int* __restrict__ starts,
                                             const int* __restrict__ deg,
                                             const float* __restrict__ attn_t,
                                             const float* __restrict__ gtbl,
                                             const u16* __restrict__ gate,
                                             float* __restrict__ agg,
                                             int j0, int j1) {
    int lane = threadIdx.x & 63;
    int gw = (blockIdx.x * 256 + threadIdx.x) >> 6;
    int nw = gridDim.x * 4;
    int c0 = 2 * lane;
    float ax = attn_t[c0], ay = attn_t[c0 + 1];
    int h = lane >> 4;
    const float2* hs2v = (const float2*)hs;
    const float2* gt2v = (const float2*)gtbl;
    const unsigned* g32 = (const unsigned*)gate;
    float2* agg2v = (float2*)agg;
    int q0base = 0;
    if (MODE == 3) q0base = __builtin_amdgcn_readfirstlane(starts[j0]);
    for (int j = j0 + gw; j < j1; j += nw) {
        int st = __builtin_amdgcn_readfirstlane(starts[j]);
        int n  = __builtin_amdgcn_readfirstlane(deg[j]);
        float adv = ad[(size_t)j * 4 + h];
        float mm = -3.0e38f, ss = 0.f, vx = 0.f, vy = 0.f;
        for (int q = 0; q < n; q += 4) {
            bool b1 = q + 1 < n, b2 = q + 2 < n, b3 = q + 3 < n;
            AGG_LOAD(0, true) AGG_LOAD(1, b1) AGG_LOAD(2, b2) AGG_LOAD(3, b3)
            AGG_UPD(0, true) AGG_UPD(1, b1) AGG_UPD(2, b2) AGG_UPD(3, b3)
        }
        float inv = ss > 0.f ? 1.f / ss : 0.f;
        float2 o; o.x = vx * inv; o.y = vy * inv;
        agg2v[(size_t)j * 64 + lane] = o;
    }
}

// ---------------------------------------------------------------------------
extern "C" void kernel_launch(void* const* d_in, const int* in_sizes, int n_in,
                              void* d_out, int out_size, void* d_ws, size_t ws_size,
                              hipStream_t stream) {
    static const int expect[29] = {
        6400000, 3840000, 1280000, 640000,
        500000, 500000, 500000, 500000, 250000, 250000, 250000, 250000,
        1000000, 750000, 65536, 512, 65536, 512, 512, 320, 256,
        8192, 128, 384, 128, 16384, 128, 65536, 512};
    int bad = 0;
    if (n_in != 29) bad = 1;
    else {
        for (int i = 0; i < 29; i++)
            if (in_sizes[i] != expect[i]) { bad = 4 + i; break; }
    }
    if (!bad && out_size != 12160000) bad = 2;
    if (!bad && ws_size < (size_t)63425536) bad = 3;
    if (bad) {
        senthost_k<<<1, 1, 0, stream>>>((float*)d_out, 4096.f * (float)bad);
        return;
    }

    const float* x_chem = (const float*)d_in[0];
    const float* x_gene = (const float*)d_in[1];
    const float* x_dis  = (const float*)d_in[2];
    const float* x_path = (const float*)d_in[3];
    const int* src0 = (const int*)d_in[4];  const int* dst0 = (const int*)d_in[5];
    const int* src1 = (const int*)d_in[6];  const int* dst1 = (const int*)d_in[7];
    const int* src2 = (const int*)d_in[8];  const int* dst2 = (const int*)d_in[9];
    const int* src3 = (const int*)d_in[10]; const int* dst3 = (const int*)d_in[11];
    const int*   cg   = (const int*)d_in[12];
    const float* cp   = (const float*)d_in[13];
    const float* Wsrc = (const float*)d_in[14]; const float* bsrc = (const float*)d_in[15];
    const float* Wdst = (const float*)d_in[16]; const float* bdst = (const float*)d_in[17];
    const float* attn = (const float*)d_in[18];
    const float* temb = (const float*)d_in[19]; const float* semb = (const float*)d_in[20];
    const float* Wg   = (const float*)d_in[21]; const float* bg   = (const float*)d_in[22];
    const float* W1c  = (const float*)d_in[23]; const float* b1c  = (const float*)d_in[24];
    const float* W2c  = (const float*)d_in[25]; const float* b2c  = (const float*)d_in[26];
    const float* Wout = (const float*)d_in[27]; const float* bout = (const float*)d_in[28];

    constexpr int NC = 50000, NG = 30000, ND = 10000, NP = 5000;
    constexpr int E0 = 500000, E1 = 500000, E2 = 250000, E3 = 250000;
    constexpr int GCAP = 80000;

    char* ws = (char*)d_ws;
    float* gt   = (float*)ws;              // [64][128] f32 = 32768 B
    int*   csum = (int*)(ws + 32768);      // chunk sums for scan (<=49 ints)
    char*  A    = ws + 65536;              // stage arena (<= 63,360,000 B)

    float* out = (float*)d_out;
    float* out_chem = out;
    float* out_gene = out + (size_t)NC * 128;
    float* out_dis  = out + (size_t)(NC + NG) * 128;
    float* out_path = out + (size_t)(NC + NG + ND) * 128;

    gtbl_k<<<32, 256, 0, stream>>>(temb, semb, Wg, bg, gt);

    // ---------- STAGE A: chemical output (t1: gene -> chemical) ----------
    {
        float* hs1  = (float*)(A);                 //  0 .. 15,360,000
        float* ad1  = (float*)(A + 15360000);      // .. 16,160,000
        int*   deg  = (int*)  (A + 16160000);      // .. 16,360,000
        int*   sts  = (int*)  (A + 16360000);      // .. 16,560,000
        int*   cur  = (int*)  (A + 16560000);      // .. 16,760,000
        int*   srcpA = (int*) (A + 16760000);      // .. 18,760,000
        float* agg1 = (float*)(A + 18760000);      // .. 44,360,000
        int nch = (NC + 1023) / 1024;
        zero_k<<<(NC + 255) / 256, 256, 0, stream>>>((float*)deg, NC);
        hist_k<<<(E1 + 255) / 256, 256, 0, stream>>>(dst1, deg, E1, NC);
        scan1_k<<<nch, 256, 0, stream>>>(deg, csum, NC);
        scan2_k<<<1, 64, 0, stream>>>(csum, nch);
        scan3_k<<<nch, 256, 0, stream>>>(deg, csum, sts, cur, NC);
        scatter_k<<<(E1 + 255) / 256, 256, 0, stream>>>(dst1, src1, nullptr, cur,
                                                        nullptr, srcpA, nullptr, E1, NC, NG);
        hsrow4_k<<<(NG + 15) / 16, 256, 0, stream>>>(x_gene, Wsrc + 1 * 16384, bsrc + 1 * 128, hs1, NG);
        adirect4_k<<<(NC + 15) / 16, 256, 0, stream>>>(x_chem, Wdst + 1 * 16384, bdst + 1 * 128, attn + 1 * 128, ad1, NC);
        agg_k<0><<<2048, 256, 0, stream>>>(hs1, ad1, srcpA, nullptr, sts, deg,
                                           attn + 1 * 128, nullptr, nullptr, agg1, 0, NC);
        outrow4_k<1><<<(NC + 15) / 16, 256, 0, stream>>>(agg1, nullptr,
                                                         Wout + 0 * 16384, bout + 0 * 128, out_chem, NC);
    }

    // ---------- STAGE B: pathway output (t2: chemical -> pathway) ----------
    {
        float* hs2  = (float*)(A);                 //  0 .. 25,600,000
        float* ad2  = (float*)(A + 25600000);      // .. 25,680,000
        int*   deg  = (int*)  (A + 25680000);      // .. 25,700,000
        int*   sts  = (int*)  (A + 25700000);      // .. 25,720,000
        int*   cur  = (int*)  (A + 25720000);      // .. 25,740,000
        int*   perm = (int*)  (A + 25740000);      // .. 26,740,000
        int*   srcpB = (int*) (A + 26740000);      // .. 27,740,000
        float* agg2 = (float*)(A + 27740000);      // .. 30,300,000
        u16*   gatep = (u16*) (A + 30300000);      // .. 50,780,000
        int nch = (NP + 1023) / 1024;
        zero_k<<<(NP + 255) / 256, 256, 0, stream>>>((float*)deg, NP);
        hist_k<<<(E2 + 255) / 256, 256, 0, stream>>>(dst2, deg, E2, NP);
        scan1_k<<<nch, 256, 0, stream>>>(deg, csum, NP);
        scan2_k<<<1, 64, 0, stream>>>(csum, nch);
        scan3_k<<<nch, 256, 0, stream>>>(deg, csum, sts, cur, NP);
        scatter_k<<<(E2 + 255) / 256, 256, 0, stream>>>(dst2, src2, nullptr, cur,
                                                        perm, srcpB, nullptr, E2, NP, NC);
        hsrow4_k<<<(NC + 15) / 16, 256, 0, stream>>>(x_chem, Wsrc + 2 * 16384, bsrc + 2 * 128, hs2, NC);
        adirect4_k<<<(NP + 15) / 16, 256, 0, stream>>>(x_path, Wdst + 2 * 16384, bdst + 2 * 128, attn + 2 * 128, ad2, NP);
        for (int ck = 0; ck < 4; ck++) {
            int j0 = ck * 1250, j1 = j0 + 1250;
            gate_k<<<1024, 256, 0, stream>>>(cp, W1c, b1c, W2c, b2c, perm, sts, gatep,
                                             j0, j1, NP, E2, GCAP);
            agg_k<3><<<313, 256, 0, stream>>>(hs2, ad2, srcpB, nullptr, sts, deg,
                                              attn + 2 * 128, nullptr, gatep, agg2, j0, j1);
        }
        outrow4_k<1><<<(NP + 15) / 16, 256, 0, stream>>>(agg2, nullptr,
                                                         Wout + 3 * 16384, bout + 3 * 128, out_path, NP);
    }

    // ---------- STAGE C: gene output (t0 + t3, sequential buffer reuse) -----
    {
        float* ad0  = (float*)(A + 25600000);      // .. 26,080,000
        float* ad3  = (float*)(A + 26080000);      // .. 26,560,000 (survives)
        int*   deg  = (int*)  (A + 26560000);      // .. 26,680,000
        int*   sts  = (int*)  (A + 26680000);      // .. 26,800,000
        int*   cur  = (int*)  (A + 26800000);      // .. 26,920,000
        int*   srcpC = (int*) (A + 26920000);      // .. 28,920,000
        int*   cmbp = (int*)  (A + 28920000);      // .. 30,920,000
        float* agg0 = (float*)(A + 30920000);      // .. 46,280,000
        float* agg3 = (float*)(A + 46280000);      // .. 61,640,000
        int nch = (NG + 1023) / 1024;

        // phase 1: t0 chemical -> gene (categorical gate)
        float* hs0 = (float*)(A);                  //  0 .. 25,600,000
        zero_k<<<(NG + 255) / 256, 256, 0, stream>>>((float*)deg, NG);
        hist_k<<<(E0 + 255) / 256, 256, 0, stream>>>(dst0, deg, E0, NG);
        scan1_k<<<nch, 256, 0, stream>>>(deg, csum, NG);
        scan2_k<<<1, 64, 0, stream>>>(csum, nch);
        scan3_k<<<nch, 256, 0, stream>>>(deg, csum, sts, cur, NG);
        scatter_k<<<(E0 + 255) / 256, 256, 0, stream>>>(dst0, src0, cg, cur,
                                                        nullptr, srcpC, cmbp, E0, NG, NC);
        hsrow4_k<<<(NC + 15) / 16, 256, 0, stream>>>(x_chem, Wsrc + 0 * 16384, bsrc + 0 * 128, hs0, NC);
        adirect4_k<<<(NG + 15) / 16, 256, 0, stream>>>(x_gene, Wdst + 0 * 16384, bdst + 0 * 128, attn + 0 * 128, ad0, NG);
        adirect4_k<<<(NG + 15) / 16, 256, 0, stream>>>(x_gene, Wdst + 3 * 16384, bdst + 3 * 128, attn + 3 * 128, ad3, NG);
        agg_k<1><<<2048, 256, 0, stream>>>(hs0, ad0, srcpC, cmbp, sts, deg,
                                           attn + 0 * 128, gt, nullptr, agg0, 0, NG);

        // phase 2: t3 disease -> gene (plain), reusing hs/CSR buffers
        float* hs3 = (float*)(A);                  //  0 .. 5,120,000
        zero_k<<<(NG + 255) / 256, 256, 0, stream>>>((float*)deg, NG);
        hist_k<<<(E3 + 255) / 256, 256, 0, stream>>>(dst3, deg, E3, NG);
        scan1_k<<<nch, 256, 0, stream>>>(deg, csum, NG);
        scan2_k<<<1, 64, 0, stream>>>(csum, nch);
        scan3_k<<<nch, 256, 0, stream>>>(deg, csum, sts, cur, NG);
        scatter_k<<<(E3 + 255) / 256, 256, 0, stream>>>(dst3, src3, nullptr, cur,
                                                        nullptr, srcpC, nullptr, E3, NG, ND);
        hsrow4_k<<<(ND + 15) / 16, 256, 0, stream>>>(x_dis, Wsrc + 3 * 16384, bsrc + 3 * 128, hs3, ND);
        agg_k<0><<<2048, 256, 0, stream>>>(hs3, ad3, srcpC, nullptr, sts, deg,
                                           attn + 3 * 128, nullptr, nullptr, agg3, 0, NG);
        outrow4_k<2><<<(NG + 15) / 16, 256, 0, stream>>>(agg0, agg3,
                                                         Wout + 1 * 16384, bout + 1 * 128, out_gene, NG);
    }

    // ---------- STAGE D: disease output (no incoming edges: bias only) ------
    outrow4_k<0><<<(ND + 15) / 16, 256, 0, stream>>>(nullptr, nullptr,
                                                     Wout + 2 * 16384, bout + 2 * 128, out_dis, ND);
}

// Round 9
// 1121.711 us; speedup vs baseline: 2.0306x; 1.4852x over previous
//
#include <hip/hip_runtime.h>

// EdgeAttrHeteroConv — round 16 (= R15 resubmitted verbatim; R15 died on
// GPUAcquisitionTimeout before any measurement). R14 = 1666 us; top-5 all
// adirect4_k (NC: 114 us, VALUBusy 13.6%, HBM 1.5%) -> dense kernels are
// latency-bound on wave-uniform x loads + W thrashing L1. This round:
// (a) adirect is a GEMV in disguise: ad[j][h] = bb[h] + x[j].av[:,h] with
//     av[k][h] = sum_{c in head h} Wd[k][c]*attn[c] (exact reassociation,
//     32x less compute). avprep_k (tiny) + adg_k (1 float2 load + 8 FMA +
//     24 shfl per row).
// (b) hsrow/outrow -> denseT_k: 32-row x-tile staged in LDS (16 KB) via
//     coalesced float4; each of 4 waves computes 8 rows, x via broadcast
//     ds_read_b128, W via L1 float2 (reused 8 rows/pass, shared by 4 waves).
// (c) agg_k/gate_k/CSR identical to R14 (verified absmax 1.95e-3).

typedef unsigned short u16;
typedef _Float16 h2_t __attribute__((ext_vector_type(2)));
union H2U { unsigned u; h2_t h; };
union HSU { _Float16 f; unsigned short s; };

#if __has_builtin(__builtin_amdgcn_fdot2)
#define FDOT2(a, b, c) __builtin_amdgcn_fdot2((a), (b), (c), false)
#else
#define FDOT2(a, b, c) ((c) + (float)(a).x * (float)(b).x + (float)(a).y * (float)(b).y)
#endif

__device__ __forceinline__ float sigm(float x) { return 1.f / (1.f + expf(-x)); }

// ---------------------------------------------------------------------------
__global__ void zero_k(float* __restrict__ p, int n) {
    int i = blockIdx.x * 256 + threadIdx.x;
    if (i < n) p[i] = 0.f;
}

__global__ void senthost_k(float* out, float v) { out[0] = v; }

// ---------------------------------------------------------------------------
// CSR build: histogram -> 3-kernel exclusive scan (1024-elem chunks) -> scatter
__global__ void hist_k(const int* __restrict__ dst, int* __restrict__ deg, int E, int Nd) {
    int e = blockIdx.x * 256 + threadIdx.x;
    if (e < E) {
        int d = dst[e];
        d = d < 0 ? 0 : (d >= Nd ? Nd - 1 : d);
        atomicAdd(&deg[d], 1);
    }
}

__global__ void scan1_k(const int* __restrict__ deg, int* __restrict__ csum, int Nd) {
    __shared__ int red[256];
    int base = blockIdx.x * 1024;
    int t = threadIdx.x;
    int s = 0;
    for (int i = 0; i < 4; i++) {
        int idx = base + t * 4 + i;
        if (idx < Nd) s += deg[idx];
    }
    red[t] = s;
    __syncthreads();
    for (int off = 128; off > 0; off >>= 1) {
        if (t < off) red[t] += red[t + off];
        __syncthreads();
    }
    if (t == 0) csum[blockIdx.x] = red[0];
}

__global__ void scan2_k(int* __restrict__ csum, int nch) {
    if (threadIdx.x == 0) {
        int acc = 0;
        for (int i = 0; i < nch; i++) { int v = csum[i]; csum[i] = acc; acc += v; }
    }
}

__global__ void scan3_k(const int* __restrict__ deg, const int* __restrict__ csum,
                        int* __restrict__ starts, int* __restrict__ cur, int Nd) {
    __shared__ int sc[256];
    int base = blockIdx.x * 1024;
    int t = threadIdx.x;
    int v[4];
    int s = 0;
    for (int i = 0; i < 4; i++) {
        int idx = base + t * 4 + i;
        v[i] = idx < Nd ? deg[idx] : 0;
        s += v[i];
    }
    sc[t] = s;
    __syncthreads();
    for (int off = 1; off < 256; off <<= 1) {           // Hillis-Steele inclusive
        int add = (t >= off) ? sc[t - off] : 0;
        __syncthreads();
        sc[t] += add;
        __syncthreads();
    }
    int excl = sc[t] - s + csum[blockIdx.x];
    for (int i = 0; i < 4; i++) {
        int idx = base + t * 4 + i;
        if (idx < Nd) { starts[idx] = excl; cur[idx] = excl; excl += v[i]; }
    }
}

// scatter: build CSR payloads directly. perm (edge id) only if needed (t2),
// srcp = clamped source index always, cmb = packed gate combo if cg given.
__global__ void scatter_k(const int* __restrict__ dst, const int* __restrict__ src,
                          const int* __restrict__ cg, int* __restrict__ cur,
                          int* __restrict__ perm, int* __restrict__ srcp,
                          int* __restrict__ cmb, int E, int Nd, int Ns) {
    int e = blockIdx.x * 256 + threadIdx.x;
    if (e < E) {
        int d = dst[e];
        d = d < 0 ? 0 : (d >= Nd ? Nd - 1 : d);
        int p = atomicAdd(&cur[d], 1);
        if (perm) perm[p] = e;
        int si = src[e];
        si = si < 0 ? 0 : (si >= Ns ? Ns - 1 : si);
        srcp[p] = si;
        if (cmb) {
            int a = cg[2 * e] & 7, b = cg[2 * e + 1] & 7;
            cmb[p] = a * 8 + b;
        }
    }
}

// ---------------------------------------------------------------------------
__global__ void gtbl_k(const float* __restrict__ temb, const float* __restrict__ semb,
                       const float* __restrict__ Wg, const float* __restrict__ bg,
                       float* __restrict__ gtbl) {
    int idx = blockIdx.x * 256 + threadIdx.x;
    if (idx >= 8192) return;
    int combo = idx >> 7, c = idx & 127;
    int a = combo >> 3, b = combo & 7;
    float s = bg[c];
    for (int k = 0; k < 32; k++) s += temb[a * 32 + k] * Wg[k * 128 + c];
    for (int k = 0; k < 32; k++) s += semb[b * 32 + k] * Wg[(32 + k) * 128 + c];
    gtbl[combo * 128 + c] = sigm(s);
}

// ---------------------------------------------------------------------------
// adirect as GEMV: av[k][h] = sum_{c in head h} Wd[k][c]*attn[c];
// bb[h] = sum_{c in head h} bd[c]*attn[c]. Exact reassociation.
__global__ void avprep_k(const float* __restrict__ Wd, const float* __restrict__ bd,
                         const float* __restrict__ at, float* __restrict__ av,
                         float* __restrict__ bb) {
    int k = threadIdx.x;                       // 128 threads
    float a0 = 0.f, a1 = 0.f, a2 = 0.f, a3 = 0.f;
    for (int c = 0; c < 32; c++) {
        a0 += Wd[k * 128 + 0 * 32 + c] * at[0 * 32 + c];
        a1 += Wd[k * 128 + 1 * 32 + c] * at[1 * 32 + c];
        a2 += Wd[k * 128 + 2 * 32 + c] * at[2 * 32 + c];
        a3 += Wd[k * 128 + 3 * 32 + c] * at[3 * 32 + c];
    }
    float4 o; o.x = a0; o.y = a1; o.z = a2; o.w = a3;
    ((float4*)av)[k] = o;
    if (k < 4) {
        float s = 0.f;
        for (int c = 0; c < 32; c++) s += bd[k * 32 + c] * at[k * 32 + c];
        bb[k] = s;
    }
}

__global__ __launch_bounds__(256) void adg_k(const float* __restrict__ x,
                                             const float* __restrict__ av,
                                             const float* __restrict__ bb,
                                             float* __restrict__ ad, int N) {
    int l = threadIdx.x & 63;
    int gw = (blockIdx.x * 256 + threadIdx.x) >> 6;
    int nw = gridDim.x * 4;
    float4 av0 = ((const float4*)av)[2 * l];
    float4 av1 = ((const float4*)av)[2 * l + 1];
    float4 bbv = *(const float4*)bb;
    const float2* x2 = (const float2*)x;
    for (int j = gw; j < N; j += nw) {
        float2 xv = x2[(size_t)j * 64 + l];
        float p0 = xv.x * av0.x + xv.y * av1.x;
        float p1 = xv.x * av0.y + xv.y * av1.y;
        float p2 = xv.x * av0.z + xv.y * av1.z;
        float p3 = xv.x * av0.w + xv.y * av1.w;
        #pragma unroll
        for (int off = 1; off < 64; off <<= 1) {
            p0 += __shfl_xor(p0, off);
            p1 += __shfl_xor(p1, off);
            p2 += __shfl_xor(p2, off);
            p3 += __shfl_xor(p3, off);
        }
        if (l == 0) {
            float4 o; o.x = p0 + bbv.x; o.y = p1 + bbv.y; o.z = p2 + bbv.z; o.w = p3 + bbv.w;
            *(float4*)&ad[(size_t)j * 4] = o;
        }
    }
}

// ---------------------------------------------------------------------------
// Tiled dense: 32-row x tile in LDS (16 KB), 4 waves x 8 rows, 2 ch/lane.
// NIN=1: O = X@W + b. NIN=2: O = (X+Xb)@W + b.
#define STEP4(A, XV)                                     \
    A.x += XV.x * w0.x; A.y += XV.x * w0.y;              \
    A.x += XV.y * w1.x; A.y += XV.y * w1.y;              \
    A.x += XV.z * w2.x; A.y += XV.z * w2.y;              \
    A.x += XV.w * w3.x; A.y += XV.w * w3.y;

template <int NIN>
__global__ __launch_bounds__(256) void denseT_k(const float* __restrict__ X,
                                                const float* __restrict__ Xb,
                                                const float* __restrict__ W,
                                                const float* __restrict__ bias,
                                                float* __restrict__ O, int N, int NT) {
    __shared__ float4 xs4[1024];               // 32 rows x 128 ch = 16 KB
    int t = threadIdx.x;
    int l = t & 63, w = t >> 6;
    float2 bi = *(const float2*)&bias[2 * l];
    const float4* X4 = (const float4*)X;
    const float4* B4 = (const float4*)Xb;
    const float2* Wv = (const float2*)W;
    float2* O2 = (float2*)O;
    for (int tile = blockIdx.x; tile < NT; tile += gridDim.x) {
        int R0 = tile * 32;
        #pragma unroll
        for (int i = 0; i < 4; i++) {
            int idx = t + 256 * i;             // 0..1023 over 512 B tile rows
            int r = R0 + (idx >> 5);
            int rc = min(r, N - 1);
            float4 v = X4[(size_t)rc * 32 + (idx & 31)];
            if (NIN == 2) {
                float4 b = B4[(size_t)rc * 32 + (idx & 31)];
                v.x += b.x; v.y += b.y; v.z += b.z; v.w += b.w;
            }
            xs4[idx] = v;
        }
        __syncthreads();
        float2 a0 = bi, a1 = bi, a2 = bi, a3 = bi, a4 = bi, a5 = bi, a6 = bi, a7 = bi;
        int rb = 8 * w;                        // wave's row base within tile
        #pragma unroll 2
        for (int kb = 0; kb < 32; kb++) {
            float2 w0 = Wv[(4 * kb + 0) * 64 + l];
            float2 w1 = Wv[(4 * kb + 1) * 64 + l];
            float2 w2 = Wv[(4 * kb + 2) * 64 + l];
            float2 w3 = Wv[(4 * kb + 3) * 64 + l];
            float4 x0 = xs4[(rb + 0) * 32 + kb];
            float4 x1 = xs4[(rb + 1) * 32 + kb];
            float4 x2 = xs4[(rb + 2) * 32 + kb];
            float4 x3 = xs4[(rb + 3) * 32 + kb];
            float4 x4v = xs4[(rb + 4) * 32 + kb];
            float4 x5 = xs4[(rb + 5) * 32 + kb];
            float4 x6 = xs4[(rb + 6) * 32 + kb];
            float4 x7 = xs4[(rb + 7) * 32 + kb];
            STEP4(a0, x0) STEP4(a1, x1) STEP4(a2, x2) STEP4(a3, x3)
            STEP4(a4, x4v) STEP4(a5, x5) STEP4(a6, x6) STEP4(a7, x7)
        }
        int rbase = R0 + rb;
        if (rbase + 0 < N) O2[(size_t)(rbase + 0) * 64 + l] = a0;
        if (rbase + 1 < N) O2[(size_t)(rbase + 1) * 64 + l] = a1;
        if (rbase + 2 < N) O2[(size_t)(rbase + 2) * 64 + l] = a2;
        if (rbase + 3 < N) O2[(size_t)(rbase + 3) * 64 + l] = a3;
        if (rbase + 4 < N) O2[(size_t)(rbase + 4) * 64 + l] = a4;
        if (rbase + 5 < N) O2[(size_t)(rbase + 5) * 64 + l] = a5;
        if (rbase + 6 < N) O2[(size_t)(rbase + 6) * 64 + l] = a6;
        if (rbase + 7 < N) O2[(size_t)(rbase + 7) * 64 + l] = a7;
        __syncthreads();
    }
}

// bias-only rows (disease output)
__global__ void biasrow_k(const float* __restrict__ bo, float* __restrict__ out, int N) {
    int idx = blockIdx.x * 256 + threadIdx.x;
    if (idx < N * 64) {
        float2 bi = *(const float2*)&bo[2 * (idx & 63)];
        ((float2*)out)[idx] = bi;
    }
}

// ---------------------------------------------------------------------------
// t2 gate precompute, perm-order chunk [starts[j0], starts[j1]).
__global__ __launch_bounds__(256) void gate_k(const float* __restrict__ cp,
                                              const float* __restrict__ W1c, const float* __restrict__ b1c,
                                              const float* __restrict__ W2c, const float* __restrict__ b2c,
                                              const int* __restrict__ perm, const int* __restrict__ starts,
                                              u16* __restrict__ gate,
                                              int j0, int j1, int NP_, int E, int CAP) {
    __shared__ __align__(16) u16 u_sh[256];
    int c = threadIdx.x & 127;
    int slot = threadIdx.x >> 7;
    int q0 = starts[j0];
    int q1 = (j1 >= NP_) ? E : starts[j1];
    int npairs = (q1 - q0 + 1) >> 1;
    h2_t w2r[64];
    #pragma unroll
    for (int kk = 0; kk < 64; kk++) {
        h2_t w;
        w.x = (_Float16)W2c[(2 * kk) * 128 + c];
        w.y = (_Float16)W2c[(2 * kk + 1) * 128 + c];
        w2r[kk] = w;
    }
    float w1a = W1c[c], w1b = W1c[128 + c], w1cc = W1c[256 + c];
    float b1 = b1c[c], b2 = b2c[c];
    const uint4* u4 = (const uint4*)u_sh;
    for (int it = blockIdx.x; it < npairs; it += gridDim.x) {
        int q = q0 + it * 2 + slot;
        bool act = q < q1;
        if (act) {
            int e = __builtin_amdgcn_readfirstlane(perm[q]);
            float p0 = cp[(size_t)e * 3 + 0];
            float p1 = cp[(size_t)e * 3 + 1];
            float p2 = cp[(size_t)e * 3 + 2];
            float z = b1 + p0 * w1a + p1 * w1b + p2 * w1cc;
            float u = 0.5f * z * (1.f + erff(z * 0.70710678118654752f));
            HSU cv; cv.f = (_Float16)u;
            u_sh[slot * 128 + c] = cv.s;
        }
        __syncthreads();
        if (act) {
            float acc = b2;
            #pragma unroll
            for (int tt = 0; tt < 16; tt++) {
                uint4 uv = u4[slot * 16 + tt];
                H2U x0, x1, x2, x3;
                x0.u = uv.x; x1.u = uv.y; x2.u = uv.z; x3.u = uv.w;
                acc = FDOT2(x0.h, w2r[4 * tt + 0], acc);
                acc = FDOT2(x1.h, w2r[4 * tt + 1], acc);
                acc = FDOT2(x2.h, w2r[4 * tt + 2], acc);
                acc = FDOT2(x3.h, w2r[4 * tt + 3], acc);
            }
            float g = sigm(acc);
            int qrel = q - q0;
            if (qrel < CAP) {
                HSU cv2; cv2.f = (_Float16)g;
                gate[(size_t)qrel * 128 + c] = cv2.s;
            }
        }
        __syncthreads();
    }
}

// ---------------------------------------------------------------------------
// Gather aggregation: ONE destination per wave, FOUR edges batched per
// iteration. MODE 0: plain. MODE 1: gate table via cmb. MODE 3: f16 gate.
#define AGG_LOAD(K, ACT)                                                     \
    float2 hv##K; float2 gv##K; unsigned gu##K = 0;                          \
    if (ACT) {                                                               \
        int si = srcp[st + q + K];                                           \
        hv##K = hs2v[(size_t)si * 64 + lane];                                \
        if (MODE == 1) { int ab = cmb[st + q + K]; gv##K = gt2v[ab * 64 + lane]; } \
        if (MODE == 3) { int qq = st + q + K - q0base;                       \
                         qq = qq < 79999 ? qq : 79999;                       \
                         gu##K = g32[(size_t)qq * 64 + lane]; }              \
    }

#define AGG_UPD(K, ACT)                                                      \
    if (ACT) {                                                               \
        float mx = hv##K.x, my = hv##K.y;                                    \
        if (MODE == 1) { mx *= gv##K.x; my *= gv##K.y; }                     \
        if (MODE == 3) { H2U gz; gz.u = gu##K; mx *= (float)gz.h.x; my *= (float)gz.h.y; } \
        float p = mx * ax + my * ay;                                         \
        p += __shfl_xor(p, 1); p += __shfl_xor(p, 2);                        \
        p += __shfl_xor(p, 4); p += __shfl_xor(p, 8);                        \
        float logit = p + adv;                                               \
        logit = logit > 0.f ? logit : 0.2f * logit;                          \
        if (logit > mm) {                                                    \
            float r = expf(mm - logit);                                      \
            ss *= r; vx *= r; vy *= r; mm = logit;                           \
        }                                                                    \
        float ex = expf(logit - mm);                                         \
        ss += ex; vx += ex * mx; vy += ex * my;                              \
    }

template <int MODE>
__global__ __launch_bounds__(256) void agg_k(const float* __restrict__ hs,
                                             const float* __restrict__ ad,
                                             const int* __restrict__ srcp,
                                             const int* __restrict__ cmb,
                                             const int* __restrict__ starts,
                                             const int* __restrict__ deg,
                                             const float* __restrict__ attn_t,
                                             const float* __restrict__ gtbl,
                                             const u16* __restrict__ gate,
                                             float* __restrict__ agg,
                                             int j0, int j1) {
    int lane = threadIdx.x & 63;
    int gw = (blockIdx.x * 256 + threadIdx.x) >> 6;
    int nw = gridDim.x * 4;
    int c0 = 2 * lane;
    float ax = attn_t[c0], ay = attn_t[c0 + 1];
    int h = lane >> 4;
    const float2* hs2v = (const float2*)hs;
    const float2* gt2v = (const float2*)gtbl;
    const unsigned* g32 = (const unsigned*)gate;
    float2* agg2v = (float2*)agg;
    int q0base = 0;
    if (MODE == 3) q0base = __builtin_amdgcn_readfirstlane(starts[j0]);
    for (int j = j0 + gw; j < j1; j += nw) {
        int st = __builtin_amdgcn_readfirstlane(starts[j]);
        int n  = __builtin_amdgcn_readfirstlane(deg[j]);
        float adv = ad[(size_t)j * 4 + h];
        float mm = -3.0e38f, ss = 0.f, vx = 0.f, vy = 0.f;
        for (int q = 0; q < n; q += 4) {
            bool b1 = q + 1 < n, b2 = q + 2 < n, b3 = q + 3 < n;
            AGG_LOAD(0, true) AGG_LOAD(1, b1) AGG_LOAD(2, b2) AGG_LOAD(3, b3)
            AGG_UPD(0, true) AGG_UPD(1, b1) AGG_UPD(2, b2) AGG_UPD(3, b3)
        }
        float inv = ss > 0.f ? 1.f / ss : 0.f;
        float2 o; o.x = vx * inv; o.y = vy * inv;
        agg2v[(size_t)j * 64 + lane] = o;
    }
}

// ---------------------------------------------------------------------------
extern "C" void kernel_launch(void* const* d_in, const int* in_sizes, int n_in,
                              void* d_out, int out_size, void* d_ws, size_t ws_size,
                              hipStream_t stream) {
    static const int expect[29] = {
        6400000, 3840000, 1280000, 640000,
        500000, 500000, 500000, 500000, 250000, 250000, 250000, 250000,
        1000000, 750000, 65536, 512, 65536, 512, 512, 320, 256,
        8192, 128, 384, 128, 16384, 128, 65536, 512};
    int bad = 0;
    if (n_in != 29) bad = 1;
    else {
        for (int i = 0; i < 29; i++)
            if (in_sizes[i] != expect[i]) { bad = 4 + i; break; }
    }
    if (!bad && out_size != 12160000) bad = 2;
    if (!bad && ws_size < (size_t)63425536) bad = 3;
    if (bad) {
        senthost_k<<<1, 1, 0, stream>>>((float*)d_out, 4096.f * (float)bad);
        return;
    }

    const float* x_chem = (const float*)d_in[0];
    const float* x_gene = (const float*)d_in[1];
    const float* x_dis  = (const float*)d_in[2];
    const float* x_path = (const float*)d_in[3];
    const int* src0 = (const int*)d_in[4];  const int* dst0 = (const int*)d_in[5];
    const int* src1 = (const int*)d_in[6];  const int* dst1 = (const int*)d_in[7];
    const int* src2 = (const int*)d_in[8];  const int* dst2 = (const int*)d_in[9];
    const int* src3 = (const int*)d_in[10]; const int* dst3 = (const int*)d_in[11];
    const int*   cg   = (const int*)d_in[12];
    const float* cp   = (const float*)d_in[13];
    const float* Wsrc = (const float*)d_in[14]; const float* bsrc = (const float*)d_in[15];
    const float* Wdst = (const float*)d_in[16]; const float* bdst = (const float*)d_in[17];
    const float* attn = (const float*)d_in[18];
    const float* temb = (const float*)d_in[19]; const float* semb = (const float*)d_in[20];
    const float* Wg   = (const float*)d_in[21]; const float* bg   = (const float*)d_in[22];
    const float* W1c  = (const float*)d_in[23]; const float* b1c  = (const float*)d_in[24];
    const float* W2c  = (const float*)d_in[25]; const float* b2c  = (const float*)d_in[26];
    const float* Wout = (const float*)d_in[27]; const float* bout = (const float*)d_in[28];

    constexpr int NC = 50000, NG = 30000, ND = 10000, NP = 5000;
    constexpr int E0 = 500000, E1 = 500000, E2 = 250000, E3 = 250000;
    constexpr int GCAP = 80000;

    char* ws = (char*)d_ws;
    float* gt   = (float*)ws;              // [64][128] f32 = 32768 B
    int*   csum = (int*)(ws + 32768);      // chunk sums for scan (<=49 ints)
    float* avb  = (float*)(ws + 36864);    // 4 slots x (128x4 av + 4 bb) = ~8.3 KB
    char*  A    = ws + 65536;              // stage arena (<= 63,360,000 B)

    float* out = (float*)d_out;
    float* out_chem = out;
    float* out_gene = out + (size_t)NC * 128;
    float* out_dis  = out + (size_t)(NC + NG) * 128;
    float* out_path = out + (size_t)(NC + NG + ND) * 128;

    // per-slot: av = 512 floats, bb = 4 floats, pad to 520
    float* av1 = avb + 0 * 520; float* bb1 = av1 + 512;
    float* av2 = avb + 1 * 520; float* bb2 = av2 + 512;
    float* av0 = avb + 2 * 520; float* bb0 = av0 + 512;
    float* av3 = avb + 3 * 520; float* bb3 = av3 + 512;

    gtbl_k<<<32, 256, 0, stream>>>(temb, semb, Wg, bg, gt);
    avprep_k<<<1, 128, 0, stream>>>(Wdst + 1 * 16384, bdst + 1 * 128, attn + 1 * 128, av1, bb1);
    avprep_k<<<1, 128, 0, stream>>>(Wdst + 2 * 16384, bdst + 2 * 128, attn + 2 * 128, av2, bb2);
    avprep_k<<<1, 128, 0, stream>>>(Wdst + 0 * 16384, bdst + 0 * 128, attn + 0 * 128, av0, bb0);
    avprep_k<<<1, 128, 0, stream>>>(Wdst + 3 * 16384, bdst + 3 * 128, attn + 3 * 128, av3, bb3);

    // ---------- STAGE A: chemical output (t1: gene -> chemical) ----------
    {
        float* hs1  = (float*)(A);                 //  0 .. 15,360,000
        float* ad1  = (float*)(A + 15360000);      // .. 16,160,000
        int*   deg  = (int*)  (A + 16160000);      // .. 16,360,000
        int*   sts  = (int*)  (A + 16360000);      // .. 16,560,000
        int*   cur  = (int*)  (A + 16560000);      // .. 16,760,000
        int*   srcpA = (int*) (A + 16760000);      // .. 18,760,000
        float* agg1 = (float*)(A + 18760000);      // .. 44,360,000
        int nch = (NC + 1023) / 1024;
        zero_k<<<(NC + 255) / 256, 256, 0, stream>>>((float*)deg, NC);
        hist_k<<<(E1 + 255) / 256, 256, 0, stream>>>(dst1, deg, E1, NC);
        scan1_k<<<nch, 256, 0, stream>>>(deg, csum, NC);
        scan2_k<<<1, 64, 0, stream>>>(csum, nch);
        scan3_k<<<nch, 256, 0, stream>>>(deg, csum, sts, cur, NC);
        scatter_k<<<(E1 + 255) / 256, 256, 0, stream>>>(dst1, src1, nullptr, cur,
                                                        nullptr, srcpA, nullptr, E1, NC, NG);
        denseT_k<1><<<(NG + 31) / 32, 256, 0, stream>>>(x_gene, nullptr,
                                                        Wsrc + 1 * 16384, bsrc + 1 * 128, hs1, NG, (NG + 31) / 32);
        adg_k<<<1024, 256, 0, stream>>>(x_chem, av1, bb1, ad1, NC);
        agg_k<0><<<2048, 256, 0, stream>>>(hs1, ad1, srcpA, nullptr, sts, deg,
                                           attn + 1 * 128, nullptr, nullptr, agg1, 0, NC);
        denseT_k<1><<<(NC + 31) / 32, 256, 0, stream>>>(agg1, nullptr,
                                                        Wout + 0 * 16384, bout + 0 * 128, out_chem, NC, (NC + 31) / 32);
    }

    // ---------- STAGE B: pathway output (t2: chemical -> pathway) ----------
    {
        float* hs2  = (float*)(A);                 //  0 .. 25,600,000
        float* ad2  = (float*)(A + 25600000);      // .. 25,680,000
        int*   deg  = (int*)  (A + 25680000);      // .. 25,700,000
        int*   sts  = (int*)  (A + 25700000);      // .. 25,720,000
        int*   cur  = (int*)  (A + 25720000);      // .. 25,740,000
        int*   perm = (int*)  (A + 25740000);      // .. 26,740,000
        int*   srcpB = (int*) (A + 26740000);      // .. 27,740,000
        float* agg2 = (float*)(A + 27740000);      // .. 30,300,000
        u16*   gatep = (u16*) (A + 30300000);      // .. 50,780,000
        int nch = (NP + 1023) / 1024;
        zero_k<<<(NP + 255) / 256, 256, 0, stream>>>((float*)deg, NP);
        hist_k<<<(E2 + 255) / 256, 256, 0, stream>>>(dst2, deg, E2, NP);
        scan1_k<<<nch, 256, 0, stream>>>(deg, csum, NP);
        scan2_k<<<1, 64, 0, stream>>>(csum, nch);
        scan3_k<<<nch, 256, 0, stream>>>(deg, csum, sts, cur, NP);
        scatter_k<<<(E2 + 255) / 256, 256, 0, stream>>>(dst2, src2, nullptr, cur,
                                                        perm, srcpB, nullptr, E2, NP, NC);
        denseT_k<1><<<(NC + 31) / 32, 256, 0, stream>>>(x_chem, nullptr,
                                                        Wsrc + 2 * 16384, bsrc + 2 * 128, hs2, NC, (NC + 31) / 32);
        adg_k<<<256, 256, 0, stream>>>(x_path, av2, bb2, ad2, NP);
        for (int ck = 0; ck < 4; ck++) {
            int j0 = ck * 1250, j1 = j0 + 1250;
            gate_k<<<1024, 256, 0, stream>>>(cp, W1c, b1c, W2c, b2c, perm, sts, gatep,
                                             j0, j1, NP, E2, GCAP);
            agg_k<3><<<313, 256, 0, stream>>>(hs2, ad2, srcpB, nullptr, sts, deg,
                                              attn + 2 * 128, nullptr, gatep, agg2, j0, j1);
        }
        denseT_k<1><<<(NP + 31) / 32, 256, 0, stream>>>(agg2, nullptr,
                                                        Wout + 3 * 16384, bout + 3 * 128, out_path, NP, (NP + 31) / 32);
    }

    // ---------- STAGE C: gene output (t0 + t3, sequential buffer reuse) -----
    {
        float* ad0  = (float*)(A + 25600000);      // .. 26,080,000
        float* ad3  = (float*)(A + 26080000);      // .. 26,560,000 (survives)
        int*   deg  = (int*)  (A + 26560000);      // .. 26,680,000
        int*   sts  = (int*)  (A + 26680000);      // .. 26,800,000
        int*   cur  = (int*)  (A + 26800000);      // .. 26,920,000
        int*   srcpC = (int*) (A + 26920000);      // .. 28,920,000
        int*   cmbp = (int*)  (A + 28920000);      // .. 30,920,000
        float* agg0 = (float*)(A + 30920000);      // .. 46,280,000
        float* agg3 = (float*)(A + 46280000);      // .. 61,640,000
        int nch = (NG + 1023) / 1024;

        // phase 1: t0 chemical -> gene (categorical gate)
        float* hs0 = (float*)(A);                  //  0 .. 25,600,000
        zero_k<<<(NG + 255) / 256, 256, 0, stream>>>((float*)deg, NG);
        hist_k<<<(E0 + 255) / 256, 256, 0, stream>>>(dst0, deg, E0, NG);
        scan1_k<<<nch, 256, 0, stream>>>(deg, csum, NG);
        scan2_k<<<1, 64, 0, stream>>>(csum, nch);
        scan3_k<<<nch, 256, 0, stream>>>(deg, csum, sts, cur, NG);
        scatter_k<<<(E0 + 255) / 256, 256, 0, stream>>>(dst0, src0, cg, cur,
                                                        nullptr, srcpC, cmbp, E0, NG, NC);
        denseT_k<1><<<(NC + 31) / 32, 256, 0, stream>>>(x_chem, nullptr,
                                                        Wsrc + 0 * 16384, bsrc + 0 * 128, hs0, NC, (NC + 31) / 32);
        adg_k<<<1024, 256, 0, stream>>>(x_gene, av0, bb0, ad0, NG);
        adg_k<<<1024, 256, 0, stream>>>(x_gene, av3, bb3, ad3, NG);
        agg_k<1><<<2048, 256, 0, stream>>>(hs0, ad0, srcpC, cmbp, sts, deg,
                                           attn + 0 * 128, gt, nullptr, agg0, 0, NG);

        // phase 2: t3 disease -> gene (plain), reusing hs/CSR buffers
        float* hs3 = (float*)(A);                  //  0 .. 5,120,000
        zero_k<<<(NG + 255) / 256, 256, 0, stream>>>((float*)deg, NG);
        hist_k<<<(E3 + 255) / 256, 256, 0, stream>>>(dst3, deg, E3, NG);
        scan1_k<<<nch, 256, 0, stream>>>(deg, csum, NG);
        scan2_k<<<1, 64, 0, stream>>>(csum, nch);
        scan3_k<<<nch, 256, 0, stream>>>(deg, csum, sts, cur, NG);
        scatter_k<<<(E3 + 255) / 256, 256, 0, stream>>>(dst3, src3, nullptr, cur,
                                                        nullptr, srcpC, nullptr, E3, NG, ND);
        denseT_k<1><<<(ND + 31) / 32, 256, 0, stream>>>(x_dis, nullptr,
                                                        Wsrc + 3 * 16384, bsrc + 3 * 128, hs3, ND, (ND + 31) / 32);
        agg_k<0><<<2048, 256, 0, stream>>>(hs3, ad3, srcpC, nullptr, sts, deg,
                                           attn + 3 * 128, nullptr, nullptr, agg3, 0, NG);
        denseT_k<2><<<(NG + 31) / 32, 256, 0, stream>>>(agg0, agg3,
                                                        Wout + 1 * 16384, bout + 1 * 128, out_gene, NG, (NG + 31) / 32);
    }

    // ---------- STAGE D: disease output (no incoming edges: bias only) ------
    biasrow_k<<<(ND * 64 + 255) / 256, 256, 0, stream>>>(bout + 2 * 128, out_dis, ND);
}

// Round 10
// 993.394 us; speedup vs baseline: 2.2929x; 1.1292x over previous
//
#include <hip/hip_runtime.h>

// EdgeAttrHeteroConv — round 17. R16 = 1122 us; top-5 all gate_k (4 x 72 us
// = 290 us, VALUBusy 36%, occ 38%). gate is an E2x128 @ 128x128 f16 GEMM
// (8.2 GFLOP) done as per-lane FDOT2 (2 edges/block-iter between syncs).
// R17 moves it to MFMA (G10): w2pack_k packs W2 into B-fragment order for
// mfma_f32_16x16x32_f16; ugen_k (1 wave/edge) writes u=gelu(cp@W1+b1) f16
// into the gate buffer; gmm_k (1 wave per 16-edge row-block) loads A-frags
// from u, 32 MFMAs (8 col-tiles x 4 k-blocks), bias+sigmoid, writes gate IN
// PLACE (rows wave-exclusive, loads before stores, tail clamped in-block).
// C/D map col=lane&15,row=(lane>>4)*4+reg (m89-verified, dtype-independent).
// Arena shifted to ws+98304 to make room for w2p (32 KB at ws+49152).
// Everything else identical to R16 (verified 1122 us, absmax 1.95e-3).

typedef unsigned short u16;
typedef _Float16 h2_t __attribute__((ext_vector_type(2)));
typedef _Float16 f16x8 __attribute__((ext_vector_type(8)));
typedef float f32x4 __attribute__((ext_vector_type(4)));
union H2U { unsigned u; h2_t h; };
union HSU { _Float16 f; unsigned short s; };
union U4F8 { uint4 u; f16x8 h; };

__device__ __forceinline__ float sigm(float x) { return 1.f / (1.f + expf(-x)); }

// ---------------------------------------------------------------------------
__global__ void zero_k(float* __restrict__ p, int n) {
    int i = blockIdx.x * 256 + threadIdx.x;
    if (i < n) p[i] = 0.f;
}

__global__ void senthost_k(float* out, float v) { out[0] = v; }

// ---------------------------------------------------------------------------
// CSR build: histogram -> 3-kernel exclusive scan (1024-elem chunks) -> scatter
__global__ void hist_k(const int* __restrict__ dst, int* __restrict__ deg, int E, int Nd) {
    int e = blockIdx.x * 256 + threadIdx.x;
    if (e < E) {
        int d = dst[e];
        d = d < 0 ? 0 : (d >= Nd ? Nd - 1 : d);
        atomicAdd(&deg[d], 1);
    }
}

__global__ void scan1_k(const int* __restrict__ deg, int* __restrict__ csum, int Nd) {
    __shared__ int red[256];
    int base = blockIdx.x * 1024;
    int t = threadIdx.x;
    int s = 0;
    for (int i = 0; i < 4; i++) {
        int idx = base + t * 4 + i;
        if (idx < Nd) s += deg[idx];
    }
    red[t] = s;
    __syncthreads();
    for (int off = 128; off > 0; off >>= 1) {
        if (t < off) red[t] += red[t + off];
        __syncthreads();
    }
    if (t == 0) csum[blockIdx.x] = red[0];
}

__global__ void scan2_k(int* __restrict__ csum, int nch) {
    if (threadIdx.x == 0) {
        int acc = 0;
        for (int i = 0; i < nch; i++) { int v = csum[i]; csum[i] = acc; acc += v; }
    }
}

__global__ void scan3_k(const int* __restrict__ deg, const int* __restrict__ csum,
                        int* __restrict__ starts, int* __restrict__ cur, int Nd) {
    __shared__ int sc[256];
    int base = blockIdx.x * 1024;
    int t = threadIdx.x;
    int v[4];
    int s = 0;
    for (int i = 0; i < 4; i++) {
        int idx = base + t * 4 + i;
        v[i] = idx < Nd ? deg[idx] : 0;
        s += v[i];
    }
    sc[t] = s;
    __syncthreads();
    for (int off = 1; off < 256; off <<= 1) {           // Hillis-Steele inclusive
        int add = (t >= off) ? sc[t - off] : 0;
        __syncthreads();
        sc[t] += add;
        __syncthreads();
    }
    int excl = sc[t] - s + csum[blockIdx.x];
    for (int i = 0; i < 4; i++) {
        int idx = base + t * 4 + i;
        if (idx < Nd) { starts[idx] = excl; cur[idx] = excl; excl += v[i]; }
    }
}

// scatter: build CSR payloads directly. perm (edge id) only if needed (t2),
// srcp = clamped source index always, cmb = packed gate combo if cg given.
__global__ void scatter_k(const int* __restrict__ dst, const int* __restrict__ src,
                          const int* __restrict__ cg, int* __restrict__ cur,
                          int* __restrict__ perm, int* __restrict__ srcp,
                          int* __restrict__ cmb, int E, int Nd, int Ns) {
    int e = blockIdx.x * 256 + threadIdx.x;
    if (e < E) {
        int d = dst[e];
        d = d < 0 ? 0 : (d >= Nd ? Nd - 1 : d);
        int p = atomicAdd(&cur[d], 1);
        if (perm) perm[p] = e;
        int si = src[e];
        si = si < 0 ? 0 : (si >= Ns ? Ns - 1 : si);
        srcp[p] = si;
        if (cmb) {
            int a = cg[2 * e] & 7, b = cg[2 * e + 1] & 7;
            cmb[p] = a * 8 + b;
        }
    }
}

// ---------------------------------------------------------------------------
__global__ void gtbl_k(const float* __restrict__ temb, const float* __restrict__ semb,
                       const float* __restrict__ Wg, const float* __restrict__ bg,
                       float* __restrict__ gtbl) {
    int idx = blockIdx.x * 256 + threadIdx.x;
    if (idx >= 8192) return;
    int combo = idx >> 7, c = idx & 127;
    int a = combo >> 3, b = combo & 7;
    float s = bg[c];
    for (int k = 0; k < 32; k++) s += temb[a * 32 + k] * Wg[k * 128 + c];
    for (int k = 0; k < 32; k++) s += semb[b * 32 + k] * Wg[(32 + k) * 128 + c];
    gtbl[combo * 128 + c] = sigm(s);
}

// ---------------------------------------------------------------------------
// adirect as GEMV: av[k][h] = sum_{c in head h} Wd[k][c]*attn[c];
// bb[h] = sum_{c in head h} bd[c]*attn[c]. Exact reassociation.
__global__ void avprep_k(const float* __restrict__ Wd, const float* __restrict__ bd,
                         const float* __restrict__ at, float* __restrict__ av,
                         float* __restrict__ bb) {
    int k = threadIdx.x;                       // 128 threads
    float a0 = 0.f, a1 = 0.f, a2 = 0.f, a3 = 0.f;
    for (int c = 0; c < 32; c++) {
        a0 += Wd[k * 128 + 0 * 32 + c] * at[0 * 32 + c];
        a1 += Wd[k * 128 + 1 * 32 + c] * at[1 * 32 + c];
        a2 += Wd[k * 128 + 2 * 32 + c] * at[2 * 32 + c];
        a3 += Wd[k * 128 + 3 * 32 + c] * at[3 * 32 + c];
    }
    float4 o; o.x = a0; o.y = a1; o.z = a2; o.w = a3;
    ((float4*)av)[k] = o;
    if (k < 4) {
        float s = 0.f;
        for (int c = 0; c < 32; c++) s += bd[k * 32 + c] * at[k * 32 + c];
        bb[k] = s;
    }
}

__global__ __launch_bounds__(256) void adg_k(const float* __restrict__ x,
                                             const float* __restrict__ av,
                                             const float* __restrict__ bb,
                                             float* __restrict__ ad, int N) {
    int l = threadIdx.x & 63;
    int gw = (blockIdx.x * 256 + threadIdx.x) >> 6;
    int nw = gridDim.x * 4;
    float4 av0 = ((const float4*)av)[2 * l];
    float4 av1 = ((const float4*)av)[2 * l + 1];
    float4 bbv = *(const float4*)bb;
    const float2* x2 = (const float2*)x;
    for (int j = gw; j < N; j += nw) {
        float2 xv = x2[(size_t)j * 64 + l];
        float p0 = xv.x * av0.x + xv.y * av1.x;
        float p1 = xv.x * av0.y + xv.y * av1.y;
        float p2 = xv.x * av0.z + xv.y * av1.z;
        float p3 = xv.x * av0.w + xv.y * av1.w;
        #pragma unroll
        for (int off = 1; off < 64; off <<= 1) {
            p0 += __shfl_xor(p0, off);
            p1 += __shfl_xor(p1, off);
            p2 += __shfl_xor(p2, off);
            p3 += __shfl_xor(p3, off);
        }
        if (l == 0) {
            float4 o; o.x = p0 + bbv.x; o.y = p1 + bbv.y; o.z = p2 + bbv.z; o.w = p3 + bbv.w;
            *(float4*)&ad[(size_t)j * 4] = o;
        }
    }
}

// ---------------------------------------------------------------------------
// Tiled dense: 32-row x tile in LDS (16 KB), 4 waves x 8 rows, 2 ch/lane.
// NIN=1: O = X@W + b. NIN=2: O = (X+Xb)@W + b.
#define STEP4(A, XV)                                     \
    A.x += XV.x * w0.x; A.y += XV.x * w0.y;              \
    A.x += XV.y * w1.x; A.y += XV.y * w1.y;              \
    A.x += XV.z * w2.x; A.y += XV.z * w2.y;              \
    A.x += XV.w * w3.x; A.y += XV.w * w3.y;

template <int NIN>
__global__ __launch_bounds__(256) void denseT_k(const float* __restrict__ X,
                                                const float* __restrict__ Xb,
                                                const float* __restrict__ W,
                                                const float* __restrict__ bias,
                                                float* __restrict__ O, int N, int NT) {
    __shared__ float4 xs4[1024];               // 32 rows x 128 ch = 16 KB
    int t = threadIdx.x;
    int l = t & 63, w = t >> 6;
    float2 bi = *(const float2*)&bias[2 * l];
    const float4* X4 = (const float4*)X;
    const float4* B4 = (const float4*)Xb;
    const float2* Wv = (const float2*)W;
    float2* O2 = (float2*)O;
    for (int tile = blockIdx.x; tile < NT; tile += gridDim.x) {
        int R0 = tile * 32;
        #pragma unroll
        for (int i = 0; i < 4; i++) {
            int idx = t + 256 * i;             // 0..1023 over 512 B tile rows
            int r = R0 + (idx >> 5);
            int rc = min(r, N - 1);
            float4 v = X4[(size_t)rc * 32 + (idx & 31)];
            if (NIN == 2) {
                float4 b = B4[(size_t)rc * 32 + (idx & 31)];
                v.x += b.x; v.y += b.y; v.z += b.z; v.w += b.w;
            }
            xs4[idx] = v;
        }
        __syncthreads();
        float2 a0 = bi, a1 = bi, a2 = bi, a3 = bi, a4 = bi, a5 = bi, a6 = bi, a7 = bi;
        int rb = 8 * w;                        // wave's row base within tile
        #pragma unroll 2
        for (int kb = 0; kb < 32; kb++) {
            float2 w0 = Wv[(4 * kb + 0) * 64 + l];
            float2 w1 = Wv[(4 * kb + 1) * 64 + l];
            float2 w2 = Wv[(4 * kb + 2) * 64 + l];
            float2 w3 = Wv[(4 * kb + 3) * 64 + l];
            float4 x0 = xs4[(rb + 0) * 32 + kb];
            float4 x1 = xs4[(rb + 1) * 32 + kb];
            float4 x2 = xs4[(rb + 2) * 32 + kb];
            float4 x3 = xs4[(rb + 3) * 32 + kb];
            float4 x4v = xs4[(rb + 4) * 32 + kb];
            float4 x5 = xs4[(rb + 5) * 32 + kb];
            float4 x6 = xs4[(rb + 6) * 32 + kb];
            float4 x7 = xs4[(rb + 7) * 32 + kb];
            STEP4(a0, x0) STEP4(a1, x1) STEP4(a2, x2) STEP4(a3, x3)
            STEP4(a4, x4v) STEP4(a5, x5) STEP4(a6, x6) STEP4(a7, x7)
        }
        int rbase = R0 + rb;
        if (rbase + 0 < N) O2[(size_t)(rbase + 0) * 64 + l] = a0;
        if (rbase + 1 < N) O2[(size_t)(rbase + 1) * 64 + l] = a1;
        if (rbase + 2 < N) O2[(size_t)(rbase + 2) * 64 + l] = a2;
        if (rbase + 3 < N) O2[(size_t)(rbase + 3) * 64 + l] = a3;
        if (rbase + 4 < N) O2[(size_t)(rbase + 4) * 64 + l] = a4;
        if (rbase + 5 < N) O2[(size_t)(rbase + 5) * 64 + l] = a5;
        if (rbase + 6 < N) O2[(size_t)(rbase + 6) * 64 + l] = a6;
        if (rbase + 7 < N) O2[(size_t)(rbase + 7) * 64 + l] = a7;
        __syncthreads();
    }
}

// bias-only rows (disease output)
__global__ void biasrow_k(const float* __restrict__ bo, float* __restrict__ out, int N) {
    int idx = blockIdx.x * 256 + threadIdx.x;
    if (idx < N * 64) {
        float2 bi = *(const float2*)&bo[2 * (idx & 63)];
        ((float2*)out)[idx] = bi;
    }
}

// ---------------------------------------------------------------------------
// t2 gate via MFMA.
// w2pack: B-fragment order for mfma_f32_16x16x32_f16. Lane l = c + 16*g
// holds B[8g+i][c]; tile (ct, kb) covers cols 16ct..16ct+15, k 32kb..32kb+31.
// w2p[((ct*4+kb)*64 + l)*8 + i] = (f16) W2[32kb + 8*(l>>4) + i][16ct + (l&15)]
__global__ void w2pack_k(const float* __restrict__ W2c, u16* __restrict__ w2p) {
    int t = blockIdx.x * 256 + threadIdx.x;    // 0..2047
    if (t >= 2048) return;
    int l = t & 63;
    int tile = t >> 6;                         // ct*4 + kb
    int ct = tile >> 2, kb = tile & 3;
    int k0 = kb * 32 + (l >> 4) * 8;
    int c  = ct * 16 + (l & 15);
    for (int i = 0; i < 8; i++) {
        HSU cv; cv.f = (_Float16)W2c[(k0 + i) * 128 + c];
        w2p[(size_t)t * 8 + i] = cv.s;
    }
}

// ugen: one wave per edge (perm order); u = gelu(cp@W1 + b1) -> f16 into gate rows.
__global__ __launch_bounds__(256) void ugen_k(const float* __restrict__ cp,
                                              const float* __restrict__ W1c, const float* __restrict__ b1c,
                                              const int* __restrict__ perm, const int* __restrict__ starts,
                                              u16* __restrict__ gate,
                                              int j0, int j1, int NP_, int E, int CAP) {
    int lane = threadIdx.x & 63;
    int wv = (blockIdx.x * 256 + threadIdx.x) >> 6;
    int nw = gridDim.x * 4;
    int q0 = starts[j0];
    int q1 = (j1 >= NP_) ? E : starts[j1];
    int cnt = min(q1 - q0, CAP);
    int c0 = 2 * lane;
    float w1a = W1c[c0],     w1b = W1c[128 + c0],     w1c_ = W1c[256 + c0];
    float w1d = W1c[c0 + 1], w1e = W1c[128 + c0 + 1], w1f  = W1c[256 + c0 + 1];
    float b1a = b1c[c0], b1b = b1c[c0 + 1];
    unsigned* g32 = (unsigned*)gate;
    for (int qr = wv; qr < cnt; qr += nw) {
        int e = __builtin_amdgcn_readfirstlane(perm[q0 + qr]);
        float p0 = cp[(size_t)e * 3 + 0];
        float p1 = cp[(size_t)e * 3 + 1];
        float p2 = cp[(size_t)e * 3 + 2];
        float z0 = b1a + p0 * w1a + p1 * w1b + p2 * w1c_;
        float z1 = b1b + p0 * w1d + p1 * w1e + p2 * w1f;
        float u0 = 0.5f * z0 * (1.f + erff(z0 * 0.70710678118654752f));
        float u1 = 0.5f * z1 * (1.f + erff(z1 * 0.70710678118654752f));
        HSU h0; h0.f = (_Float16)u0;
        HSU h1; h1.f = (_Float16)u1;
        g32[(size_t)qr * 64 + lane] = ((unsigned)h1.s << 16) | h0.s;
    }
}

// gmm: one wave per 16-edge row-block; gate = sigmoid(u @ W2 + b2) IN PLACE.
// A-frag (kb): lane l holds u[r0 + (l&15)][32kb + 8*(l>>4) .. +7] (one dwordx4).
// C/D: col = lane&15, row = (lane>>4)*4 + reg (m89-verified).
__global__ __launch_bounds__(256) void gmm_k(const u16* __restrict__ w2p,
                                             const float* __restrict__ b2c,
                                             const int* __restrict__ starts,
                                             u16* __restrict__ gate,
                                             int j0, int j1, int NP_, int E, int CAP) {
    int lane = threadIdx.x & 63;
    int wv = (blockIdx.x * 256 + threadIdx.x) >> 6;
    int nw = gridDim.x * 4;
    int q0 = starts[j0];
    int q1 = (j1 >= NP_) ? E : starts[j1];
    int cnt = min(q1 - q0, CAP);
    if (cnt <= 0) return;
    int nrb = (cnt + 15) >> 4;
    const uint4* wp4 = (const uint4*)w2p;
    int colr = lane & 15, grp = lane >> 4;
    for (int rb = wv; rb < nrb; rb += nw) {
        int r0 = rb * 16;
        int arow = r0 + colr;
        if (arow >= cnt) arow = cnt - 1;       // clamp stays within this block
        const uint4* urow = (const uint4*)(gate + (size_t)arow * 128);
        U4F8 a0, a1, a2, a3;
        a0.u = urow[0 * 4 + grp];
        a1.u = urow[1 * 4 + grp];
        a2.u = urow[2 * 4 + grp];
        a3.u = urow[3 * 4 + grp];
        f32x4 res[8];
        #pragma unroll
        for (int ct = 0; ct < 8; ct++) {
            float b2v = b2c[ct * 16 + colr];
            f32x4 acc = {b2v, b2v, b2v, b2v};
            U4F8 b0, b1, b2, b3;
            b0.u = wp4[(ct * 4 + 0) * 64 + lane];
            b1.u = wp4[(ct * 4 + 1) * 64 + lane];
            b2.u = wp4[(ct * 4 + 2) * 64 + lane];
            b3.u = wp4[(ct * 4 + 3) * 64 + lane];
            acc = __builtin_amdgcn_mfma_f32_16x16x32_f16(a0.h, b0.h, acc, 0, 0, 0);
            acc = __builtin_amdgcn_mfma_f32_16x16x32_f16(a1.h, b1.h, acc, 0, 0, 0);
            acc = __builtin_amdgcn_mfma_f32_16x16x32_f16(a2.h, b2.h, acc, 0, 0, 0);
            acc = __builtin_amdgcn_mfma_f32_16x16x32_f16(a3.h, b3.h, acc, 0, 0, 0);
            res[ct] = acc;
        }
        #pragma unroll
        for (int ct = 0; ct < 8; ct++) {
            int col = ct * 16 + colr;
            #pragma unroll
            for (int r = 0; r < 4; r++) {
                int row = r0 + grp * 4 + r;
                if (row < cnt) {
                    HSU cv; cv.f = (_Float16)sigm(res[ct][r]);
                    gate[(size_t)row * 128 + col] = cv.s;
                }
            }
        }
    }
}

// ---------------------------------------------------------------------------
// Gather aggregation: ONE destination per wave, FOUR edges batched per
// iteration. MODE 0: plain. MODE 1: gate table via cmb. MODE 3: f16 gate.
#define AGG_LOAD(K, ACT)                                                     \
    float2 hv##K; float2 gv##K; unsigned gu##K = 0;                          \
    if (ACT) {                                                               \
        int si = srcp[st + q + K];                                           \
        hv##K = hs2v[(size_t)si * 64 + lane];                                \
        if (MODE == 1) { int ab = cmb[st + q + K]; gv##K = gt2v[ab * 64 + lane]; } \
        if (MODE == 3) { int qq = st + q + K - q0base;                       \
                         qq = qq < 79999 ? qq : 79999;                       \
                         gu##K = g32[(size_t)qq * 64 + lane]; }              \
    }

#define AGG_UPD(K, ACT)                                                      \
    if (ACT) {                                                               \
        float mx = hv##K.x, my = hv##K.y;                                    \
        if (MODE == 1) { mx *= gv##K.x; my *= gv##K.y; }                     \
        if (MODE == 3) { H2U gz; gz.u = gu##K; mx *= (float)gz.h.x; my *= (float)gz.h.y; } \
        float p = mx * ax + my * ay;                                         \
        p += __shfl_xor(p, 1); p += __shfl_xor(p, 2);                        \
        p += __shfl_xor(p, 4); p += __shfl_xor(p, 8);                        \
        float logit = p + adv;                                               \
        logit = logit > 0.f ? logit : 0.2f * logit;                          \
        if (logit > mm) {                                                    \
            float r = expf(mm - logit);                                      \
            ss *= r; vx *= r; vy *= r; mm = logit;                           \
        }                                                                    \
        float ex = expf(logit - mm);                                         \
        ss += ex; vx += ex * mx; vy += ex * my;                              \
    }

template <int MODE>
__global__ __launch_bounds__(256) void agg_k(const float* __restrict__ hs,
                                             const float* __restrict__ ad,
                                             const int* __restrict__ srcp,
                                             const int* __restrict__ cmb,
                                             const int* __restrict__ starts,
                                             const int* __restrict__ deg,
                                             const float* __restrict__ attn_t,
                                             const float* __restrict__ gtbl,
                                             const u16* __restrict__ gate,
                                             float* __restrict__ agg,
                                             int j0, int j1) {
    int lane = threadIdx.x & 63;
    int gw = (blockIdx.x * 256 + threadIdx.x) >> 6;
    int nw = gridDim.x * 4;
    int c0 = 2 * lane;
    float ax = attn_t[c0], ay = attn_t[c0 + 1];
    int h = lane >> 4;
    const float2* hs2v = (const float2*)hs;
    const float2* gt2v = (const float2*)gtbl;
    const unsigned* g32 = (const unsigned*)gate;
    float2* agg2v = (float2*)agg;
    int q0base = 0;
    if (MODE == 3) q0base = __builtin_amdgcn_readfirstlane(starts[j0]);
    for (int j = j0 + gw; j < j1; j += nw) {
        int st = __builtin_amdgcn_readfirstlane(starts[j]);
        int n  = __builtin_amdgcn_readfirstlane(deg[j]);
        float adv = ad[(size_t)j * 4 + h];
        float mm = -3.0e38f, ss = 0.f, vx = 0.f, vy = 0.f;
        for (int q = 0; q < n; q += 4) {
            bool b1 = q + 1 < n, b2 = q + 2 < n, b3 = q + 3 < n;
            AGG_LOAD(0, true) AGG_LOAD(1, b1) AGG_LOAD(2, b2) AGG_LOAD(3, b3)
            AGG_UPD(0, true) AGG_UPD(1, b1) AGG_UPD(2, b2) AGG_UPD(3, b3)
        }
        float inv = ss > 0.f ? 1.f / ss : 0.f;
        float2 o; o.x = vx * inv; o.y = vy * inv;
        agg2v[(size_t)j * 64 + lane] = o;
    }
}

// ---------------------------------------------------------------------------
extern "C" void kernel_launch(void* const* d_in, const int* in_sizes, int n_in,
                              void* d_out, int out_size, void* d_ws, size_t ws_size,
                              hipStream_t stream) {
    static const int expect[29] = {
        6400000, 3840000, 1280000, 640000,
        500000, 500000, 500000, 500000, 250000, 250000, 250000, 250000,
        1000000, 750000, 65536, 512, 65536, 512, 512, 320, 256,
        8192, 128, 384, 128, 16384, 128, 65536, 512};
    int bad = 0;
    if (n_in != 29) bad = 1;
    else {
        for (int i = 0; i < 29; i++)
            if (in_sizes[i] != expect[i]) { bad = 4 + i; break; }
    }
    if (!bad && out_size != 12160000) bad = 2;
    if (!bad && ws_size < (size_t)63425536) bad = 3;
    if (bad) {
        senthost_k<<<1, 1, 0, stream>>>((float*)d_out, 4096.f * (float)bad);
        return;
    }

    const float* x_chem = (const float*)d_in[0];
    const float* x_gene = (const float*)d_in[1];
    const float* x_dis  = (const float*)d_in[2];
    const float* x_path = (const float*)d_in[3];
    const int* src0 = (const int*)d_in[4];  const int* dst0 = (const int*)d_in[5];
    const int* src1 = (const int*)d_in[6];  const int* dst1 = (const int*)d_in[7];
    const int* src2 = (const int*)d_in[8];  const int* dst2 = (const int*)d_in[9];
    const int* src3 = (const int*)d_in[10]; const int* dst3 = (const int*)d_in[11];
    const int*   cg   = (const int*)d_in[12];
    const float* cp   = (const float*)d_in[13];
    const float* Wsrc = (const float*)d_in[14]; const float* bsrc = (const float*)d_in[15];
    const float* Wdst = (const float*)d_in[16]; const float* bdst = (const float*)d_in[17];
    const float* attn = (const float*)d_in[18];
    const float* temb = (const float*)d_in[19]; const float* semb = (const float*)d_in[20];
    const float* Wg   = (const float*)d_in[21]; const float* bg   = (const float*)d_in[22];
    const float* W1c  = (const float*)d_in[23]; const float* b1c  = (const float*)d_in[24];
    const float* W2c  = (const float*)d_in[25]; const float* b2c  = (const float*)d_in[26];
    const float* Wout = (const float*)d_in[27]; const float* bout = (const float*)d_in[28];

    constexpr int NC = 50000, NG = 30000, ND = 10000, NP = 5000;
    constexpr int E0 = 500000, E1 = 500000, E2 = 250000, E3 = 250000;
    constexpr int GCAP = 80000;

    char* ws = (char*)d_ws;
    float* gt   = (float*)ws;              // [64][128] f32 = 32768 B
    int*   csum = (int*)(ws + 32768);      // chunk sums for scan (<=49 ints)
    float* avb  = (float*)(ws + 36864);    // 4 slots x 520 floats = 8320 B
    u16*   w2p  = (u16*)  (ws + 49152);    // packed W2 fragments, 32768 B
    char*  A    = ws + 98304;              // stage arena (stage C peak 61.64 MB -> 61.74 MB total, fits)

    float* out = (float*)d_out;
    float* out_chem = out;
    float* out_gene = out + (size_t)NC * 128;
    float* out_dis  = out + (size_t)(NC + NG) * 128;
    float* out_path = out + (size_t)(NC + NG + ND) * 128;

    // per-slot: av = 512 floats, bb = 4 floats, pad to 520
    float* av1 = avb + 0 * 520; float* bb1 = av1 + 512;
    float* av2 = avb + 1 * 520; float* bb2 = av2 + 512;
    float* av0 = avb + 2 * 520; float* bb0 = av0 + 512;
    float* av3 = avb + 3 * 520; float* bb3 = av3 + 512;

    gtbl_k<<<32, 256, 0, stream>>>(temb, semb, Wg, bg, gt);
    avprep_k<<<1, 128, 0, stream>>>(Wdst + 1 * 16384, bdst + 1 * 128, attn + 1 * 128, av1, bb1);
    avprep_k<<<1, 128, 0, stream>>>(Wdst + 2 * 16384, bdst + 2 * 128, attn + 2 * 128, av2, bb2);
    avprep_k<<<1, 128, 0, stream>>>(Wdst + 0 * 16384, bdst + 0 * 128, attn + 0 * 128, av0, bb0);
    avprep_k<<<1, 128, 0, stream>>>(Wdst + 3 * 16384, bdst + 3 * 128, attn + 3 * 128, av3, bb3);
    w2pack_k<<<8, 256, 0, stream>>>(W2c, w2p);

    // ---------- STAGE A: chemical output (t1: gene -> chemical) ----------
    {
        float* hs1  = (float*)(A);                 //  0 .. 15,360,000
        float* ad1  = (float*)(A + 15360000);      // .. 16,160,000
        int*   deg  = (int*)  (A + 16160000);      // .. 16,360,000
        int*   sts  = (int*)  (A + 16360000);      // .. 16,560,000
        int*   cur  = (int*)  (A + 16560000);      // .. 16,760,000
        int*   srcpA = (int*) (A + 16760000);      // .. 18,760,000
        float* agg1 = (float*)(A + 18760000);      // .. 44,360,000
        int nch = (NC + 1023) / 1024;
        zero_k<<<(NC + 255) / 256, 256, 0, stream>>>((float*)deg, NC);
        hist_k<<<(E1 + 255) / 256, 256, 0, stream>>>(dst1, deg, E1, NC);
        scan1_k<<<nch, 256, 0, stream>>>(deg, csum, NC);
        scan2_k<<<1, 64, 0, stream>>>(csum, nch);
        scan3_k<<<nch, 256, 0, stream>>>(deg, csum, sts, cur, NC);
        scatter_k<<<(E1 + 255) / 256, 256, 0, stream>>>(dst1, src1, nullptr, cur,
                                                        nullptr, srcpA, nullptr, E1, NC, NG);
        denseT_k<1><<<(NG + 31) / 32, 256, 0, stream>>>(x_gene, nullptr,
                                                        Wsrc + 1 * 16384, bsrc + 1 * 128, hs1, NG, (NG + 31) / 32);
        adg_k<<<1024, 256, 0, stream>>>(x_chem, av1, bb1, ad1, NC);
        agg_k<0><<<2048, 256, 0, stream>>>(hs1, ad1, srcpA, nullptr, sts, deg,
                                           attn + 1 * 128, nullptr, nullptr, agg1, 0, NC);
        denseT_k<1><<<(NC + 31) / 32, 256, 0, stream>>>(agg1, nullptr,
                                                        Wout + 0 * 16384, bout + 0 * 128, out_chem, NC, (NC + 31) / 32);
    }

    // ---------- STAGE B: pathway output (t2: chemical -> pathway) ----------
    {
        float* hs2  = (float*)(A);                 //  0 .. 25,600,000
        float* ad2  = (float*)(A + 25600000);      // .. 25,680,000
        int*   deg  = (int*)  (A + 25680000);      // .. 25,700,000
        int*   sts  = (int*)  (A + 25700000);      // .. 25,720,000
        int*   cur  = (int*)  (A + 25720000);      // .. 25,740,000
        int*   perm = (int*)  (A + 25740000);      // .. 26,740,000
        int*   srcpB = (int*) (A + 26740000);      // .. 27,740,000
        float* agg2 = (float*)(A + 27740000);      // .. 30,300,000
        u16*   gatep = (u16*) (A + 30300000);      // .. 50,780,000
        int nch = (NP + 1023) / 1024;
        zero_k<<<(NP + 255) / 256, 256, 0, stream>>>((float*)deg, NP);
        hist_k<<<(E2 + 255) / 256, 256, 0, stream>>>(dst2, deg, E2, NP);
        scan1_k<<<nch, 256, 0, stream>>>(deg, csum, NP);
        scan2_k<<<1, 64, 0, stream>>>(csum, nch);
        scan3_k<<<nch, 256, 0, stream>>>(deg, csum, sts, cur, NP);
        scatter_k<<<(E2 + 255) / 256, 256, 0, stream>>>(dst2, src2, nullptr, cur,
                                                        perm, srcpB, nullptr, E2, NP, NC);
        denseT_k<1><<<(NC + 31) / 32, 256, 0, stream>>>(x_chem, nullptr,
                                                        Wsrc + 2 * 16384, bsrc + 2 * 128, hs2, NC, (NC + 31) / 32);
        adg_k<<<256, 256, 0, stream>>>(x_path, av2, bb2, ad2, NP);
        for (int ck = 0; ck < 4; ck++) {
            int j0 = ck * 1250, j1 = j0 + 1250;
            ugen_k<<<2048, 256, 0, stream>>>(cp, W1c, b1c, perm, sts, gatep,
                                             j0, j1, NP, E2, GCAP);
            gmm_k<<<1024, 256, 0, stream>>>(w2p, b2c, sts, gatep,
                                            j0, j1, NP, E2, GCAP);
            agg_k<3><<<313, 256, 0, stream>>>(hs2, ad2, srcpB, nullptr, sts, deg,
                                              attn + 2 * 128, nullptr, gatep, agg2, j0, j1);
        }
        denseT_k<1><<<(NP + 31) / 32, 256, 0, stream>>>(agg2, nullptr,
                                                        Wout + 3 * 16384, bout + 3 * 128, out_path, NP, (NP + 31) / 32);
    }

    // ---------- STAGE C: gene output (t0 + t3, sequential buffer reuse) -----
    {
        float* ad0  = (float*)(A + 25600000);      // .. 26,080,000
        float* ad3  = (float*)(A + 26080000);      // .. 26,560,000 (survives)
        int*   deg  = (int*)  (A + 26560000);      // .. 26,680,000
        int*   sts  = (int*)  (A + 26680000);      // .. 26,800,000
        int*   cur  = (int*)  (A + 26800000);      // .. 26,920,000
        int*   srcpC = (int*) (A + 26920000);      // .. 28,920,000
        int*   cmbp = (int*)  (A + 28920000);      // .. 30,920,000
        float* agg0 = (float*)(A + 30920000);      // .. 46,280,000
        float* agg3 = (float*)(A + 46280000);      // .. 61,640,000
        int nch = (NG + 1023) / 1024;

        // phase 1: t0 chemical -> gene (categorical gate)
        float* hs0 = (float*)(A);                  //  0 .. 25,600,000
        zero_k<<<(NG + 255) / 256, 256, 0, stream>>>((float*)deg, NG);
        hist_k<<<(E0 + 255) / 256, 256, 0, stream>>>(dst0, deg, E0, NG);
        scan1_k<<<nch, 256, 0, stream>>>(deg, csum, NG);
        scan2_k<<<1, 64, 0, stream>>>(csum, nch);
        scan3_k<<<nch, 256, 0, stream>>>(deg, csum, sts, cur, NG);
        scatter_k<<<(E0 + 255) / 256, 256, 0, stream>>>(dst0, src0, cg, cur,
                                                        nullptr, srcpC, cmbp, E0, NG, NC);
        denseT_k<1><<<(NC + 31) / 32, 256, 0, stream>>>(x_chem, nullptr,
                                                        Wsrc + 0 * 16384, bsrc + 0 * 128, hs0, NC, (NC + 31) / 32);
        adg_k<<<1024, 256, 0, stream>>>(x_gene, av0, bb0, ad0, NG);
        adg_k<<<1024, 256, 0, stream>>>(x_gene, av3, bb3, ad3, NG);
        agg_k<1><<<2048, 256, 0, stream>>>(hs0, ad0, srcpC, cmbp, sts, deg,
                                           attn + 0 * 128, gt, nullptr, agg0, 0, NG);

        // phase 2: t3 disease -> gene (plain), reusing hs/CSR buffers
        float* hs3 = (float*)(A);                  //  0 .. 5,120,000
        zero_k<<<(NG + 255) / 256, 256, 0, stream>>>((float*)deg, NG);
        hist_k<<<(E3 + 255) / 256, 256, 0, stream>>>(dst3, deg, E3, NG);
        scan1_k<<<nch, 256, 0, stream>>>(deg, csum, NG);
        scan2_k<<<1, 64, 0, stream>>>(csum, nch);
        scan3_k<<<nch, 256, 0, stream>>>(deg, csum, sts, cur, NG);
        scatter_k<<<(E3 + 255) / 256, 256, 0, stream>>>(dst3, src3, nullptr, cur,
                                                        nullptr, srcpC, nullptr, E3, NG, ND);
        denseT_k<1><<<(ND + 31) / 32, 256, 0, stream>>>(x_dis, nullptr,
                                                        Wsrc + 3 * 16384, bsrc + 3 * 128, hs3, ND, (ND + 31) / 32);
        agg_k<0><<<2048, 256, 0, stream>>>(hs3, ad3, srcpC, nullptr, sts, deg,
                                           attn + 3 * 128, nullptr, nullptr, agg3, 0, NG);
        denseT_k<2><<<(NG + 31) / 32, 256, 0, stream>>>(agg0, agg3,
                                                        Wout + 1 * 16384, bout + 1 * 128, out_gene, NG, (NG + 31) / 32);
    }

    // ---------- STAGE D: disease output (no incoming edges: bias only) ------
    biasrow_k<<<(ND * 64 + 255) / 256, 256, 0, stream>>>(bout + 2 * 128, out_dis, ND);
}

// Round 12
// 964.513 us; speedup vs baseline: 2.3615x; 1.0299x over previous
//
#include <hip/hip_runtime.h>

// EdgeAttrHeteroConv — round 19 (= R18 resubmitted verbatim; R18 died on
// GPUAcquisitionTimeout before any measurement; audit re-done: hsa buffers
// in-bounds, MODE4 reduce order bit-identical, clamp path R7-verified).
// R17 = 993 us; top dispatch agg_k<1> (t0) 59 us, VALUBusy ~60%, HBM 28%
// -> gather loop is VALU-bound. This round:
// (a) clamp-softmax (drop online-max rescale; logits O(5), R7-verified) +
//     __expf (hw v_exp_f32);
// (b) MODE 4 for ungated t1/t3: logit dot is per-SOURCE -> hsa_k
//     precomputes hsa[si][h] (identical reduce order -> bit-identical p);
//     edge loop = broadcast load + leaky + clamp + __expf + 3 FMA;
// (c) 8-wide edge batching (more MLP);
// (d) prep fusion: gtbl+avprep x4+w2pack -> one prep_k (-5 dispatches).
// Everything else identical to R17 (verified 993 us, absmax 1.95e-3).

typedef unsigned short u16;
typedef _Float16 h2_t __attribute__((ext_vector_type(2)));
typedef _Float16 f16x8 __attribute__((ext_vector_type(8)));
typedef float f32x4 __attribute__((ext_vector_type(4)));
union H2U { unsigned u; h2_t h; };
union HSU { _Float16 f; unsigned short s; };
union U4F8 { uint4 u; f16x8 h; };

__device__ __forceinline__ float sigm(float x) { return 1.f / (1.f + expf(-x)); }

// ---------------------------------------------------------------------------
__global__ void zero_k(float* __restrict__ p, int n) {
    int i = blockIdx.x * 256 + threadIdx.x;
    if (i < n) p[i] = 0.f;
}

__global__ void senthost_k(float* out, float v) { out[0] = v; }

// ---------------------------------------------------------------------------
// CSR build: histogram -> 3-kernel exclusive scan (1024-elem chunks) -> scatter
__global__ void hist_k(const int* __restrict__ dst, int* __restrict__ deg, int E, int Nd) {
    int e = blockIdx.x * 256 + threadIdx.x;
    if (e < E) {
        int d = dst[e];
        d = d < 0 ? 0 : (d >= Nd ? Nd - 1 : d);
        atomicAdd(&deg[d], 1);
    }
}

__global__ void scan1_k(const int* __restrict__ deg, int* __restrict__ csum, int Nd) {
    __shared__ int red[256];
    int base = blockIdx.x * 1024;
    int t = threadIdx.x;
    int s = 0;
    for (int i = 0; i < 4; i++) {
        int idx = base + t * 4 + i;
        if (idx < Nd) s += deg[idx];
    }
    red[t] = s;
    __syncthreads();
    for (int off = 128; off > 0; off >>= 1) {
        if (t < off) red[t] += red[t + off];
        __syncthreads();
    }
    if (t == 0) csum[blockIdx.x] = red[0];
}

__global__ void scan2_k(int* __restrict__ csum, int nch) {
    if (threadIdx.x == 0) {
        int acc = 0;
        for (int i = 0; i < nch; i++) { int v = csum[i]; csum[i] = acc; acc += v; }
    }
}

__global__ void scan3_k(const int* __restrict__ deg, const int* __restrict__ csum,
                        int* __restrict__ starts, int* __restrict__ cur, int Nd) {
    __shared__ int sc[256];
    int base = blockIdx.x * 1024;
    int t = threadIdx.x;
    int v[4];
    int s = 0;
    for (int i = 0; i < 4; i++) {
        int idx = base + t * 4 + i;
        v[i] = idx < Nd ? deg[idx] : 0;
        s += v[i];
    }
    sc[t] = s;
    __syncthreads();
    for (int off = 1; off < 256; off <<= 1) {           // Hillis-Steele inclusive
        int add = (t >= off) ? sc[t - off] : 0;
        __syncthreads();
        sc[t] += add;
        __syncthreads();
    }
    int excl = sc[t] - s + csum[blockIdx.x];
    for (int i = 0; i < 4; i++) {
        int idx = base + t * 4 + i;
        if (idx < Nd) { starts[idx] = excl; cur[idx] = excl; excl += v[i]; }
    }
}

// scatter: build CSR payloads directly. perm (edge id) only if needed (t2),
// srcp = clamped source index always, cmb = packed gate combo if cg given.
__global__ void scatter_k(const int* __restrict__ dst, const int* __restrict__ src,
                          const int* __restrict__ cg, int* __restrict__ cur,
                          int* __restrict__ perm, int* __restrict__ srcp,
                          int* __restrict__ cmb, int E, int Nd, int Ns) {
    int e = blockIdx.x * 256 + threadIdx.x;
    if (e < E) {
        int d = dst[e];
        d = d < 0 ? 0 : (d >= Nd ? Nd - 1 : d);
        int p = atomicAdd(&cur[d], 1);
        if (perm) perm[p] = e;
        int si = src[e];
        si = si < 0 ? 0 : (si >= Ns ? Ns - 1 : si);
        srcp[p] = si;
        if (cmb) {
            int a = cg[2 * e] & 7, b = cg[2 * e + 1] & 7;
            cmb[p] = a * 8 + b;
        }
    }
}

// ---------------------------------------------------------------------------
// Fused prep: gtbl (blocks 0..31), avprep x4 (blocks 32..35), w2pack (36..43).
// av layout: avb + type*520 (512 av + 4 bb + pad).
__global__ void prep_k(const float* __restrict__ temb, const float* __restrict__ semb,
                       const float* __restrict__ Wg, const float* __restrict__ bg,
                       float* __restrict__ gtbl,
                       const float* __restrict__ Wdst, const float* __restrict__ bdst,
                       const float* __restrict__ attn, float* __restrict__ avb,
                       const float* __restrict__ W2c, u16* __restrict__ w2p) {
    int b = blockIdx.x;
    if (b < 32) {
        int idx = b * 256 + threadIdx.x;
        int combo = idx >> 7, c = idx & 127;
        int a = combo >> 3, bb_ = combo & 7;
        float s = bg[c];
        for (int k = 0; k < 32; k++) s += temb[a * 32 + k] * Wg[k * 128 + c];
        for (int k = 0; k < 32; k++) s += semb[bb_ * 32 + k] * Wg[(32 + k) * 128 + c];
        gtbl[combo * 128 + c] = sigm(s);
    } else if (b < 36) {
        if (threadIdx.x < 128) {
            int ty = b - 32;
            const float* Wd = Wdst + ty * 16384;
            const float* bd = bdst + ty * 128;
            const float* at = attn + ty * 128;
            float* av = avb + ty * 520;
            float* bb = av + 512;
            int k = threadIdx.x;
            float a0 = 0.f, a1 = 0.f, a2 = 0.f, a3 = 0.f;
            for (int c = 0; c < 32; c++) {
                a0 += Wd[k * 128 + 0 * 32 + c] * at[0 * 32 + c];
                a1 += Wd[k * 128 + 1 * 32 + c] * at[1 * 32 + c];
                a2 += Wd[k * 128 + 2 * 32 + c] * at[2 * 32 + c];
                a3 += Wd[k * 128 + 3 * 32 + c] * at[3 * 32 + c];
            }
            float4 o; o.x = a0; o.y = a1; o.z = a2; o.w = a3;
            ((float4*)av)[k] = o;
            if (k < 4) {
                float s = 0.f;
                for (int c = 0; c < 32; c++) s += bd[k * 32 + c] * at[k * 32 + c];
                bb[k] = s;
            }
        }
    } else {
        int t = (b - 36) * 256 + threadIdx.x;    // 0..2047
        if (t < 2048) {
            int l = t & 63;
            int tile = t >> 6;                   // ct*4 + kb
            int ct = tile >> 2, kb = tile & 3;
            int k0 = kb * 32 + (l >> 4) * 8;
            int c  = ct * 16 + (l & 15);
            for (int i = 0; i < 8; i++) {
                HSU cv; cv.f = (_Float16)W2c[(k0 + i) * 128 + c];
                w2p[(size_t)t * 8 + i] = cv.s;
            }
        }
    }
}

// ---------------------------------------------------------------------------
__global__ __launch_bounds__(256) void adg_k(const float* __restrict__ x,
                                             const float* __restrict__ av,
                                             const float* __restrict__ bb,
                                             float* __restrict__ ad, int N) {
    int l = threadIdx.x & 63;
    int gw = (blockIdx.x * 256 + threadIdx.x) >> 6;
    int nw = gridDim.x * 4;
    float4 av0 = ((const float4*)av)[2 * l];
    float4 av1 = ((const float4*)av)[2 * l + 1];
    float4 bbv = *(const float4*)bb;
    const float2* x2 = (const float2*)x;
    for (int j = gw; j < N; j += nw) {
        float2 xv = x2[(size_t)j * 64 + l];
        float p0 = xv.x * av0.x + xv.y * av1.x;
        float p1 = xv.x * av0.y + xv.y * av1.y;
        float p2 = xv.x * av0.z + xv.y * av1.z;
        float p3 = xv.x * av0.w + xv.y * av1.w;
        #pragma unroll
        for (int off = 1; off < 64; off <<= 1) {
            p0 += __shfl_xor(p0, off);
            p1 += __shfl_xor(p1, off);
            p2 += __shfl_xor(p2, off);
            p3 += __shfl_xor(p3, off);
        }
        if (l == 0) {
            float4 o; o.x = p0 + bbv.x; o.y = p1 + bbv.y; o.z = p2 + bbv.z; o.w = p3 + bbv.w;
            *(float4*)&ad[(size_t)j * 4] = o;
        }
    }
}

// hsa[j][h] = sum_{c in head h} hs[j][c]*attn_t[c] — same reduce order as
// the former in-agg dot, so the logit p is bit-identical.
__global__ __launch_bounds__(256) void hsa_k(const float* __restrict__ hs,
                                             const float* __restrict__ attn_t,
                                             float* __restrict__ hsa, int N) {
    int l = threadIdx.x & 63;
    int gw = (blockIdx.x * 256 + threadIdx.x) >> 6;
    int nw = gridDim.x * 4;
    int c0 = 2 * l;
    float ax = attn_t[c0], ay = attn_t[c0 + 1];
    int h = l >> 4;
    const float2* hs2 = (const float2*)hs;
    for (int j = gw; j < N; j += nw) {
        float2 hv = hs2[(size_t)j * 64 + l];
        float p = hv.x * ax + hv.y * ay;
        p += __shfl_xor(p, 1);
        p += __shfl_xor(p, 2);
        p += __shfl_xor(p, 4);
        p += __shfl_xor(p, 8);
        if ((l & 15) == 0) hsa[(size_t)j * 4 + h] = p;
    }
}

// ---------------------------------------------------------------------------
// Tiled dense: 32-row x tile in LDS (16 KB), 4 waves x 8 rows, 2 ch/lane.
#define STEP4(A, XV)                                     \
    A.x += XV.x * w0.x; A.y += XV.x * w0.y;              \
    A.x += XV.y * w1.x; A.y += XV.y * w1.y;              \
    A.x += XV.z * w2.x; A.y += XV.z * w2.y;              \
    A.x += XV.w * w3.x; A.y += XV.w * w3.y;

template <int NIN>
__global__ __launch_bounds__(256) void denseT_k(const float* __restrict__ X,
                                                const float* __restrict__ Xb,
                                                const float* __restrict__ W,
                                                const float* __restrict__ bias,
                                                float* __restrict__ O, int N, int NT) {
    __shared__ float4 xs4[1024];               // 32 rows x 128 ch = 16 KB
    int t = threadIdx.x;
    int l = t & 63, w = t >> 6;
    float2 bi = *(const float2*)&bias[2 * l];
    const float4* X4 = (const float4*)X;
    const float4* B4 = (const float4*)Xb;
    const float2* Wv = (const float2*)W;
    float2* O2 = (float2*)O;
    for (int tile = blockIdx.x; tile < NT; tile += gridDim.x) {
        int R0 = tile * 32;
        #pragma unroll
        for (int i = 0; i < 4; i++) {
            int idx = t + 256 * i;
            int r = R0 + (idx >> 5);
            int rc = min(r, N - 1);
            float4 v = X4[(size_t)rc * 32 + (idx & 31)];
            if (NIN == 2) {
                float4 b = B4[(size_t)rc * 32 + (idx & 31)];
                v.x += b.x; v.y += b.y; v.z += b.z; v.w += b.w;
            }
            xs4[idx] = v;
        }
        __syncthreads();
        float2 a0 = bi, a1 = bi, a2 = bi, a3 = bi, a4 = bi, a5 = bi, a6 = bi, a7 = bi;
        int rb = 8 * w;
        #pragma unroll 2
        for (int kb = 0; kb < 32; kb++) {
            float2 w0 = Wv[(4 * kb + 0) * 64 + l];
            float2 w1 = Wv[(4 * kb + 1) * 64 + l];
            float2 w2 = Wv[(4 * kb + 2) * 64 + l];
            float2 w3 = Wv[(4 * kb + 3) * 64 + l];
            float4 x0 = xs4[(rb + 0) * 32 + kb];
            float4 x1 = xs4[(rb + 1) * 32 + kb];
            float4 x2 = xs4[(rb + 2) * 32 + kb];
            float4 x3 = xs4[(rb + 3) * 32 + kb];
            float4 x4v = xs4[(rb + 4) * 32 + kb];
            float4 x5 = xs4[(rb + 5) * 32 + kb];
            float4 x6 = xs4[(rb + 6) * 32 + kb];
            float4 x7 = xs4[(rb + 7) * 32 + kb];
            STEP4(a0, x0) STEP4(a1, x1) STEP4(a2, x2) STEP4(a3, x3)
            STEP4(a4, x4v) STEP4(a5, x5) STEP4(a6, x6) STEP4(a7, x7)
        }
        int rbase = R0 + rb;
        if (rbase + 0 < N) O2[(size_t)(rbase + 0) * 64 + l] = a0;
        if (rbase + 1 < N) O2[(size_t)(rbase + 1) * 64 + l] = a1;
        if (rbase + 2 < N) O2[(size_t)(rbase + 2) * 64 + l] = a2;
        if (rbase + 3 < N) O2[(size_t)(rbase + 3) * 64 + l] = a3;
        if (rbase + 4 < N) O2[(size_t)(rbase + 4) * 64 + l] = a4;
        if (rbase + 5 < N) O2[(size_t)(rbase + 5) * 64 + l] = a5;
        if (rbase + 6 < N) O2[(size_t)(rbase + 6) * 64 + l] = a6;
        if (rbase + 7 < N) O2[(size_t)(rbase + 7) * 64 + l] = a7;
        __syncthreads();
    }
}

// bias-only rows (disease output)
__global__ void biasrow_k(const float* __restrict__ bo, float* __restrict__ out, int N) {
    int idx = blockIdx.x * 256 + threadIdx.x;
    if (idx < N * 64) {
        float2 bi = *(const float2*)&bo[2 * (idx & 63)];
        ((float2*)out)[idx] = bi;
    }
}

// ---------------------------------------------------------------------------
// ugen: one wave per edge (perm order); u = gelu(cp@W1 + b1) -> f16 into gate rows.
__global__ __launch_bounds__(256) void ugen_k(const float* __restrict__ cp,
                                              const float* __restrict__ W1c, const float* __restrict__ b1c,
                                              const int* __restrict__ perm, const int* __restrict__ starts,
                                              u16* __restrict__ gate,
                                              int j0, int j1, int NP_, int E, int CAP) {
    int lane = threadIdx.x & 63;
    int wv = (blockIdx.x * 256 + threadIdx.x) >> 6;
    int nw = gridDim.x * 4;
    int q0 = starts[j0];
    int q1 = (j1 >= NP_) ? E : starts[j1];
    int cnt = min(q1 - q0, CAP);
    int c0 = 2 * lane;
    float w1a = W1c[c0],     w1b = W1c[128 + c0],     w1c_ = W1c[256 + c0];
    float w1d = W1c[c0 + 1], w1e = W1c[128 + c0 + 1], w1f  = W1c[256 + c0 + 1];
    float b1a = b1c[c0], b1b = b1c[c0 + 1];
    unsigned* g32 = (unsigned*)gate;
    for (int qr = wv; qr < cnt; qr += nw) {
        int e = __builtin_amdgcn_readfirstlane(perm[q0 + qr]);
        float p0 = cp[(size_t)e * 3 + 0];
        float p1 = cp[(size_t)e * 3 + 1];
        float p2 = cp[(size_t)e * 3 + 2];
        float z0 = b1a + p0 * w1a + p1 * w1b + p2 * w1c_;
        float z1 = b1b + p0 * w1d + p1 * w1e + p2 * w1f;
        float u0 = 0.5f * z0 * (1.f + erff(z0 * 0.70710678118654752f));
        float u1 = 0.5f * z1 * (1.f + erff(z1 * 0.70710678118654752f));
        HSU h0; h0.f = (_Float16)u0;
        HSU h1; h1.f = (_Float16)u1;
        g32[(size_t)qr * 64 + lane] = ((unsigned)h1.s << 16) | h0.s;
    }
}

// gmm: one wave per 16-edge row-block; gate = sigmoid(u @ W2 + b2) IN PLACE.
__global__ __launch_bounds__(256) void gmm_k(const u16* __restrict__ w2p,
                                             const float* __restrict__ b2c,
                                             const int* __restrict__ starts,
                                             u16* __restrict__ gate,
                                             int j0, int j1, int NP_, int E, int CAP) {
    int lane = threadIdx.x & 63;
    int wv = (blockIdx.x * 256 + threadIdx.x) >> 6;
    int nw = gridDim.x * 4;
    int q0 = starts[j0];
    int q1 = (j1 >= NP_) ? E : starts[j1];
    int cnt = min(q1 - q0, CAP);
    if (cnt <= 0) return;
    int nrb = (cnt + 15) >> 4;
    const uint4* wp4 = (const uint4*)w2p;
    int colr = lane & 15, grp = lane >> 4;
    for (int rb = wv; rb < nrb; rb += nw) {
        int r0 = rb * 16;
        int arow = r0 + colr;
        if (arow >= cnt) arow = cnt - 1;
        const uint4* urow = (const uint4*)(gate + (size_t)arow * 128);
        U4F8 a0, a1, a2, a3;
        a0.u = urow[0 * 4 + grp];
        a1.u = urow[1 * 4 + grp];
        a2.u = urow[2 * 4 + grp];
        a3.u = urow[3 * 4 + grp];
        f32x4 res[8];
        #pragma unroll
        for (int ct = 0; ct < 8; ct++) {
            float b2v = b2c[ct * 16 + colr];
            f32x4 acc = {b2v, b2v, b2v, b2v};
            U4F8 b0, b1, b2, b3;
            b0.u = wp4[(ct * 4 + 0) * 64 + lane];
            b1.u = wp4[(ct * 4 + 1) * 64 + lane];
            b2.u = wp4[(ct * 4 + 2) * 64 + lane];
            b3.u = wp4[(ct * 4 + 3) * 64 + lane];
            acc = __builtin_amdgcn_mfma_f32_16x16x32_f16(a0.h, b0.h, acc, 0, 0, 0);
            acc = __builtin_amdgcn_mfma_f32_16x16x32_f16(a1.h, b1.h, acc, 0, 0, 0);
            acc = __builtin_amdgcn_mfma_f32_16x16x32_f16(a2.h, b2.h, acc, 0, 0, 0);
            acc = __builtin_amdgcn_mfma_f32_16x16x32_f16(a3.h, b3.h, acc, 0, 0, 0);
            res[ct] = acc;
        }
        #pragma unroll
        for (int ct = 0; ct < 8; ct++) {
            int col = ct * 16 + colr;
            #pragma unroll
            for (int r = 0; r < 4; r++) {
                int row = r0 + grp * 4 + r;
                if (row < cnt) {
                    HSU cv; cv.f = (_Float16)sigm(res[ct][r]);
                    gate[(size_t)row * 128 + col] = cv.s;
                }
            }
        }
    }
}

// ---------------------------------------------------------------------------
// Gather aggregation: ONE destination per wave, EIGHT edges batched.
// Clamp-softmax (no running max; logits O(5), clamp +-60, R7-verified).
// MODE 1: gate table via cmb (dot+shfl). MODE 3: f16 gate (dot+shfl).
// MODE 4: ungated, logit precomputed per-source in hsa (no dot, no shfl).
#define AGG_LOAD(K, ACT)                                                     \
    float2 hv##K; float2 gv##K; unsigned gu##K = 0; float pl##K = 0.f;       \
    if (ACT) {                                                               \
        int si = srcp[st + q + K];                                           \
        hv##K = hs2v[(size_t)si * 64 + lane];                                \
        if (MODE == 1) { int ab = cmb[st + q + K]; gv##K = gt2v[ab * 64 + lane]; } \
        if (MODE == 3) { int qq = st + q + K - q0base;                       \
                         qq = qq < 79999 ? qq : 79999;                       \
                         gu##K = g32[(size_t)qq * 64 + lane]; }              \
        if (MODE == 4) pl##K = hsa[(size_t)si * 4 + h];                      \
    }

#define AGG_UPD(K, ACT)                                                      \
    if (ACT) {                                                               \
        float mx = hv##K.x, my = hv##K.y;                                    \
        float p;                                                             \
        if (MODE == 4) {                                                     \
            p = pl##K;                                                       \
        } else {                                                             \
            if (MODE == 1) { mx *= gv##K.x; my *= gv##K.y; }                 \
            if (MODE == 3) { H2U gz; gz.u = gu##K; mx *= (float)gz.h.x; my *= (float)gz.h.y; } \
            p = mx * ax + my * ay;                                           \
            p += __shfl_xor(p, 1); p += __shfl_xor(p, 2);                    \
            p += __shfl_xor(p, 4); p += __shfl_xor(p, 8);                    \
        }                                                                    \
        float logit = p + adv;                                               \
        logit = logit > 0.f ? logit : 0.2f * logit;                          \
        logit = fminf(fmaxf(logit, -60.f), 60.f);                            \
        float ex = __expf(logit);                                            \
        ss += ex; vx += ex * mx; vy += ex * my;                              \
    }

template <int MODE>
__global__ __launch_bounds__(256) void agg_k(const float* __restrict__ hs,
                                             const float* __restrict__ ad,
                                             const float* __restrict__ hsa,
                                             const int* __restrict__ srcp,
                                             const int* __restrict__ cmb,
                                             const int* __restrict__ starts,
                                             const int* __restrict__ deg,
                                             const float* __restrict__ attn_t,
                                             const float* __restrict__ gtbl,
                                             const u16* __restrict__ gate,
                                             float* __restrict__ agg,
                                             int j0, int j1) {
    int lane = threadIdx.x & 63;
    int gw = (blockIdx.x * 256 + threadIdx.x) >> 6;
    int nw = gridDim.x * 4;
    int c0 = 2 * lane;
    float ax = attn_t[c0], ay = attn_t[c0 + 1];
    int h = lane >> 4;
    const float2* hs2v = (const float2*)hs;
    const float2* gt2v = (const float2*)gtbl;
    const unsigned* g32 = (const unsigned*)gate;
    float2* agg2v = (float2*)agg;
    int q0base = 0;
    if (MODE == 3) q0base = __builtin_amdgcn_readfirstlane(starts[j0]);
    for (int j = j0 + gw; j < j1; j += nw) {
        int st = __builtin_amdgcn_readfirstlane(starts[j]);
        int n  = __builtin_amdgcn_readfirstlane(deg[j]);
        float adv = ad[(size_t)j * 4 + h];
        float ss = 0.f, vx = 0.f, vy = 0.f;
        for (int q = 0; q < n; q += 8) {
            bool b1 = q + 1 < n, b2 = q + 2 < n, b3 = q + 3 < n;
            bool b4 = q + 4 < n, b5 = q + 5 < n, b6 = q + 6 < n, b7 = q + 7 < n;
            AGG_LOAD(0, true) AGG_LOAD(1, b1) AGG_LOAD(2, b2) AGG_LOAD(3, b3)
            AGG_LOAD(4, b4) AGG_LOAD(5, b5) AGG_LOAD(6, b6) AGG_LOAD(7, b7)
            AGG_UPD(0, true) AGG_UPD(1, b1) AGG_UPD(2, b2) AGG_UPD(3, b3)
            AGG_UPD(4, b4) AGG_UPD(5, b5) AGG_UPD(6, b6) AGG_UPD(7, b7)
        }
        float inv = ss > 0.f ? 1.f / ss : 0.f;
        float2 o; o.x = vx * inv; o.y = vy * inv;
        agg2v[(size_t)j * 64 + lane] = o;
    }
}

// ---------------------------------------------------------------------------
extern "C" void kernel_launch(void* const* d_in, const int* in_sizes, int n_in,
                              void* d_out, int out_size, void* d_ws, size_t ws_size,
                              hipStream_t stream) {
    static const int expect[29] = {
        6400000, 3840000, 1280000, 640000,
        500000, 500000, 500000, 500000, 250000, 250000, 250000, 250000,
        1000000, 750000, 65536, 512, 65536, 512, 512, 320, 256,
        8192, 128, 384, 128, 16384, 128, 65536, 512};
    int bad = 0;
    if (n_in != 29) bad = 1;
    else {
        for (int i = 0; i < 29; i++)
            if (in_sizes[i] != expect[i]) { bad = 4 + i; break; }
    }
    if (!bad && out_size != 12160000) bad = 2;
    if (!bad && ws_size < (size_t)63425536) bad = 3;
    if (bad) {
        senthost_k<<<1, 1, 0, stream>>>((float*)d_out, 4096.f * (float)bad);
        return;
    }

    const float* x_chem = (const float*)d_in[0];
    const float* x_gene = (const float*)d_in[1];
    const float* x_dis  = (const float*)d_in[2];
    const float* x_path = (const float*)d_in[3];
    const int* src0 = (const int*)d_in[4];  const int* dst0 = (const int*)d_in[5];
    const int* src1 = (const int*)d_in[6];  const int* dst1 = (const int*)d_in[7];
    const int* src2 = (const int*)d_in[8];  const int* dst2 = (const int*)d_in[9];
    const int* src3 = (const int*)d_in[10]; const int* dst3 = (const int*)d_in[11];
    const int*   cg   = (const int*)d_in[12];
    const float* cp   = (const float*)d_in[13];
    const float* Wsrc = (const float*)d_in[14]; const float* bsrc = (const float*)d_in[15];
    const float* Wdst = (const float*)d_in[16]; const float* bdst = (const float*)d_in[17];
    const float* attn = (const float*)d_in[18];
    const float* temb = (const float*)d_in[19]; const float* semb = (const float*)d_in[20];
    const float* Wg   = (const float*)d_in[21]; const float* bg   = (const float*)d_in[22];
    const float* W1c  = (const float*)d_in[23]; const float* b1c  = (const float*)d_in[24];
    const float* W2c  = (const float*)d_in[25]; const float* b2c  = (const float*)d_in[26];
    const float* Wout = (const float*)d_in[27]; const float* bout = (const float*)d_in[28];

    constexpr int NC = 50000, NG = 30000, ND = 10000, NP = 5000;
    constexpr int E0 = 500000, E1 = 500000, E2 = 250000, E3 = 250000;
    constexpr int GCAP = 80000;

    char* ws = (char*)d_ws;
    float* gt   = (float*)ws;              // [64][128] f32 = 32768 B
    int*   csum = (int*)(ws + 32768);      // chunk sums for scan (<=49 ints)
    float* avb  = (float*)(ws + 36864);    // 4 slots x 520 floats (by TYPE)
    u16*   w2p  = (u16*)  (ws + 49152);    // packed W2 fragments, 32768 B
    char*  A    = ws + 98304;              // stage arena

    float* out = (float*)d_out;
    float* out_chem = out;
    float* out_gene = out + (size_t)NC * 128;
    float* out_dis  = out + (size_t)(NC + NG) * 128;
    float* out_path = out + (size_t)(NC + NG + ND) * 128;

    prep_k<<<44, 256, 0, stream>>>(temb, semb, Wg, bg, gt, Wdst, bdst, attn, avb, W2c, w2p);

    // ---------- STAGE A: chemical output (t1: gene -> chemical) ----------
    {
        float* hs1  = (float*)(A);                 //  0 .. 15,360,000
        float* ad1  = (float*)(A + 15360000);      // .. 16,160,000
        int*   deg  = (int*)  (A + 16160000);      // .. 16,360,000
        int*   sts  = (int*)  (A + 16360000);      // .. 16,560,000
        int*   cur  = (int*)  (A + 16560000);      // .. 16,760,000
        int*   srcpA = (int*) (A + 16760000);      // .. 18,760,000
        float* agg1 = (float*)(A + 18760000);      // .. 44,360,000
        float* hsa1 = (float*)(A + 44360000);      // .. 44,840,000
        int nch = (NC + 1023) / 1024;
        zero_k<<<(NC + 255) / 256, 256, 0, stream>>>((float*)deg, NC);
        hist_k<<<(E1 + 255) / 256, 256, 0, stream>>>(dst1, deg, E1, NC);
        scan1_k<<<nch, 256, 0, stream>>>(deg, csum, NC);
        scan2_k<<<1, 64, 0, stream>>>(csum, nch);
        scan3_k<<<nch, 256, 0, stream>>>(deg, csum, sts, cur, NC);
        scatter_k<<<(E1 + 255) / 256, 256, 0, stream>>>(dst1, src1, nullptr, cur,
                                                        nullptr, srcpA, nullptr, E1, NC, NG);
        denseT_k<1><<<(NG + 31) / 32, 256, 0, stream>>>(x_gene, nullptr,
                                                        Wsrc + 1 * 16384, bsrc + 1 * 128, hs1, NG, (NG + 31) / 32);
        hsa_k<<<512, 256, 0, stream>>>(hs1, attn + 1 * 128, hsa1, NG);
        adg_k<<<1024, 256, 0, stream>>>(x_chem, avb + 1 * 520, avb + 1 * 520 + 512, ad1, NC);
        agg_k<4><<<2048, 256, 0, stream>>>(hs1, ad1, hsa1, srcpA, nullptr, sts, deg,
                                           attn + 1 * 128, nullptr, nullptr, agg1, 0, NC);
        denseT_k<1><<<(NC + 31) / 32, 256, 0, stream>>>(agg1, nullptr,
                                                        Wout + 0 * 16384, bout + 0 * 128, out_chem, NC, (NC + 31) / 32);
    }

    // ---------- STAGE B: pathway output (t2: chemical -> pathway) ----------
    {
        float* hs2  = (float*)(A);                 //  0 .. 25,600,000
        float* ad2  = (float*)(A + 25600000);      // .. 25,680,000
        int*   deg  = (int*)  (A + 25680000);      // .. 25,700,000
        int*   sts  = (int*)  (A + 25700000);      // .. 25,720,000
        int*   cur  = (int*)  (A + 25720000);      // .. 25,740,000
        int*   perm = (int*)  (A + 25740000);      // .. 26,740,000
        int*   srcpB = (int*) (A + 26740000);      // .. 27,740,000
        float* agg2 = (float*)(A + 27740000);      // .. 30,300,000
        u16*   gatep = (u16*) (A + 30300000);      // .. 50,780,000
        int nch = (NP + 1023) / 1024;
        zero_k<<<(NP + 255) / 256, 256, 0, stream>>>((float*)deg, NP);
        hist_k<<<(E2 + 255) / 256, 256, 0, stream>>>(dst2, deg, E2, NP);
        scan1_k<<<nch, 256, 0, stream>>>(deg, csum, NP);
        scan2_k<<<1, 64, 0, stream>>>(csum, nch);
        scan3_k<<<nch, 256, 0, stream>>>(deg, csum, sts, cur, NP);
        scatter_k<<<(E2 + 255) / 256, 256, 0, stream>>>(dst2, src2, nullptr, cur,
                                                        perm, srcpB, nullptr, E2, NP, NC);
        denseT_k<1><<<(NC + 31) / 32, 256, 0, stream>>>(x_chem, nullptr,
                                                        Wsrc + 2 * 16384, bsrc + 2 * 128, hs2, NC, (NC + 31) / 32);
        adg_k<<<256, 256, 0, stream>>>(x_path, avb + 2 * 520, avb + 2 * 520 + 512, ad2, NP);
        for (int ck = 0; ck < 4; ck++) {
            int j0 = ck * 1250, j1 = j0 + 1250;
            ugen_k<<<2048, 256, 0, stream>>>(cp, W1c, b1c, perm, sts, gatep,
                                             j0, j1, NP, E2, GCAP);
            gmm_k<<<1024, 256, 0, stream>>>(w2p, b2c, sts, gatep,
                                            j0, j1, NP, E2, GCAP);
            agg_k<3><<<313, 256, 0, stream>>>(hs2, ad2, nullptr, srcpB, nullptr, sts, deg,
                                              attn + 2 * 128, nullptr, gatep, agg2, j0, j1);
        }
        denseT_k<1><<<(NP + 31) / 32, 256, 0, stream>>>(agg2, nullptr,
                                                        Wout + 3 * 16384, bout + 3 * 128, out_path, NP, (NP + 31) / 32);
    }

    // ---------- STAGE C: gene output (t0 + t3, sequential buffer reuse) -----
    {
        float* ad0  = (float*)(A + 25600000);      // .. 26,080,000
        float* ad3  = (float*)(A + 26080000);      // .. 26,560,000 (survives)
        int*   deg  = (int*)  (A + 26560000);      // .. 26,680,000
        int*   sts  = (int*)  (A + 26680000);      // .. 26,800,000
        int*   cur  = (int*)  (A + 26800000);      // .. 26,920,000
        int*   srcpC = (int*) (A + 26920000);      // .. 28,920,000
        int*   cmbp = (int*)  (A + 28920000);      // .. 30,920,000
        float* agg0 = (float*)(A + 30920000);      // .. 46,280,000
        float* agg3 = (float*)(A + 46280000);      // .. 61,640,000
        float* hsa3 = (float*)(A + 61640000);      // .. 61,800,000
        int nch = (NG + 1023) / 1024;

        // phase 1: t0 chemical -> gene (categorical gate)
        float* hs0 = (float*)(A);                  //  0 .. 25,600,000
        zero_k<<<(NG + 255) / 256, 256, 0, stream>>>((float*)deg, NG);
        hist_k<<<(E0 + 255) / 256, 256, 0, stream>>>(dst0, deg, E0, NG);
        scan1_k<<<nch, 256, 0, stream>>>(deg, csum, NG);
        scan2_k<<<1, 64, 0, stream>>>(csum, nch);
        scan3_k<<<nch, 256, 0, stream>>>(deg, csum, sts, cur, NG);
        scatter_k<<<(E0 + 255) / 256, 256, 0, stream>>>(dst0, src0, cg, cur,
                                                        nullptr, srcpC, cmbp, E0, NG, NC);
        denseT_k<1><<<(NC + 31) / 32, 256, 0, stream>>>(x_chem, nullptr,
                                                        Wsrc + 0 * 16384, bsrc + 0 * 128, hs0, NC, (NC + 31) / 32);
        adg_k<<<1024, 256, 0, stream>>>(x_gene, avb + 0 * 520, avb + 0 * 520 + 512, ad0, NG);
        adg_k<<<1024, 256, 0, stream>>>(x_gene, avb + 3 * 520, avb + 3 * 520 + 512, ad3, NG);
        agg_k<1><<<2048, 256, 0, stream>>>(hs0, ad0, nullptr, srcpC, cmbp, sts, deg,
                                           attn + 0 * 128, gt, nullptr, agg0, 0, NG);

        // phase 2: t3 disease -> gene (plain), reusing hs/CSR buffers
        float* hs3 = (float*)(A);                  //  0 .. 5,120,000
        zero_k<<<(NG + 255) / 256, 256, 0, stream>>>((float*)deg, NG);
        hist_k<<<(E3 + 255) / 256, 256, 0, stream>>>(dst3, deg, E3, NG);
        scan1_k<<<nch, 256, 0, stream>>>(deg, csum, NG);
        scan2_k<<<1, 64, 0, stream>>>(csum, nch);
        scan3_k<<<nch, 256, 0, stream>>>(deg, csum, sts, cur, NG);
        scatter_k<<<(E3 + 255) / 256, 256, 0, stream>>>(dst3, src3, nullptr, cur,
                                                        nullptr, srcpC, nullptr, E3, NG, ND);
        denseT_k<1><<<(ND + 31) / 32, 256, 0, stream>>>(x_dis, nullptr,
                                                        Wsrc + 3 * 16384, bsrc + 3 * 128, hs3, ND, (ND + 31) / 32);
        hsa_k<<<256, 256, 0, stream>>>(hs3, attn + 3 * 128, hsa3, ND);
        agg_k<4><<<2048, 256, 0, stream>>>(hs3, ad3, hsa3, srcpC, nullptr, sts, deg,
                                           attn + 3 * 128, nullptr, nullptr, agg3, 0, NG);
        denseT_k<2><<<(NG + 31) / 32, 256, 0, stream>>>(agg0, agg3,
                                                        Wout + 1 * 16384, bout + 1 * 128, out_gene, NG, (NG + 31) / 32);
    }

    // ---------- STAGE D: disease output (no incoming edges: bias only) ------
    biasrow_k<<<(ND * 64 + 255) / 256, 256, 0, stream>>>(bout + 2 * 128, out_dis, ND);
}

// Round 13
// 956.734 us; speedup vs baseline: 2.3807x; 1.0081x over previous
//
#include <hip/hip_runtime.h>

// EdgeAttrHeteroConv — round 20. R19 = 964.5 us; top dispatch agg_k<1> (t0)
// 52 us (VALUBusy 38%, HBM 32%) and a ~56-dispatch tail. R20, math-free:
// (a) batched CSR build for all 4 edge types (zero/hist4/scan x3/scatter4 =
//     6 launches, was 24), CSR block at arena [50.78M..61.16M] (no overlap
//     with any stage peak; stage C agg3 relocated to [5.12M..20.48M]);
// (b) ugmm_k = ugen+gmm fused: u computed in-register directly in MFMA
//     A-frag layout (same z/gelu expressions -> same f16 bits), W1/b1/b2 in
//     2.5KB LDS; kills the 16MBx2 u round-trip and 4 launches;
// (c) agg_k<1> stages gtbl (32KB) in LDS -> frees L1 for the hs gather;
// (d) adg2_k fuses stage C's two adg passes over x_gene.
// Everything else identical to R19 (verified 964.5 us, absmax 1.95e-3).

typedef unsigned short u16;
typedef _Float16 h2_t __attribute__((ext_vector_type(2)));
typedef _Float16 f16x8 __attribute__((ext_vector_type(8)));
typedef float f32x4 __attribute__((ext_vector_type(4)));
union H2U { unsigned u; h2_t h; };
union HSU { _Float16 f; unsigned short s; };
union U4F8 { uint4 u; f16x8 h; };

__device__ __forceinline__ float sigm(float x) { return 1.f / (1.f + expf(-x)); }

// ---------------------------------------------------------------------------
__global__ void zero_k(int* __restrict__ p, int n) {
    int i = blockIdx.x * 256 + threadIdx.x;
    if (i < n) p[i] = 0;
}

__global__ void senthost_k(float* out, float v) { out[0] = v; }

// ---------------------------------------------------------------------------
// Batched CSR build. Unified deg/sts/cur arrays, type offsets:
//   t1@0 (NC), t2@50000 (NP), t0@55000 (NG), t3@85000 (NG). Total 115000.
// Edge ranges in the 1.5M unified edge space:
//   t1 [0,500K), t2 [500K,750K), t0 [750K,1.25M), t3 [1.25M,1.5M).
__global__ void hist4_k(const int* __restrict__ dst1, const int* __restrict__ dst2,
                        const int* __restrict__ dst0, const int* __restrict__ dst3,
                        int* __restrict__ degU) {
    int e = blockIdx.x * 256 + threadIdx.x;
    if (e >= 1500000) return;
    int d, off, Nd;
    if (e < 500000)       { d = dst1[e];           off = 0;     Nd = 50000; }
    else if (e < 750000)  { d = dst2[e - 500000];  off = 50000; Nd = 5000;  }
    else if (e < 1250000) { d = dst0[e - 750000];  off = 55000; Nd = 30000; }
    else                  { d = dst3[e - 1250000]; off = 85000; Nd = 30000; }
    d = d < 0 ? 0 : (d >= Nd ? Nd - 1 : d);
    atomicAdd(&degU[off + d], 1);
}

__global__ void scan1b_k(const int* __restrict__ degU, int* __restrict__ csum) {
    const int degOff[4] = {0, 50000, 55000, 85000};
    const int NdT[4]    = {50000, 5000, 30000, 30000};
    __shared__ int red[256];
    int ty = blockIdx.y;
    int Nd = NdT[ty];
    int base = blockIdx.x * 1024;
    if (base >= Nd) return;
    int t = threadIdx.x;
    int s = 0;
    for (int i = 0; i < 4; i++) {
        int idx = base + t * 4 + i;
        if (idx < Nd) s += degU[degOff[ty] + idx];
    }
    red[t] = s;
    __syncthreads();
    for (int off = 128; off > 0; off >>= 1) {
        if (t < off) red[t] += red[t + off];
        __syncthreads();
    }
    if (t == 0) csum[ty * 64 + blockIdx.x] = red[0];
}

__global__ void scan2b_k(int* __restrict__ csum) {
    const int nchT[4] = {49, 5, 30, 30};
    int t = threadIdx.x;
    if (t < 4) {
        int acc = 0;
        for (int i = 0; i < nchT[t]; i++) {
            int v = csum[t * 64 + i]; csum[t * 64 + i] = acc; acc += v;
        }
    }
}

__global__ void scan3b_k(const int* __restrict__ degU, const int* __restrict__ csum,
                         int* __restrict__ stsU, int* __restrict__ curU) {
    const int degOff[4] = {0, 50000, 55000, 85000};
    const int NdT[4]    = {50000, 5000, 30000, 30000};
    __shared__ int sc[256];
    int ty = blockIdx.y;
    int Nd = NdT[ty];
    int base = blockIdx.x * 1024;
    if (base >= Nd) return;
    int off = degOff[ty];
    int t = threadIdx.x;
    int v[4];
    int s = 0;
    for (int i = 0; i < 4; i++) {
        int idx = base + t * 4 + i;
        v[i] = idx < Nd ? degU[off + idx] : 0;
        s += v[i];
    }
    sc[t] = s;
    __syncthreads();
    for (int o = 1; o < 256; o <<= 1) {
        int add = (t >= o) ? sc[t - o] : 0;
        __syncthreads();
        sc[t] += add;
        __syncthreads();
    }
    int excl = sc[t] - s + csum[ty * 64 + blockIdx.x];
    for (int i = 0; i < 4; i++) {
        int idx = base + t * 4 + i;
        if (idx < Nd) { stsU[off + idx] = excl; curU[off + idx] = excl; excl += v[i]; }
    }
}

__global__ void scatter4_k(const int* __restrict__ dst1, const int* __restrict__ src1,
                           const int* __restrict__ dst2, const int* __restrict__ src2,
                           const int* __restrict__ dst0, const int* __restrict__ src0,
                           const int* __restrict__ dst3, const int* __restrict__ src3,
                           const int* __restrict__ cg, int* __restrict__ curU,
                           int* __restrict__ sp1, int* __restrict__ sp2,
                           int* __restrict__ perm2, int* __restrict__ sp0,
                           int* __restrict__ cmb0, int* __restrict__ sp3) {
    int e = blockIdx.x * 256 + threadIdx.x;
    if (e >= 1500000) return;
    if (e < 500000) {
        int d = dst1[e]; d = d < 0 ? 0 : (d >= 50000 ? 49999 : d);
        int p = atomicAdd(&curU[0 + d], 1);
        int si = src1[e]; si = si < 0 ? 0 : (si >= 30000 ? 29999 : si);
        sp1[p] = si;
    } else if (e < 750000) {
        int el = e - 500000;
        int d = dst2[el]; d = d < 0 ? 0 : (d >= 5000 ? 4999 : d);
        int p = atomicAdd(&curU[50000 + d], 1);
        int si = src2[el]; si = si < 0 ? 0 : (si >= 50000 ? 49999 : si);
        sp2[p] = si;
        perm2[p] = el;
    } else if (e < 1250000) {
        int el = e - 750000;
        int d = dst0[el]; d = d < 0 ? 0 : (d >= 30000 ? 29999 : d);
        int p = atomicAdd(&curU[55000 + d], 1);
        int si = src0[el]; si = si < 0 ? 0 : (si >= 50000 ? 49999 : si);
        sp0[p] = si;
        int a = cg[2 * el] & 7, b = cg[2 * el + 1] & 7;
        cmb0[p] = a * 8 + b;
    } else {
        int el = e - 1250000;
        int d = dst3[el]; d = d < 0 ? 0 : (d >= 30000 ? 29999 : d);
        int p = atomicAdd(&curU[85000 + d], 1);
        int si = src3[el]; si = si < 0 ? 0 : (si >= 10000 ? 9999 : si);
        sp3[p] = si;
    }
}

// ---------------------------------------------------------------------------
// Fused prep: gtbl (blocks 0..31), avprep x4 (blocks 32..35), w2pack (36..43).
__global__ void prep_k(const float* __restrict__ temb, const float* __restrict__ semb,
                       const float* __restrict__ Wg, const float* __restrict__ bg,
                       float* __restrict__ gtbl,
                       const float* __restrict__ Wdst, const float* __restrict__ bdst,
                       const float* __restrict__ attn, float* __restrict__ avb,
                       const float* __restrict__ W2c, u16* __restrict__ w2p) {
    int b = blockIdx.x;
    if (b < 32) {
        int idx = b * 256 + threadIdx.x;
        int combo = idx >> 7, c = idx & 127;
        int a = combo >> 3, bb_ = combo & 7;
        float s = bg[c];
        for (int k = 0; k < 32; k++) s += temb[a * 32 + k] * Wg[k * 128 + c];
        for (int k = 0; k < 32; k++) s += semb[bb_ * 32 + k] * Wg[(32 + k) * 128 + c];
        gtbl[combo * 128 + c] = sigm(s);
    } else if (b < 36) {
        if (threadIdx.x < 128) {
            int ty = b - 32;
            const float* Wd = Wdst + ty * 16384;
            const float* bd = bdst + ty * 128;
            const float* at = attn + ty * 128;
            float* av = avb + ty * 520;
            float* bb = av + 512;
            int k = threadIdx.x;
            float a0 = 0.f, a1 = 0.f, a2 = 0.f, a3 = 0.f;
            for (int c = 0; c < 32; c++) {
                a0 += Wd[k * 128 + 0 * 32 + c] * at[0 * 32 + c];
                a1 += Wd[k * 128 + 1 * 32 + c] * at[1 * 32 + c];
                a2 += Wd[k * 128 + 2 * 32 + c] * at[2 * 32 + c];
                a3 += Wd[k * 128 + 3 * 32 + c] * at[3 * 32 + c];
            }
            float4 o; o.x = a0; o.y = a1; o.z = a2; o.w = a3;
            ((float4*)av)[k] = o;
            if (k < 4) {
                float s = 0.f;
                for (int c = 0; c < 32; c++) s += bd[k * 32 + c] * at[k * 32 + c];
                bb[k] = s;
            }
        }
    } else {
        int t = (b - 36) * 256 + threadIdx.x;    // 0..2047
        if (t < 2048) {
            int l = t & 63;
            int tile = t >> 6;                   // ct*4 + kb
            int ct = tile >> 2, kb = tile & 3;
            int k0 = kb * 32 + (l >> 4) * 8;
            int c  = ct * 16 + (l & 15);
            for (int i = 0; i < 8; i++) {
                HSU cv; cv.f = (_Float16)W2c[(k0 + i) * 128 + c];
                w2p[(size_t)t * 8 + i] = cv.s;
            }
        }
    }
}

// ---------------------------------------------------------------------------
__global__ __launch_bounds__(256) void adg_k(const float* __restrict__ x,
                                             const float* __restrict__ av,
                                             const float* __restrict__ bb,
                                             float* __restrict__ ad, int N) {
    int l = threadIdx.x & 63;
    int gw = (blockIdx.x * 256 + threadIdx.x) >> 6;
    int nw = gridDim.x * 4;
    float4 av0 = ((const float4*)av)[2 * l];
    float4 av1 = ((const float4*)av)[2 * l + 1];
    float4 bbv = *(const float4*)bb;
    const float2* x2 = (const float2*)x;
    for (int j = gw; j < N; j += nw) {
        float2 xv = x2[(size_t)j * 64 + l];
        float p0 = xv.x * av0.x + xv.y * av1.x;
        float p1 = xv.x * av0.y + xv.y * av1.y;
        float p2 = xv.x * av0.z + xv.y * av1.z;
        float p3 = xv.x * av0.w + xv.y * av1.w;
        #pragma unroll
        for (int off = 1; off < 64; off <<= 1) {
            p0 += __shfl_xor(p0, off);
            p1 += __shfl_xor(p1, off);
            p2 += __shfl_xor(p2, off);
            p3 += __shfl_xor(p3, off);
        }
        if (l == 0) {
            float4 o; o.x = p0 + bbv.x; o.y = p1 + bbv.y; o.z = p2 + bbv.z; o.w = p3 + bbv.w;
            *(float4*)&ad[(size_t)j * 4] = o;
        }
    }
}

// Two edge types' ad from one pass over x (stage C: ad0 + ad3 from x_gene).
__global__ __launch_bounds__(256) void adg2_k(const float* __restrict__ x,
                                              const float* __restrict__ avA,
                                              const float* __restrict__ bbA,
                                              const float* __restrict__ avB,
                                              const float* __restrict__ bbB,
                                              float* __restrict__ adA,
                                              float* __restrict__ adB, int N) {
    int l = threadIdx.x & 63;
    int gw = (blockIdx.x * 256 + threadIdx.x) >> 6;
    int nw = gridDim.x * 4;
    float4 aA0 = ((const float4*)avA)[2 * l];
    float4 aA1 = ((const float4*)avA)[2 * l + 1];
    float4 aB0 = ((const float4*)avB)[2 * l];
    float4 aB1 = ((const float4*)avB)[2 * l + 1];
    float4 bA = *(const float4*)bbA;
    float4 bB = *(const float4*)bbB;
    const float2* x2 = (const float2*)x;
    for (int j = gw; j < N; j += nw) {
        float2 xv = x2[(size_t)j * 64 + l];
        float p0 = xv.x * aA0.x + xv.y * aA1.x;
        float p1 = xv.x * aA0.y + xv.y * aA1.y;
        float p2 = xv.x * aA0.z + xv.y * aA1.z;
        float p3 = xv.x * aA0.w + xv.y * aA1.w;
        float r0 = xv.x * aB0.x + xv.y * aB1.x;
        float r1 = xv.x * aB0.y + xv.y * aB1.y;
        float r2 = xv.x * aB0.z + xv.y * aB1.z;
        float r3 = xv.x * aB0.w + xv.y * aB1.w;
        #pragma unroll
        for (int off = 1; off < 64; off <<= 1) {
            p0 += __shfl_xor(p0, off); p1 += __shfl_xor(p1, off);
            p2 += __shfl_xor(p2, off); p3 += __shfl_xor(p3, off);
            r0 += __shfl_xor(r0, off); r1 += __shfl_xor(r1, off);
            r2 += __shfl_xor(r2, off); r3 += __shfl_xor(r3, off);
        }
        if (l == 0) {
            float4 oa; oa.x = p0 + bA.x; oa.y = p1 + bA.y; oa.z = p2 + bA.z; oa.w = p3 + bA.w;
            float4 ob; ob.x = r0 + bB.x; ob.y = r1 + bB.y; ob.z = r2 + bB.z; ob.w = r3 + bB.w;
            *(float4*)&adA[(size_t)j * 4] = oa;
            *(float4*)&adB[(size_t)j * 4] = ob;
        }
    }
}

// hsa[j][h] = sum_{c in head h} hs[j][c]*attn_t[c] — same reduce order as
// the former in-agg dot, so the logit p is bit-identical.
__global__ __launch_bounds__(256) void hsa_k(const float* __restrict__ hs,
                                             const float* __restrict__ attn_t,
                                             float* __restrict__ hsa, int N) {
    int l = threadIdx.x & 63;
    int gw = (blockIdx.x * 256 + threadIdx.x) >> 6;
    int nw = gridDim.x * 4;
    int c0 = 2 * l;
    float ax = attn_t[c0], ay = attn_t[c0 + 1];
    int h = l >> 4;
    const float2* hs2 = (const float2*)hs;
    for (int j = gw; j < N; j += nw) {
        float2 hv = hs2[(size_t)j * 64 + l];
        float p = hv.x * ax + hv.y * ay;
        p += __shfl_xor(p, 1);
        p += __shfl_xor(p, 2);
        p += __shfl_xor(p, 4);
        p += __shfl_xor(p, 8);
        if ((l & 15) == 0) hsa[(size_t)j * 4 + h] = p;
    }
}

// ---------------------------------------------------------------------------
// Tiled dense: 32-row x tile in LDS (16 KB), 4 waves x 8 rows, 2 ch/lane.
#define STEP4(A, XV)                                     \
    A.x += XV.x * w0.x; A.y += XV.x * w0.y;              \
    A.x += XV.y * w1.x; A.y += XV.y * w1.y;              \
    A.x += XV.z * w2.x; A.y += XV.z * w2.y;              \
    A.x += XV.w * w3.x; A.y += XV.w * w3.y;

template <int NIN>
__global__ __launch_bounds__(256) void denseT_k(const float* __restrict__ X,
                                                const float* __restrict__ Xb,
                                                const float* __restrict__ W,
                                                const float* __restrict__ bias,
                                                float* __restrict__ O, int N, int NT) {
    __shared__ float4 xs4[1024];               // 32 rows x 128 ch = 16 KB
    int t = threadIdx.x;
    int l = t & 63, w = t >> 6;
    float2 bi = *(const float2*)&bias[2 * l];
    const float4* X4 = (const float4*)X;
    const float4* B4 = (const float4*)Xb;
    const float2* Wv = (const float2*)W;
    float2* O2 = (float2*)O;
    for (int tile = blockIdx.x; tile < NT; tile += gridDim.x) {
        int R0 = tile * 32;
        #pragma unroll
        for (int i = 0; i < 4; i++) {
            int idx = t + 256 * i;
            int r = R0 + (idx >> 5);
            int rc = min(r, N - 1);
            float4 v = X4[(size_t)rc * 32 + (idx & 31)];
            if (NIN == 2) {
                float4 b = B4[(size_t)rc * 32 + (idx & 31)];
                v.x += b.x; v.y += b.y; v.z += b.z; v.w += b.w;
            }
            xs4[idx] = v;
        }
        __syncthreads();
        float2 a0 = bi, a1 = bi, a2 = bi, a3 = bi, a4 = bi, a5 = bi, a6 = bi, a7 = bi;
        int rb = 8 * w;
        #pragma unroll 2
        for (int kb = 0; kb < 32; kb++) {
            float2 w0 = Wv[(4 * kb + 0) * 64 + l];
            float2 w1 = Wv[(4 * kb + 1) * 64 + l];
            float2 w2 = Wv[(4 * kb + 2) * 64 + l];
            float2 w3 = Wv[(4 * kb + 3) * 64 + l];
            float4 x0 = xs4[(rb + 0) * 32 + kb];
            float4 x1 = xs4[(rb + 1) * 32 + kb];
            float4 x2 = xs4[(rb + 2) * 32 + kb];
            float4 x3 = xs4[(rb + 3) * 32 + kb];
            float4 x4v = xs4[(rb + 4) * 32 + kb];
            float4 x5 = xs4[(rb + 5) * 32 + kb];
            float4 x6 = xs4[(rb + 6) * 32 + kb];
            float4 x7 = xs4[(rb + 7) * 32 + kb];
            STEP4(a0, x0) STEP4(a1, x1) STEP4(a2, x2) STEP4(a3, x3)
            STEP4(a4, x4v) STEP4(a5, x5) STEP4(a6, x6) STEP4(a7, x7)
        }
        int rbase = R0 + rb;
        if (rbase + 0 < N) O2[(size_t)(rbase + 0) * 64 + l] = a0;
        if (rbase + 1 < N) O2[(size_t)(rbase + 1) * 64 + l] = a1;
        if (rbase + 2 < N) O2[(size_t)(rbase + 2) * 64 + l] = a2;
        if (rbase + 3 < N) O2[(size_t)(rbase + 3) * 64 + l] = a3;
        if (rbase + 4 < N) O2[(size_t)(rbase + 4) * 64 + l] = a4;
        if (rbase + 5 < N) O2[(size_t)(rbase + 5) * 64 + l] = a5;
        if (rbase + 6 < N) O2[(size_t)(rbase + 6) * 64 + l] = a6;
        if (rbase + 7 < N) O2[(size_t)(rbase + 7) * 64 + l] = a7;
        __syncthreads();
    }
}

// bias-only rows (disease output)
__global__ void biasrow_k(const float* __restrict__ bo, float* __restrict__ out, int N) {
    int idx = blockIdx.x * 256 + threadIdx.x;
    if (idx < N * 64) {
        float2 bi = *(const float2*)&bo[2 * (idx & 63)];
        ((float2*)out)[idx] = bi;
    }
}

// ---------------------------------------------------------------------------
// ugmm: fused t2 gate. One wave per 16-edge row-block: compute
// u = gelu(cp@W1+b1) per lane DIRECTLY in MFMA A-frag layout (same z/gelu
// expressions as R19's ugen -> same f16 bits), then 32 MFMAs against packed
// W2 frags, sigmoid, store f16 gate. W1/b1/b2 staged in LDS (640 floats).
__global__ __launch_bounds__(256) void ugmm_k(const float* __restrict__ cp,
                                              const float* __restrict__ W1c, const float* __restrict__ b1c,
                                              const u16* __restrict__ w2p, const float* __restrict__ b2c,
                                              const int* __restrict__ perm, const int* __restrict__ starts,
                                              u16* __restrict__ gate,
                                              int j0, int j1, int NP_, int E, int CAP) {
    __shared__ float f6[640];                  // [0..384) W1 rows, [384..512) b1, [512..640) b2
    for (int i = threadIdx.x; i < 640; i += 256) {
        f6[i] = (i < 384) ? W1c[i] : (i < 512 ? b1c[i - 384] : b2c[i - 512]);
    }
    __syncthreads();
    int lane = threadIdx.x & 63;
    int wv = (blockIdx.x * 256 + threadIdx.x) >> 6;
    int nw = gridDim.x * 4;
    int q0 = starts[j0];
    int q1 = (j1 >= NP_) ? E : starts[j1];
    int cnt = min(q1 - q0, CAP);
    if (cnt <= 0) return;
    int nrb = (cnt + 15) >> 4;
    const uint4* wp4 = (const uint4*)w2p;
    int colr = lane & 15, grp = lane >> 4;
    for (int rb = wv; rb < nrb; rb += nw) {
        int r0 = rb * 16;
        // lanes 0..15 load cp for rows r0..r0+15 (clamped within block)
        float c0v = 0.f, c1v = 0.f, c2v = 0.f;
        if (lane < 16) {
            int arow = r0 + lane;
            if (arow >= cnt) arow = cnt - 1;
            int e = perm[q0 + arow];
            c0v = cp[(size_t)e * 3 + 0];
            c1v = cp[(size_t)e * 3 + 1];
            c2v = cp[(size_t)e * 3 + 2];
        }
        float p0 = __shfl(c0v, colr);
        float p1 = __shfl(c1v, colr);
        float p2 = __shfl(c2v, colr);
        // A-frags: lane holds u[r0+colr][kb*32 + grp*8 + i]
        U4F8 af[4];
        #pragma unroll
        for (int kb = 0; kb < 4; kb++) {
            f16x8 v;
            #pragma unroll
            for (int i = 0; i < 8; i++) {
                int c = kb * 32 + grp * 8 + i;
                float z = f6[384 + c] + p0 * f6[c] + p1 * f6[128 + c] + p2 * f6[256 + c];
                float u = 0.5f * z * (1.f + erff(z * 0.70710678118654752f));
                v[i] = (_Float16)u;
            }
            af[kb].h = v;
        }
        #pragma unroll
        for (int ct = 0; ct < 8; ct++) {
            float b2v = f6[512 + ct * 16 + colr];
            f32x4 acc = {b2v, b2v, b2v, b2v};
            U4F8 b0, b1, b2, b3;
            b0.u = wp4[(ct * 4 + 0) * 64 + lane];
            b1.u = wp4[(ct * 4 + 1) * 64 + lane];
            b2.u = wp4[(ct * 4 + 2) * 64 + lane];
            b3.u = wp4[(ct * 4 + 3) * 64 + lane];
            acc = __builtin_amdgcn_mfma_f32_16x16x32_f16(af[0].h, b0.h, acc, 0, 0, 0);
            acc = __builtin_amdgcn_mfma_f32_16x16x32_f16(af[1].h, b1.h, acc, 0, 0, 0);
            acc = __builtin_amdgcn_mfma_f32_16x16x32_f16(af[2].h, b2.h, acc, 0, 0, 0);
            acc = __builtin_amdgcn_mfma_f32_16x16x32_f16(af[3].h, b3.h, acc, 0, 0, 0);
            int col = ct * 16 + colr;
            #pragma unroll
            for (int r = 0; r < 4; r++) {
                int row = r0 + grp * 4 + r;
                if (row < cnt) {
                    HSU cv; cv.f = (_Float16)sigm(acc[r]);
                    gate[(size_t)row * 128 + col] = cv.s;
                }
            }
        }
    }
}

// ---------------------------------------------------------------------------
// Gather aggregation: ONE destination per wave, EIGHT edges batched.
// Clamp-softmax (logits O(5), clamp +-60, R7-verified) + __expf.
// MODE 1: gate table via cmb (LDS-staged gtbl). MODE 3: f16 gate.
// MODE 4: ungated, logit precomputed per-source in hsa.
#define AGG_LOAD(K, ACT)                                                     \
    float2 hv##K; float2 gv##K; unsigned gu##K = 0; float pl##K = 0.f;       \
    if (ACT) {                                                               \
        int si = srcp[st + q + K];                                           \
        hv##K = hs2v[(size_t)si * 64 + lane];                                \
        if (MODE == 1) { int ab = cmb[st + q + K]; gv##K = gl2[ab * 64 + lane]; } \
        if (MODE == 3) { int qq = st + q + K - q0base;                       \
                         qq = qq < 79999 ? qq : 79999;                       \
                         gu##K = g32[(size_t)qq * 64 + lane]; }              \
        if (MODE == 4) pl##K = hsa[(size_t)si * 4 + h];                      \
    }

#define AGG_UPD(K, ACT)                                                      \
    if (ACT) {                                                               \
        float mx = hv##K.x, my = hv##K.y;                                    \
        float p;                                                             \
        if (MODE == 4) {                                                     \
            p = pl##K;                                                       \
        } else {                                                             \
            if (MODE == 1) { mx *= gv##K.x; my *= gv##K.y; }                 \
            if (MODE == 3) { H2U gz; gz.u = gu##K; mx *= (float)gz.h.x; my *= (float)gz.h.y; } \
            p = mx * ax + my * ay;                                           \
            p += __shfl_xor(p, 1); p += __shfl_xor(p, 2);                    \
            p += __shfl_xor(p, 4); p += __shfl_xor(p, 8);                    \
        }                                                                    \
        float logit = p + adv;                                               \
        logit = logit > 0.f ? logit : 0.2f * logit;                          \
        logit = fminf(fmaxf(logit, -60.f), 60.f);                            \
        float ex = __expf(logit);                                            \
        ss += ex; vx += ex * mx; vy += ex * my;                              \
    }

template <int MODE>
__global__ __launch_bounds__(256) void agg_k(const float* __restrict__ hs,
                                             const float* __restrict__ ad,
                                             const float* __restrict__ hsa,
                                             const int* __restrict__ srcp,
                                             const int* __restrict__ cmb,
                                             const int* __restrict__ starts,
                                             const int* __restrict__ deg,
                                             const float* __restrict__ attn_t,
                                             const float* __restrict__ gtbl,
                                             const u16* __restrict__ gate,
                                             float* __restrict__ agg,
                                             int j0, int j1) {
    __shared__ float4 gt_sh[MODE == 1 ? 2048 : 1];   // 32 KB gate table
    if (MODE == 1) {
        const float4* g4 = (const float4*)gtbl;
        for (int i = threadIdx.x; i < 2048; i += 256) gt_sh[i] = g4[i];
        __syncthreads();
    }
    const float2* gl2 = (const float2*)gt_sh;
    int lane = threadIdx.x & 63;
    int gw = (blockIdx.x * 256 + threadIdx.x) >> 6;
    int nw = gridDim.x * 4;
    int c0 = 2 * lane;
    float ax = attn_t[c0], ay = attn_t[c0 + 1];
    int h = lane >> 4;
    const float2* hs2v = (const float2*)hs;
    const unsigned* g32 = (const unsigned*)gate;
    float2* agg2v = (float2*)agg;
    int q0base = 0;
    if (MODE == 3) q0base = __builtin_amdgcn_readfirstlane(starts[j0]);
    for (int j = j0 + gw; j < j1; j += nw) {
        int st = __builtin_amdgcn_readfirstlane(starts[j]);
        int n  = __builtin_amdgcn_readfirstlane(deg[j]);
        float adv = ad[(size_t)j * 4 + h];
        float ss = 0.f, vx = 0.f, vy = 0.f;
        for (int q = 0; q < n; q += 8) {
            bool b1 = q + 1 < n, b2 = q + 2 < n, b3 = q + 3 < n;
            bool b4 = q + 4 < n, b5 = q + 5 < n, b6 = q + 6 < n, b7 = q + 7 < n;
            AGG_LOAD(0, true) AGG_LOAD(1, b1) AGG_LOAD(2, b2) AGG_LOAD(3, b3)
            AGG_LOAD(4, b4) AGG_LOAD(5, b5) AGG_LOAD(6, b6) AGG_LOAD(7, b7)
            AGG_UPD(0, true) AGG_UPD(1, b1) AGG_UPD(2, b2) AGG_UPD(3, b3)
            AGG_UPD(4, b4) AGG_UPD(5, b5) AGG_UPD(6, b6) AGG_UPD(7, b7)
        }
        float inv = ss > 0.f ? 1.f / ss : 0.f;
        float2 o; o.x = vx * inv; o.y = vy * inv;
        agg2v[(size_t)j * 64 + lane] = o;
    }
}

// ---------------------------------------------------------------------------
extern "C" void kernel_launch(void* const* d_in, const int* in_sizes, int n_in,
                              void* d_out, int out_size, void* d_ws, size_t ws_size,
                              hipStream_t stream) {
    static const int expect[29] = {
        6400000, 3840000, 1280000, 640000,
        500000, 500000, 500000, 500000, 250000, 250000, 250000, 250000,
        1000000, 750000, 65536, 512, 65536, 512, 512, 320, 256,
        8192, 128, 384, 128, 16384, 128, 65536, 512};
    int bad = 0;
    if (n_in != 29) bad = 1;
    else {
        for (int i = 0; i < 29; i++)
            if (in_sizes[i] != expect[i]) { bad = 4 + i; break; }
    }
    if (!bad && out_size != 12160000) bad = 2;
    if (!bad && ws_size < (size_t)63425536) bad = 3;
    if (bad) {
        senthost_k<<<1, 1, 0, stream>>>((float*)d_out, 4096.f * (float)bad);
        return;
    }

    const float* x_chem = (const float*)d_in[0];
    const float* x_gene = (const float*)d_in[1];
    const float* x_dis  = (const float*)d_in[2];
    const float* x_path = (const float*)d_in[3];
    const int* src0 = (const int*)d_in[4];  const int* dst0 = (const int*)d_in[5];
    const int* src1 = (const int*)d_in[6];  const int* dst1 = (const int*)d_in[7];
    const int* src2 = (const int*)d_in[8];  const int* dst2 = (const int*)d_in[9];
    const int* src3 = (const int*)d_in[10]; const int* dst3 = (const int*)d_in[11];
    const int*   cg   = (const int*)d_in[12];
    const float* cp   = (const float*)d_in[13];
    const float* Wsrc = (const float*)d_in[14]; const float* bsrc = (const float*)d_in[15];
    const float* Wdst = (const float*)d_in[16]; const float* bdst = (const float*)d_in[17];
    const float* attn = (const float*)d_in[18];
    const float* temb = (const float*)d_in[19]; const float* semb = (const float*)d_in[20];
    const float* Wg   = (const float*)d_in[21]; const float* bg   = (const float*)d_in[22];
    const float* W1c  = (const float*)d_in[23]; const float* b1c  = (const float*)d_in[24];
    const float* W2c  = (const float*)d_in[25]; const float* b2c  = (const float*)d_in[26];
    const float* Wout = (const float*)d_in[27]; const float* bout = (const float*)d_in[28];

    constexpr int NC = 50000, NG = 30000, ND = 10000, NP = 5000;
    constexpr int E2 = 250000;
    constexpr int ET = 1500000;
    constexpr int GCAP = 80000;

    char* ws = (char*)d_ws;
    float* gt   = (float*)ws;              // [64][128] f32 = 32768 B
    int*   csum = (int*)(ws + 32768);      // 4 x 64 ints = 1024 B
    float* avb  = (float*)(ws + 36864);    // 4 slots x 520 floats
    u16*   w2p  = (u16*)  (ws + 49152);    // packed W2 fragments, 32768 B
    char*  A    = ws + 98304;              // stage arena

    // CSR block [A+50,780,000 .. A+61,160,000] — untouched by any stage peak.
    char* CB = A + 50780000;
    int* degU = (int*)(CB);                 // 115000 ints
    int* stsU = (int*)(CB + 460000);
    int* curU = (int*)(CB + 920000);
    int* sp1   = (int*)(CB + 1380000);      // t1 srcp (500K)
    int* sp2   = (int*)(CB + 3380000);      // t2 srcp (250K)
    int* perm2 = (int*)(CB + 4380000);      // t2 perm (250K)
    int* sp0   = (int*)(CB + 5380000);      // t0 srcp (500K)
    int* cmb0  = (int*)(CB + 7380000);      // t0 cmb  (500K)
    int* sp3   = (int*)(CB + 9380000);      // t3 srcp (250K)  ends CB+10,380,000

    float* out = (float*)d_out;
    float* out_chem = out;
    float* out_gene = out + (size_t)NC * 128;
    float* out_dis  = out + (size_t)(NC + NG) * 128;
    float* out_path = out + (size_t)(NC + NG + ND) * 128;

    // ---------- prep + batched CSR build (all 4 edge types) ----------
    prep_k<<<44, 256, 0, stream>>>(temb, semb, Wg, bg, gt, Wdst, bdst, attn, avb, W2c, w2p);
    zero_k<<<(115000 + 255) / 256, 256, 0, stream>>>(degU, 115000);
    hist4_k<<<(ET + 255) / 256, 256, 0, stream>>>(dst1, dst2, dst0, dst3, degU);
    {
        dim3 g1(49, 4);
        scan1b_k<<<g1, 256, 0, stream>>>(degU, csum);
        scan2b_k<<<1, 64, 0, stream>>>(csum);
        scan3b_k<<<g1, 256, 0, stream>>>(degU, csum, stsU, curU);
    }
    scatter4_k<<<(ET + 255) / 256, 256, 0, stream>>>(dst1, src1, dst2, src2, dst0, src0,
                                                     dst3, src3, cg, curU,
                                                     sp1, sp2, perm2, sp0, cmb0, sp3);

    // ---------- STAGE A: chemical output (t1: gene -> chemical) ----------
    {
        float* hs1  = (float*)(A);                 //  0 .. 15,360,000
        float* ad1  = (float*)(A + 15360000);      // .. 16,160,000
        float* hsa1 = (float*)(A + 16160000);      // .. 16,640,000
        float* agg1 = (float*)(A + 16640000);      // .. 42,240,000
        denseT_k<1><<<(NG + 31) / 32, 256, 0, stream>>>(x_gene, nullptr,
                                                        Wsrc + 1 * 16384, bsrc + 1 * 128, hs1, NG, (NG + 31) / 32);
        hsa_k<<<512, 256, 0, stream>>>(hs1, attn + 1 * 128, hsa1, NG);
        adg_k<<<1024, 256, 0, stream>>>(x_chem, avb + 1 * 520, avb + 1 * 520 + 512, ad1, NC);
        agg_k<4><<<2048, 256, 0, stream>>>(hs1, ad1, hsa1, sp1, nullptr, stsU + 0, degU + 0,
                                           attn + 1 * 128, nullptr, nullptr, agg1, 0, NC);
        denseT_k<1><<<(NC + 31) / 32, 256, 0, stream>>>(agg1, nullptr,
                                                        Wout + 0 * 16384, bout + 0 * 128, out_chem, NC, (NC + 31) / 32);
    }

    // ---------- STAGE B: pathway output (t2: chemical -> pathway) ----------
    {
        float* hs2  = (float*)(A);                 //  0 .. 25,600,000
        float* ad2  = (float*)(A + 25600000);      // .. 25,680,000
        float* agg2 = (float*)(A + 25680000);      // .. 28,240,000
        u16*   gatep = (u16*) (A + 28240000);      // .. 48,720,000
        denseT_k<1><<<(NC + 31) / 32, 256, 0, stream>>>(x_chem, nullptr,
                                                        Wsrc + 2 * 16384, bsrc + 2 * 128, hs2, NC, (NC + 31) / 32);
        adg_k<<<256, 256, 0, stream>>>(x_path, avb + 2 * 520, avb + 2 * 520 + 512, ad2, NP);
        for (int ck = 0; ck < 4; ck++) {
            int j0 = ck * 1250, j1 = j0 + 1250;
            ugmm_k<<<1024, 256, 0, stream>>>(cp, W1c, b1c, w2p, b2c, perm2, stsU + 50000, gatep,
                                             j0, j1, NP, E2, GCAP);
            agg_k<3><<<313, 256, 0, stream>>>(hs2, ad2, nullptr, sp2, nullptr,
                                              stsU + 50000, degU + 50000,
                                              attn + 2 * 128, nullptr, gatep, agg2, j0, j1);
        }
        denseT_k<1><<<(NP + 31) / 32, 256, 0, stream>>>(agg2, nullptr,
                                                        Wout + 3 * 16384, bout + 3 * 128, out_path, NP, (NP + 31) / 32);
    }

    // ---------- STAGE C: gene output (t0 + t3) ----------
    {
        float* hs0  = (float*)(A);                 //  0 .. 25,600,000 (phase 1)
        float* ad0  = (float*)(A + 25600000);      // .. 26,080,000
        float* ad3  = (float*)(A + 26080000);      // .. 26,560,000
        float* hsa3 = (float*)(A + 26560000);      // .. 26,720,000
        float* agg0 = (float*)(A + 26720000);      // .. 42,080,000
        float* hs3  = (float*)(A);                 //  0 .. 5,120,000 (phase 2)
        float* agg3 = (float*)(A + 5120000);       // .. 20,480,000 (phase 2, hs0 dead)
        denseT_k<1><<<(NC + 31) / 32, 256, 0, stream>>>(x_chem, nullptr,
                                                        Wsrc + 0 * 16384, bsrc + 0 * 128, hs0, NC, (NC + 31) / 32);
        adg2_k<<<1024, 256, 0, stream>>>(x_gene, avb + 0 * 520, avb + 0 * 520 + 512,
                                         avb + 3 * 520, avb + 3 * 520 + 512, ad0, ad3, NG);
        agg_k<1><<<2048, 256, 0, stream>>>(hs0, ad0, nullptr, sp0, cmb0,
                                           stsU + 55000, degU + 55000,
                                           attn + 0 * 128, gt, nullptr, agg0, 0, NG);
        denseT_k<1><<<(ND + 31) / 32, 256, 0, stream>>>(x_dis, nullptr,
                                                        Wsrc + 3 * 16384, bsrc + 3 * 128, hs3, ND, (ND + 31) / 32);
        hsa_k<<<256, 256, 0, stream>>>(hs3, attn + 3 * 128, hsa3, ND);
        agg_k<4><<<2048, 256, 0, stream>>>(hs3, ad3, hsa3, sp3, nullptr,
                                           stsU + 85000, degU + 85000,
                                           attn + 3 * 128, nullptr, nullptr, agg3, 0, NG);
        denseT_k<2><<<(NG + 31) / 32, 256, 0, stream>>>(agg0, agg3,
                                                        Wout + 1 * 16384, bout + 1 * 128, out_gene, NG, (NG + 31) / 32);
    }

    // ---------- STAGE D: disease output (no incoming edges: bias only) ------
    biasrow_k<<<(ND * 64 + 255) / 256, 256, 0, stream>>>(bout + 2 * 128, out_dis, ND);
}

// Round 15
// 946.802 us; speedup vs baseline: 2.4057x; 1.0105x over previous
//
#include <hip/hip_runtime.h>

// EdgeAttrHeteroConv — round 22 (= R21 resubmitted verbatim; R21 died on
// GPUAcquisitionTimeout before measurement; audit re-done: payload packing
// exact, int2 alignment fine, fused-HSA bit-identical). R20 = 956.7 us; top
// dispatch scatter4_k ~103 us: WRITE_SIZE 116 MB for ~10 MB payload ->
// WRITE-AMPLIFICATION-bound. This round:
// (a) ONE payload store per edge: t0 packs si|cmb<<16 (si<65536), t2 packs
//     int2{si, edge_id}; consumers decode. Line-touches 2.25M -> 1.5M.
// (b) hsa fused into denseT epilogue (rows already in registers; identical
//     reduce expression+order -> bit-identical); -2 dispatches, -20MB reads.
// Everything else identical to R20 (verified 956.7 us, absmax 1.95e-3).

typedef unsigned short u16;
typedef _Float16 f16x8 __attribute__((ext_vector_type(8)));
typedef float f32x4 __attribute__((ext_vector_type(4)));
union H2U { unsigned u; _Float16 h[2]; };
union HSU { _Float16 f; unsigned short s; };
union U4F8 { uint4 u; f16x8 h; };

__device__ __forceinline__ float sigm(float x) { return 1.f / (1.f + expf(-x)); }

// ---------------------------------------------------------------------------
__global__ void zero_k(int* __restrict__ p, int n) {
    int i = blockIdx.x * 256 + threadIdx.x;
    if (i < n) p[i] = 0;
}

__global__ void senthost_k(float* out, float v) { out[0] = v; }

// ---------------------------------------------------------------------------
// Batched CSR build. Unified deg/sts/cur arrays, type offsets:
//   t1@0 (NC), t2@50000 (NP), t0@55000 (NG), t3@85000 (NG). Total 115000.
__global__ void hist4_k(const int* __restrict__ dst1, const int* __restrict__ dst2,
                        const int* __restrict__ dst0, const int* __restrict__ dst3,
                        int* __restrict__ degU) {
    int e = blockIdx.x * 256 + threadIdx.x;
    if (e >= 1500000) return;
    int d, off, Nd;
    if (e < 500000)       { d = dst1[e];           off = 0;     Nd = 50000; }
    else if (e < 750000)  { d = dst2[e - 500000];  off = 50000; Nd = 5000;  }
    else if (e < 1250000) { d = dst0[e - 750000];  off = 55000; Nd = 30000; }
    else                  { d = dst3[e - 1250000]; off = 85000; Nd = 30000; }
    d = d < 0 ? 0 : (d >= Nd ? Nd - 1 : d);
    atomicAdd(&degU[off + d], 1);
}

__global__ void scan1b_k(const int* __restrict__ degU, int* __restrict__ csum) {
    const int degOff[4] = {0, 50000, 55000, 85000};
    const int NdT[4]    = {50000, 5000, 30000, 30000};
    __shared__ int red[256];
    int ty = blockIdx.y;
    int Nd = NdT[ty];
    int base = blockIdx.x * 1024;
    if (base >= Nd) return;
    int t = threadIdx.x;
    int s = 0;
    for (int i = 0; i < 4; i++) {
        int idx = base + t * 4 + i;
        if (idx < Nd) s += degU[degOff[ty] + idx];
    }
    red[t] = s;
    __syncthreads();
    for (int off = 128; off > 0; off >>= 1) {
        if (t < off) red[t] += red[t + off];
        __syncthreads();
    }
    if (t == 0) csum[ty * 64 + blockIdx.x] = red[0];
}

__global__ void scan2b_k(int* __restrict__ csum) {
    const int nchT[4] = {49, 5, 30, 30};
    int t = threadIdx.x;
    if (t < 4) {
        int acc = 0;
        for (int i = 0; i < nchT[t]; i++) {
            int v = csum[t * 64 + i]; csum[t * 64 + i] = acc; acc += v;
        }
    }
}

__global__ void scan3b_k(const int* __restrict__ degU, const int* __restrict__ csum,
                         int* __restrict__ stsU, int* __restrict__ curU) {
    const int degOff[4] = {0, 50000, 55000, 85000};
    const int NdT[4]    = {50000, 5000, 30000, 30000};
    __shared__ int sc[256];
    int ty = blockIdx.y;
    int Nd = NdT[ty];
    int base = blockIdx.x * 1024;
    if (base >= Nd) return;
    int off = degOff[ty];
    int t = threadIdx.x;
    int v[4];
    int s = 0;
    for (int i = 0; i < 4; i++) {
        int idx = base + t * 4 + i;
        v[i] = idx < Nd ? degU[off + idx] : 0;
        s += v[i];
    }
    sc[t] = s;
    __syncthreads();
    for (int o = 1; o < 256; o <<= 1) {
        int add = (t >= o) ? sc[t - o] : 0;
        __syncthreads();
        sc[t] += add;
        __syncthreads();
    }
    int excl = sc[t] - s + csum[ty * 64 + blockIdx.x];
    for (int i = 0; i < 4; i++) {
        int idx = base + t * 4 + i;
        if (idx < Nd) { stsU[off + idx] = excl; curU[off + idx] = excl; excl += v[i]; }
    }
}

// ONE payload store per edge: t1/t3 plain si; t0 si|cmb<<16; t2 int2{si,el}.
__global__ void scatter4_k(const int* __restrict__ dst1, const int* __restrict__ src1,
                           const int* __restrict__ dst2, const int* __restrict__ src2,
                           const int* __restrict__ dst0, const int* __restrict__ src0,
                           const int* __restrict__ dst3, const int* __restrict__ src3,
                           const int* __restrict__ cg, int* __restrict__ curU,
                           int* __restrict__ sp1, int2* __restrict__ sp2i,
                           int* __restrict__ sp0, int* __restrict__ sp3) {
    int e = blockIdx.x * 256 + threadIdx.x;
    if (e >= 1500000) return;
    if (e < 500000) {
        int d = dst1[e]; d = d < 0 ? 0 : (d >= 50000 ? 49999 : d);
        int p = atomicAdd(&curU[0 + d], 1);
        int si = src1[e]; si = si < 0 ? 0 : (si >= 30000 ? 29999 : si);
        sp1[p] = si;
    } else if (e < 750000) {
        int el = e - 500000;
        int d = dst2[el]; d = d < 0 ? 0 : (d >= 5000 ? 4999 : d);
        int p = atomicAdd(&curU[50000 + d], 1);
        int si = src2[el]; si = si < 0 ? 0 : (si >= 50000 ? 49999 : si);
        int2 v; v.x = si; v.y = el;
        sp2i[p] = v;
    } else if (e < 1250000) {
        int el = e - 750000;
        int d = dst0[el]; d = d < 0 ? 0 : (d >= 30000 ? 29999 : d);
        int p = atomicAdd(&curU[55000 + d], 1);
        int si = src0[el]; si = si < 0 ? 0 : (si >= 50000 ? 49999 : si);
        int a = cg[2 * el] & 7, b = cg[2 * el + 1] & 7;
        sp0[p] = si | ((a * 8 + b) << 16);
    } else {
        int el = e - 1250000;
        int d = dst3[el]; d = d < 0 ? 0 : (d >= 30000 ? 29999 : d);
        int p = atomicAdd(&curU[85000 + d], 1);
        int si = src3[el]; si = si < 0 ? 0 : (si >= 10000 ? 9999 : si);
        sp3[p] = si;
    }
}

// ---------------------------------------------------------------------------
// Fused prep: gtbl (blocks 0..31), avprep x4 (blocks 32..35), w2pack (36..43).
__global__ void prep_k(const float* __restrict__ temb, const float* __restrict__ semb,
                       const float* __restrict__ Wg, const float* __restrict__ bg,
                       float* __restrict__ gtbl,
                       const float* __restrict__ Wdst, const float* __restrict__ bdst,
                       const float* __restrict__ attn, float* __restrict__ avb,
                       const float* __restrict__ W2c, u16* __restrict__ w2p) {
    int b = blockIdx.x;
    if (b < 32) {
        int idx = b * 256 + threadIdx.x;
        int combo = idx >> 7, c = idx & 127;
        int a = combo >> 3, bb_ = combo & 7;
        float s = bg[c];
        for (int k = 0; k < 32; k++) s += temb[a * 32 + k] * Wg[k * 128 + c];
        for (int k = 0; k < 32; k++) s += semb[bb_ * 32 + k] * Wg[(32 + k) * 128 + c];
        gtbl[combo * 128 + c] = sigm(s);
    } else if (b < 36) {
        if (threadIdx.x < 128) {
            int ty = b - 32;
            const float* Wd = Wdst + ty * 16384;
            const float* bd = bdst + ty * 128;
            const float* at = attn + ty * 128;
            float* av = avb + ty * 520;
            float* bb = av + 512;
            int k = threadIdx.x;
            float a0 = 0.f, a1 = 0.f, a2 = 0.f, a3 = 0.f;
            for (int c = 0; c < 32; c++) {
                a0 += Wd[k * 128 + 0 * 32 + c] * at[0 * 32 + c];
                a1 += Wd[k * 128 + 1 * 32 + c] * at[1 * 32 + c];
                a2 += Wd[k * 128 + 2 * 32 + c] * at[2 * 32 + c];
                a3 += Wd[k * 128 + 3 * 32 + c] * at[3 * 32 + c];
            }
            float4 o; o.x = a0; o.y = a1; o.z = a2; o.w = a3;
            ((float4*)av)[k] = o;
            if (k < 4) {
                float s = 0.f;
                for (int c = 0; c < 32; c++) s += bd[k * 32 + c] * at[k * 32 + c];
                bb[k] = s;
            }
        }
    } else {
        int t = (b - 36) * 256 + threadIdx.x;    // 0..2047
        if (t < 2048) {
            int l = t & 63;
            int tile = t >> 6;                   // ct*4 + kb
            int ct = tile >> 2, kb = tile & 3;
            int k0 = kb * 32 + (l >> 4) * 8;
            int c  = ct * 16 + (l & 15);
            for (int i = 0; i < 8; i++) {
                HSU cv; cv.f = (_Float16)W2c[(k0 + i) * 128 + c];
                w2p[(size_t)t * 8 + i] = cv.s;
            }
        }
    }
}

// ---------------------------------------------------------------------------
__global__ __launch_bounds__(256) void adg_k(const float* __restrict__ x,
                                             const float* __restrict__ av,
                                             const float* __restrict__ bb,
                                             float* __restrict__ ad, int N) {
    int l = threadIdx.x & 63;
    int gw = (blockIdx.x * 256 + threadIdx.x) >> 6;
    int nw = gridDim.x * 4;
    float4 av0 = ((const float4*)av)[2 * l];
    float4 av1 = ((const float4*)av)[2 * l + 1];
    float4 bbv = *(const float4*)bb;
    const float2* x2 = (const float2*)x;
    for (int j = gw; j < N; j += nw) {
        float2 xv = x2[(size_t)j * 64 + l];
        float p0 = xv.x * av0.x + xv.y * av1.x;
        float p1 = xv.x * av0.y + xv.y * av1.y;
        float p2 = xv.x * av0.z + xv.y * av1.z;
        float p3 = xv.x * av0.w + xv.y * av1.w;
        #pragma unroll
        for (int off = 1; off < 64; off <<= 1) {
            p0 += __shfl_xor(p0, off);
            p1 += __shfl_xor(p1, off);
            p2 += __shfl_xor(p2, off);
            p3 += __shfl_xor(p3, off);
        }
        if (l == 0) {
            float4 o; o.x = p0 + bbv.x; o.y = p1 + bbv.y; o.z = p2 + bbv.z; o.w = p3 + bbv.w;
            *(float4*)&ad[(size_t)j * 4] = o;
        }
    }
}

// Two edge types' ad from one pass over x (stage C: ad0 + ad3 from x_gene).
__global__ __launch_bounds__(256) void adg2_k(const float* __restrict__ x,
                                              const float* __restrict__ avA,
                                              const float* __restrict__ bbA,
                                              const float* __restrict__ avB,
                                              const float* __restrict__ bbB,
                                              float* __restrict__ adA,
                                              float* __restrict__ adB, int N) {
    int l = threadIdx.x & 63;
    int gw = (blockIdx.x * 256 + threadIdx.x) >> 6;
    int nw = gridDim.x * 4;
    float4 aA0 = ((const float4*)avA)[2 * l];
    float4 aA1 = ((const float4*)avA)[2 * l + 1];
    float4 aB0 = ((const float4*)avB)[2 * l];
    float4 aB1 = ((const float4*)avB)[2 * l + 1];
    float4 bA = *(const float4*)bbA;
    float4 bB = *(const float4*)bbB;
    const float2* x2 = (const float2*)x;
    for (int j = gw; j < N; j += nw) {
        float2 xv = x2[(size_t)j * 64 + l];
        float p0 = xv.x * aA0.x + xv.y * aA1.x;
        float p1 = xv.x * aA0.y + xv.y * aA1.y;
        float p2 = xv.x * aA0.z + xv.y * aA1.z;
        float p3 = xv.x * aA0.w + xv.y * aA1.w;
        float r0 = xv.x * aB0.x + xv.y * aB1.x;
        float r1 = xv.x * aB0.y + xv.y * aB1.y;
        float r2 = xv.x * aB0.z + xv.y * aB1.z;
        float r3 = xv.x * aB0.w + xv.y * aB1.w;
        #pragma unroll
        for (int off = 1; off < 64; off <<= 1) {
            p0 += __shfl_xor(p0, off); p1 += __shfl_xor(p1, off);
            p2 += __shfl_xor(p2, off); p3 += __shfl_xor(p3, off);
            r0 += __shfl_xor(r0, off); r1 += __shfl_xor(r1, off);
            r2 += __shfl_xor(r2, off); r3 += __shfl_xor(r3, off);
        }
        if (l == 0) {
            float4 oa; oa.x = p0 + bA.x; oa.y = p1 + bA.y; oa.z = p2 + bA.z; oa.w = p3 + bA.w;
            float4 ob; ob.x = r0 + bB.x; ob.y = r1 + bB.y; ob.z = r2 + bB.z; ob.w = r3 + bB.w;
            *(float4*)&adA[(size_t)j * 4] = oa;
            *(float4*)&adB[(size_t)j * 4] = ob;
        }
    }
}

// ---------------------------------------------------------------------------
// Tiled dense: 32-row x tile in LDS (16 KB), 4 waves x 8 rows, 2 ch/lane.
// HSA=1: additionally emit hsa[j][h] (identical expression + shfl order as
// the old hsa_k -> bit-identical).
#define STEP4(A, XV)                                     \
    A.x += XV.x * w0.x; A.y += XV.x * w0.y;              \
    A.x += XV.y * w1.x; A.y += XV.y * w1.y;              \
    A.x += XV.z * w2.x; A.y += XV.z * w2.y;              \
    A.x += XV.w * w3.x; A.y += XV.w * w3.y;

#define HSA_ROW(A, RIDX)                                                     \
    {                                                                        \
        float tt = A.x * ax + A.y * ay;                                      \
        tt += __shfl_xor(tt, 1); tt += __shfl_xor(tt, 2);                    \
        tt += __shfl_xor(tt, 4); tt += __shfl_xor(tt, 8);                    \
        if ((l & 15) == 0 && (RIDX) < N) hsaOut[(size_t)(RIDX) * 4 + h] = tt; \
    }

template <int NIN, int HSA>
__global__ __launch_bounds__(256) void denseT_k(const float* __restrict__ X,
                                                const float* __restrict__ Xb,
                                                const float* __restrict__ W,
                                                const float* __restrict__ bias,
                                                float* __restrict__ O,
                                                const float* __restrict__ attn_t,
                                                float* __restrict__ hsaOut,
                                                int N, int NT) {
    __shared__ float4 xs4[1024];               // 32 rows x 128 ch = 16 KB
    int t = threadIdx.x;
    int l = t & 63, w = t >> 6;
    float2 bi = *(const float2*)&bias[2 * l];
    float ax = 0.f, ay = 0.f;
    int h = l >> 4;
    if (HSA) { ax = attn_t[2 * l]; ay = attn_t[2 * l + 1]; }
    const float4* X4 = (const float4*)X;
    const float4* B4 = (const float4*)Xb;
    const float2* Wv = (const float2*)W;
    float2* O2 = (float2*)O;
    for (int tile = blockIdx.x; tile < NT; tile += gridDim.x) {
        int R0 = tile * 32;
        #pragma unroll
        for (int i = 0; i < 4; i++) {
            int idx = t + 256 * i;
            int r = R0 + (idx >> 5);
            int rc = min(r, N - 1);
            float4 v = X4[(size_t)rc * 32 + (idx & 31)];
            if (NIN == 2) {
                float4 b = B4[(size_t)rc * 32 + (idx & 31)];
                v.x += b.x; v.y += b.y; v.z += b.z; v.w += b.w;
            }
            xs4[idx] = v;
        }
        __syncthreads();
        float2 a0 = bi, a1 = bi, a2 = bi, a3 = bi, a4 = bi, a5 = bi, a6 = bi, a7 = bi;
        int rb = 8 * w;
        #pragma unroll 2
        for (int kb = 0; kb < 32; kb++) {
            float2 w0 = Wv[(4 * kb + 0) * 64 + l];
            float2 w1 = Wv[(4 * kb + 1) * 64 + l];
            float2 w2 = Wv[(4 * kb + 2) * 64 + l];
            float2 w3 = Wv[(4 * kb + 3) * 64 + l];
            float4 x0 = xs4[(rb + 0) * 32 + kb];
            float4 x1 = xs4[(rb + 1) * 32 + kb];
            float4 x2 = xs4[(rb + 2) * 32 + kb];
            float4 x3 = xs4[(rb + 3) * 32 + kb];
            float4 x4v = xs4[(rb + 4) * 32 + kb];
            float4 x5 = xs4[(rb + 5) * 32 + kb];
            float4 x6 = xs4[(rb + 6) * 32 + kb];
            float4 x7 = xs4[(rb + 7) * 32 + kb];
            STEP4(a0, x0) STEP4(a1, x1) STEP4(a2, x2) STEP4(a3, x3)
            STEP4(a4, x4v) STEP4(a5, x5) STEP4(a6, x6) STEP4(a7, x7)
        }
        int rbase = R0 + rb;
        if (rbase + 0 < N) O2[(size_t)(rbase + 0) * 64 + l] = a0;
        if (rbase + 1 < N) O2[(size_t)(rbase + 1) * 64 + l] = a1;
        if (rbase + 2 < N) O2[(size_t)(rbase + 2) * 64 + l] = a2;
        if (rbase + 3 < N) O2[(size_t)(rbase + 3) * 64 + l] = a3;
        if (rbase + 4 < N) O2[(size_t)(rbase + 4) * 64 + l] = a4;
        if (rbase + 5 < N) O2[(size_t)(rbase + 5) * 64 + l] = a5;
        if (rbase + 6 < N) O2[(size_t)(rbase + 6) * 64 + l] = a6;
        if (rbase + 7 < N) O2[(size_t)(rbase + 7) * 64 + l] = a7;
        if (HSA) {
            HSA_ROW(a0, rbase + 0) HSA_ROW(a1, rbase + 1)
            HSA_ROW(a2, rbase + 2) HSA_ROW(a3, rbase + 3)
            HSA_ROW(a4, rbase + 4) HSA_ROW(a5, rbase + 5)
            HSA_ROW(a6, rbase + 6) HSA_ROW(a7, rbase + 7)
        }
        __syncthreads();
    }
}

// bias-only rows (disease output)
__global__ void biasrow_k(const float* __restrict__ bo, float* __restrict__ out, int N) {
    int idx = blockIdx.x * 256 + threadIdx.x;
    if (idx < N * 64) {
        float2 bi = *(const float2*)&bo[2 * (idx & 63)];
        ((float2*)out)[idx] = bi;
    }
}

// ---------------------------------------------------------------------------
// ugmm: fused t2 gate. One wave per 16-edge row-block. perm read from
// int2 payload (.y) at stride 2.
__global__ __launch_bounds__(256) void ugmm_k(const float* __restrict__ cp,
                                              const float* __restrict__ W1c, const float* __restrict__ b1c,
                                              const u16* __restrict__ w2p, const float* __restrict__ b2c,
                                              const int* __restrict__ sp2i, const int* __restrict__ starts,
                                              u16* __restrict__ gate,
                                              int j0, int j1, int NP_, int E, int CAP) {
    __shared__ float f6[640];                  // [0..384) W1 rows, [384..512) b1, [512..640) b2
    for (int i = threadIdx.x; i < 640; i += 256) {
        f6[i] = (i < 384) ? W1c[i] : (i < 512 ? b1c[i - 384] : b2c[i - 512]);
    }
    __syncthreads();
    int lane = threadIdx.x & 63;
    int wv = (blockIdx.x * 256 + threadIdx.x) >> 6;
    int nw = gridDim.x * 4;
    int q0 = starts[j0];
    int q1 = (j1 >= NP_) ? E : starts[j1];
    int cnt = min(q1 - q0, CAP);
    if (cnt <= 0) return;
    int nrb = (cnt + 15) >> 4;
    const uint4* wp4 = (const uint4*)w2p;
    int colr = lane & 15, grp = lane >> 4;
    for (int rb = wv; rb < nrb; rb += nw) {
        int r0 = rb * 16;
        float c0v = 0.f, c1v = 0.f, c2v = 0.f;
        if (lane < 16) {
            int arow = r0 + lane;
            if (arow >= cnt) arow = cnt - 1;
            int e = sp2i[2 * (q0 + arow) + 1];
            c0v = cp[(size_t)e * 3 + 0];
            c1v = cp[(size_t)e * 3 + 1];
            c2v = cp[(size_t)e * 3 + 2];
        }
        float p0 = __shfl(c0v, colr);
        float p1 = __shfl(c1v, colr);
        float p2 = __shfl(c2v, colr);
        U4F8 af[4];
        #pragma unroll
        for (int kb = 0; kb < 4; kb++) {
            f16x8 v;
            #pragma unroll
            for (int i = 0; i < 8; i++) {
                int c = kb * 32 + grp * 8 + i;
                float z = f6[384 + c] + p0 * f6[c] + p1 * f6[128 + c] + p2 * f6[256 + c];
                float u = 0.5f * z * (1.f + erff(z * 0.70710678118654752f));
                v[i] = (_Float16)u;
            }
            af[kb].h = v;
        }
        #pragma unroll
        for (int ct = 0; ct < 8; ct++) {
            float b2v = f6[512 + ct * 16 + colr];
            f32x4 acc = {b2v, b2v, b2v, b2v};
            U4F8 b0, b1, b2, b3;
            b0.u = wp4[(ct * 4 + 0) * 64 + lane];
            b1.u = wp4[(ct * 4 + 1) * 64 + lane];
            b2.u = wp4[(ct * 4 + 2) * 64 + lane];
            b3.u = wp4[(ct * 4 + 3) * 64 + lane];
            acc = __builtin_amdgcn_mfma_f32_16x16x32_f16(af[0].h, b0.h, acc, 0, 0, 0);
            acc = __builtin_amdgcn_mfma_f32_16x16x32_f16(af[1].h, b1.h, acc, 0, 0, 0);
            acc = __builtin_amdgcn_mfma_f32_16x16x32_f16(af[2].h, b2.h, acc, 0, 0, 0);
            acc = __builtin_amdgcn_mfma_f32_16x16x32_f16(af[3].h, b3.h, acc, 0, 0, 0);
            int col = ct * 16 + colr;
            #pragma unroll
            for (int r = 0; r < 4; r++) {
                int row = r0 + grp * 4 + r;
                if (row < cnt) {
                    HSU cv; cv.f = (_Float16)sigm(acc[r]);
                    gate[(size_t)row * 128 + col] = cv.s;
                }
            }
        }
    }
}

// ---------------------------------------------------------------------------
// Gather aggregation: ONE destination per wave, EIGHT edges batched.
// Clamp-softmax (logits O(5), clamp +-60, R7-verified) + __expf.
// MODE 1: packed si|cmb<<16 payload, LDS gtbl. MODE 3: int2 payload (.x=si),
// f16 gate. MODE 4: plain si payload, logit from hsa.
#define AGG_LOAD(K, ACT)                                                     \
    float2 hv##K; float2 gv##K; unsigned gu##K = 0; float pl##K = 0.f;       \
    if (ACT) {                                                               \
        int si;                                                              \
        if (MODE == 1) { int v = srcp[st + q + K]; si = v & 0xFFFF;          \
                         gv##K = gl2[(v >> 16) * 64 + lane]; }               \
        else if (MODE == 3) { si = srcp[2 * (st + q + K)];                   \
                              int qq = st + q + K - q0base;                  \
                              qq = qq < 79999 ? qq : 79999;                  \
                              gu##K = g32[(size_t)qq * 64 + lane]; }         \
        else { si = srcp[st + q + K]; pl##K = hsa[(size_t)si * 4 + h]; }     \
        hv##K = hs2v[(size_t)si * 64 + lane];                                \
    }

#define AGG_UPD(K, ACT)                                                      \
    if (ACT) {                                                               \
        float mx = hv##K.x, my = hv##K.y;                                    \
        float p;                                                             \
        if (MODE == 4) {                                                     \
            p = pl##K;                                                       \
        } else {                                                             \
            if (MODE == 1) { mx *= gv##K.x; my *= gv##K.y; }                 \
            if (MODE == 3) { H2U gz; gz.u = gu##K; mx *= (float)gz.h[0]; my *= (float)gz.h[1]; } \
            p = mx * ax + my * ay;                                           \
            p += __shfl_xor(p, 1); p += __shfl_xor(p, 2);                    \
            p += __shfl_xor(p, 4); p += __shfl_xor(p, 8);                    \
        }                                                                    \
        float logit = p + adv;                                               \
        logit = logit > 0.f ? logit : 0.2f * logit;                          \
        logit = fminf(fmaxf(logit, -60.f), 60.f);                            \
        float ex = __expf(logit);                                            \
        ss += ex; vx += ex * mx; vy += ex * my;                              \
    }

template <int MODE>
__global__ __launch_bounds__(256) void agg_k(const float* __restrict__ hs,
                                             const float* __restrict__ ad,
                                             const float* __restrict__ hsa,
                                             const int* __restrict__ srcp,
                                             const int* __restrict__ starts,
                                             const int* __restrict__ deg,
                                             const float* __restrict__ attn_t,
                                             const float* __restrict__ gtbl,
                                             const u16* __restrict__ gate,
                                             float* __restrict__ agg,
                                             int j0, int j1) {
    __shared__ float4 gt_sh[MODE == 1 ? 2048 : 1];   // 32 KB gate table
    if (MODE == 1) {
        const float4* g4 = (const float4*)gtbl;
        for (int i = threadIdx.x; i < 2048; i += 256) gt_sh[i] = g4[i];
        __syncthreads();
    }
    const float2* gl2 = (const float2*)gt_sh;
    int lane = threadIdx.x & 63;
    int gw = (blockIdx.x * 256 + threadIdx.x) >> 6;
    int nw = gridDim.x * 4;
    int c0 = 2 * lane;
    float ax = attn_t[c0], ay = attn_t[c0 + 1];
    int h = lane >> 4;
    const float2* hs2v = (const float2*)hs;
    const unsigned* g32 = (const unsigned*)gate;
    float2* agg2v = (float2*)agg;
    int q0base = 0;
    if (MODE == 3) q0base = __builtin_amdgcn_readfirstlane(starts[j0]);
    for (int j = j0 + gw; j < j1; j += nw) {
        int st = __builtin_amdgcn_readfirstlane(starts[j]);
        int n  = __builtin_amdgcn_readfirstlane(deg[j]);
        float adv = ad[(size_t)j * 4 + h];
        float ss = 0.f, vx = 0.f, vy = 0.f;
        for (int q = 0; q < n; q += 8) {
            bool b1 = q + 1 < n, b2 = q + 2 < n, b3 = q + 3 < n;
            bool b4 = q + 4 < n, b5 = q + 5 < n, b6 = q + 6 < n, b7 = q + 7 < n;
            AGG_LOAD(0, true) AGG_LOAD(1, b1) AGG_LOAD(2, b2) AGG_LOAD(3, b3)
            AGG_LOAD(4, b4) AGG_LOAD(5, b5) AGG_LOAD(6, b6) AGG_LOAD(7, b7)
            AGG_UPD(0, true) AGG_UPD(1, b1) AGG_UPD(2, b2) AGG_UPD(3, b3)
            AGG_UPD(4, b4) AGG_UPD(5, b5) AGG_UPD(6, b6) AGG_UPD(7, b7)
        }
        float inv = ss > 0.f ? 1.f / ss : 0.f;
        float2 o; o.x = vx * inv; o.y = vy * inv;
        agg2v[(size_t)j * 64 + lane] = o;
    }
}

// ---------------------------------------------------------------------------
extern "C" void kernel_launch(void* const* d_in, const int* in_sizes, int n_in,
                              void* d_out, int out_size, void* d_ws, size_t ws_size,
                              hipStream_t stream) {
    static const int expect[29] = {
        6400000, 3840000, 1280000, 640000,
        500000, 500000, 500000, 500000, 250000, 250000, 250000, 250000,
        1000000, 750000, 65536, 512, 65536, 512, 512, 320, 256,
        8192, 128, 384, 128, 16384, 128, 65536, 512};
    int bad = 0;
    if (n_in != 29) bad = 1;
    else {
        for (int i = 0; i < 29; i++)
            if (in_sizes[i] != expect[i]) { bad = 4 + i; break; }
    }
    if (!bad && out_size != 12160000) bad = 2;
    if (!bad && ws_size < (size_t)63425536) bad = 3;
    if (bad) {
        senthost_k<<<1, 1, 0, stream>>>((float*)d_out, 4096.f * (float)bad);
        return;
    }

    const float* x_chem = (const float*)d_in[0];
    const float* x_gene = (const float*)d_in[1];
    const float* x_dis  = (const float*)d_in[2];
    const float* x_path = (const float*)d_in[3];
    const int* src0 = (const int*)d_in[4];  const int* dst0 = (const int*)d_in[5];
    const int* src1 = (const int*)d_in[6];  const int* dst1 = (const int*)d_in[7];
    const int* src2 = (const int*)d_in[8];  const int* dst2 = (const int*)d_in[9];
    const int* src3 = (const int*)d_in[10]; const int* dst3 = (const int*)d_in[11];
    const int*   cg   = (const int*)d_in[12];
    const float* cp   = (const float*)d_in[13];
    const float* Wsrc = (const float*)d_in[14]; const float* bsrc = (const float*)d_in[15];
    const float* Wdst = (const float*)d_in[16]; const float* bdst = (const float*)d_in[17];
    const float* attn = (const float*)d_in[18];
    const float* temb = (const float*)d_in[19]; const float* semb = (const float*)d_in[20];
    const float* Wg   = (const float*)d_in[21]; const float* bg   = (const float*)d_in[22];
    const float* W1c  = (const float*)d_in[23]; const float* b1c  = (const float*)d_in[24];
    const float* W2c  = (const float*)d_in[25]; const float* b2c  = (const float*)d_in[26];
    const float* Wout = (const float*)d_in[27]; const float* bout = (const float*)d_in[28];

    constexpr int NC = 50000, NG = 30000, ND = 10000, NP = 5000;
    constexpr int E2 = 250000;
    constexpr int ET = 1500000;
    constexpr int GCAP = 80000;

    char* ws = (char*)d_ws;
    float* gt   = (float*)ws;              // [64][128] f32 = 32768 B
    int*   csum = (int*)(ws + 32768);      // 4 x 64 ints
    float* avb  = (float*)(ws + 36864);    // 4 slots x 520 floats
    u16*   w2p  = (u16*)  (ws + 49152);    // packed W2 fragments, 32768 B
    char*  A    = ws + 98304;              // stage arena

    // CSR block [A+50,780,000 ..] — untouched by any stage peak.
    char* CB = A + 50780000;
    int*  degU = (int*)(CB);                // 115000 ints
    int*  stsU = (int*)(CB + 460000);
    int*  curU = (int*)(CB + 920000);
    int*  sp1  = (int*)(CB + 1380000);      // t1 si (500K)        .. 3,380,000
    int2* sp2i = (int2*)(CB + 3380000);     // t2 {si,el} (250K)   .. 5,380,000
    int*  sp0  = (int*)(CB + 5380000);      // t0 si|cmb<<16 (500K).. 7,380,000
    int*  sp3  = (int*)(CB + 7380000);      // t3 si (250K)        .. 8,380,000

    float* out = (float*)d_out;
    float* out_chem = out;
    float* out_gene = out + (size_t)NC * 128;
    float* out_dis  = out + (size_t)(NC + NG) * 128;
    float* out_path = out + (size_t)(NC + NG + ND) * 128;

    // ---------- prep + batched CSR build (all 4 edge types) ----------
    prep_k<<<44, 256, 0, stream>>>(temb, semb, Wg, bg, gt, Wdst, bdst, attn, avb, W2c, w2p);
    zero_k<<<(115000 + 255) / 256, 256, 0, stream>>>(degU, 115000);
    hist4_k<<<(ET + 255) / 256, 256, 0, stream>>>(dst1, dst2, dst0, dst3, degU);
    {
        dim3 g1(49, 4);
        scan1b_k<<<g1, 256, 0, stream>>>(degU, csum);
        scan2b_k<<<1, 64, 0, stream>>>(csum);
        scan3b_k<<<g1, 256, 0, stream>>>(degU, csum, stsU, curU);
    }
    scatter4_k<<<(ET + 255) / 256, 256, 0, stream>>>(dst1, src1, dst2, src2, dst0, src0,
                                                     dst3, src3, cg, curU,
                                                     sp1, sp2i, sp0, sp3);

    // ---------- STAGE A: chemical output (t1: gene -> chemical) ----------
    {
        float* hs1  = (float*)(A);                 //  0 .. 15,360,000
        float* ad1  = (float*)(A + 15360000);      // .. 16,160,000
        float* hsa1 = (float*)(A + 16160000);      // .. 16,640,000
        float* agg1 = (float*)(A + 16640000);      // .. 42,240,000
        denseT_k<1, 1><<<(NG + 31) / 32, 256, 0, stream>>>(x_gene, nullptr,
                                                           Wsrc + 1 * 16384, bsrc + 1 * 128, hs1,
                                                           attn + 1 * 128, hsa1, NG, (NG + 31) / 32);
        adg_k<<<1024, 256, 0, stream>>>(x_chem, avb + 1 * 520, avb + 1 * 520 + 512, ad1, NC);
        agg_k<4><<<2048, 256, 0, stream>>>(hs1, ad1, hsa1, sp1, stsU + 0, degU + 0,
                                           attn + 1 * 128, nullptr, nullptr, agg1, 0, NC);
        denseT_k<1, 0><<<(NC + 31) / 32, 256, 0, stream>>>(agg1, nullptr,
                                                           Wout + 0 * 16384, bout + 0 * 128, out_chem,
                                                           nullptr, nullptr, NC, (NC + 31) / 32);
    }

    // ---------- STAGE B: pathway output (t2: chemical -> pathway) ----------
    {
        float* hs2  = (float*)(A);                 //  0 .. 25,600,000
        float* ad2  = (float*)(A + 25600000);      // .. 25,680,000
        float* agg2 = (float*)(A + 25680000);      // .. 28,240,000
        u16*   gatep = (u16*) (A + 28240000);      // .. 48,720,000
        denseT_k<1, 0><<<(NC + 31) / 32, 256, 0, stream>>>(x_chem, nullptr,
                                                           Wsrc + 2 * 16384, bsrc + 2 * 128, hs2,
                                                           nullptr, nullptr, NC, (NC + 31) / 32);
        adg_k<<<256, 256, 0, stream>>>(x_path, avb + 2 * 520, avb + 2 * 520 + 512, ad2, NP);
        for (int ck = 0; ck < 4; ck++) {
            int j0 = ck * 1250, j1 = j0 + 1250;
            ugmm_k<<<1024, 256, 0, stream>>>(cp, W1c, b1c, w2p, b2c, (const int*)sp2i,
                                             stsU + 50000, gatep, j0, j1, NP, E2, GCAP);
            agg_k<3><<<313, 256, 0, stream>>>(hs2, ad2, nullptr, (const int*)sp2i,
                                              stsU + 50000, degU + 50000,
                                              attn + 2 * 128, nullptr, gatep, agg2, j0, j1);
        }
        denseT_k<1, 0><<<(NP + 31) / 32, 256, 0, stream>>>(agg2, nullptr,
                                                           Wout + 3 * 16384, bout + 3 * 128, out_path,
                                                           nullptr, nullptr, NP, (NP + 31) / 32);
    }

    // ---------- STAGE C: gene output (t0 + t3) ----------
    {
        float* hs0  = (float*)(A);                 //  0 .. 25,600,000 (phase 1)
        float* ad0  = (float*)(A + 25600000);      // .. 26,080,000
        float* ad3  = (float*)(A + 26080000);      // .. 26,560,000
        float* hsa3 = (float*)(A + 26560000);      // .. 26,720,000
        float* agg0 = (float*)(A + 26720000);      // .. 42,080,000
        float* hs3  = (float*)(A);                 //  0 .. 5,120,000 (phase 2)
        float* agg3 = (float*)(A + 5120000);       // .. 20,480,000 (phase 2, hs0 dead)
        denseT_k<1, 0><<<(NC + 31) / 32, 256, 0, stream>>>(x_chem, nullptr,
                                                           Wsrc + 0 * 16384, bsrc + 0 * 128, hs0,
                                                           nullptr, nullptr, NC, (NC + 31) / 32);
        adg2_k<<<1024, 256, 0, stream>>>(x_gene, avb + 0 * 520, avb + 0 * 520 + 512,
                                         avb + 3 * 520, avb + 3 * 520 + 512, ad0, ad3, NG);
        agg_k<1><<<2048, 256, 0, stream>>>(hs0, ad0, nullptr, sp0,
                                           stsU + 55000, degU + 55000,
                                           attn + 0 * 128, gt, nullptr, agg0, 0, NG);
        denseT_k<1, 1><<<(ND + 31) / 32, 256, 0, stream>>>(x_dis, nullptr,
                                                           Wsrc + 3 * 16384, bsrc + 3 * 128, hs3,
                                                           attn + 3 * 128, hsa3, ND, (ND + 31) / 32);
        agg_k<4><<<2048, 256, 0, stream>>>(hs3, ad3, hsa3, sp3,
                                           stsU + 85000, degU + 85000,
                                           attn + 3 * 128, nullptr, nullptr, agg3, 0, NG);
        denseT_k<2, 0><<<(NG + 31) / 32, 256, 0, stream>>>(agg0, agg3,
                                                           Wout + 1 * 16384, bout + 1 * 128, out_gene,
                                                           nullptr, nullptr, NG, (NG + 31) / 32);
    }

    // ---------- STAGE D: disease output (no incoming edges: bias only) ------
    biasrow_k<<<(ND * 64 + 255) / 256, 256, 0, stream>>>(bout + 2 * 128, out_dis, ND);
}